// Round 1
// baseline (1772.865 us; speedup 1.0000x reference)
//
#include <hip/hip_runtime.h>
#include <math.h>

#define LSEQ 4096
#define DMODEL 512
#define BB 8
#define TOPK 8

// ---------------- fp32 tiled GEMM: C[M,512] = A[M,512] @ W[512,512] + bias ----------------
__global__ __launch_bounds__(256) void gemm_bias(const float* __restrict__ A,
                                                 const float* __restrict__ W,
                                                 const float* __restrict__ bias,
                                                 float* __restrict__ C) {
    __shared__ float As[16][64];   // [k][m]
    __shared__ float Ws[16][64];   // [k][n]
    const int tid = threadIdx.x;
    const int tx = tid & 15, ty = tid >> 4;
    const int bm = blockIdx.y * 64, bn = blockIdx.x * 64;

    float acc[4][4] = {};
    const int arow = tid >> 2, ak4 = tid & 3;      // A tile: 64 rows x 16 k
    const int wrow = tid >> 4, wc4 = tid & 15;     // W tile: 16 k x 64 n

    for (int k0 = 0; k0 < 512; k0 += 16) {
        float4 av = *(const float4*)&A[(size_t)(bm + arow) * 512 + k0 + ak4 * 4];
        float4 wv = *(const float4*)&W[(size_t)(k0 + wrow) * 512 + bn + wc4 * 4];
        __syncthreads();
        As[ak4 * 4 + 0][arow] = av.x;
        As[ak4 * 4 + 1][arow] = av.y;
        As[ak4 * 4 + 2][arow] = av.z;
        As[ak4 * 4 + 3][arow] = av.w;
        *(float4*)&Ws[wrow][wc4 * 4] = wv;
        __syncthreads();
#pragma unroll
        for (int k = 0; k < 16; ++k) {
            float4 a = *(const float4*)&As[k][ty * 4];
            float4 b = *(const float4*)&Ws[k][tx * 4];
            acc[0][0] += a.x * b.x; acc[0][1] += a.x * b.y; acc[0][2] += a.x * b.z; acc[0][3] += a.x * b.w;
            acc[1][0] += a.y * b.x; acc[1][1] += a.y * b.y; acc[1][2] += a.y * b.z; acc[1][3] += a.y * b.w;
            acc[2][0] += a.z * b.x; acc[2][1] += a.z * b.y; acc[2][2] += a.z * b.z; acc[2][3] += a.z * b.w;
            acc[3][0] += a.w * b.x; acc[3][1] += a.w * b.y; acc[3][2] += a.w * b.z; acc[3][3] += a.w * b.w;
        }
    }
    float4 bv = *(const float4*)&bias[bn + tx * 4];
#pragma unroll
    for (int i = 0; i < 4; ++i) {
        float4 o;
        o.x = acc[i][0] + bv.x; o.y = acc[i][1] + bv.y;
        o.z = acc[i][2] + bv.z; o.w = acc[i][3] + bv.w;
        *(float4*)&C[(size_t)(bm + ty * 4 + i) * 512 + bn + tx * 4] = o;
    }
}

// ---------------- in-LDS radix-2 4096-pt complex FFT (DIT, input bit-reversed) ----------------
__device__ __forceinline__ void fft4096_lds(float2* buf, int tid) {
    for (int s = 0; s < 12; ++s) {
        int half = 1 << s;
#pragma unroll 8
        for (int u = tid; u < 2048; u += 256) {
            int pos = u & (half - 1);
            int i0 = ((u >> s) << (s + 1)) + pos;
            int i1 = i0 + half;
            float ang = -3.14159265358979f * (float)pos / (float)half;  // -2*pi*pos/m
            float sw, cw;
            __sincosf(ang, &sw, &cw);
            float2 x0 = buf[i0], x1 = buf[i1];
            float tr = cw * x1.x - sw * x1.y;
            float ti = cw * x1.y + sw * x1.x;
            buf[i0] = make_float2(x0.x + tr, x0.y + ti);
            buf[i1] = make_float2(x0.x - tr, x0.y - ti);
        }
        __syncthreads();
    }
}

// grid: B*32 blocks; block (b, g) handles channels d = g*16 .. g*16+15 of batch b.
// Packs z = q + i*k, one FFT per channel, accumulates cross-spectrum Qf*conj(Kf) in LDS,
// writes its partial spectrum to Ppart[b][g][4096][2].
__global__ __launch_bounds__(256) void fft_cross(const float* __restrict__ Q,
                                                 const float* __restrict__ K,
                                                 float* __restrict__ Ppart) {
    __shared__ float2 buf[4096];
    __shared__ float2 acc[4096];
    const int tid = threadIdx.x;
    const int b = blockIdx.x >> 5;
    const int g = blockIdx.x & 31;

    for (int j = tid; j < 4096; j += 256) acc[j] = make_float2(0.f, 0.f);
    __syncthreads();

    for (int c = 0; c < 16; ++c) {
        const int d = g * 16 + c;
        const float* qb = Q + (size_t)b * LSEQ * DMODEL + d;
        const float* kb = K + (size_t)b * LSEQ * DMODEL + d;
        for (int j = tid; j < 4096; j += 256) {
            int r = __brev(j) >> 20;
            buf[r] = make_float2(qb[(size_t)j * DMODEL], kb[(size_t)j * DMODEL]);
        }
        __syncthreads();
        fft4096_lds(buf, tid);
        for (int j = tid; j < 4096; j += 256) {
            float2 zf = buf[j];
            float2 zn = buf[(4096 - j) & 4095];
            float qr = 0.5f * (zf.x + zn.x);
            float qi = 0.5f * (zf.y - zn.y);
            float dr = zf.x - zn.x;
            float di = zf.y + zn.y;
            float kr = 0.5f * di;
            float ki = -0.5f * dr;
            // C = Qf * conj(Kf)
            acc[j].x += qr * kr + qi * ki;
            acc[j].y += qi * kr - qr * ki;
        }
        __syncthreads();
    }
    float* Pp = Ppart + (size_t)(b * 32 + g) * 4096 * 2;
    for (int j = tid; j < 4096; j += 256) {
        Pp[j * 2 + 0] = acc[j].x;
        Pp[j * 2 + 1] = acc[j].y;
    }
}

// grid: B blocks. Sum the 32 partial spectra, inverse FFT (conj->fft->Re), scale.
__global__ __launch_bounds__(256) void ifft_mean(const float* __restrict__ Ppart,
                                                 float* __restrict__ mv) {
    __shared__ float2 buf[4096];
    const int tid = threadIdx.x;
    const int b = blockIdx.x;
    for (int j = tid; j < 4096; j += 256) {
        float sr = 0.f, si = 0.f;
        for (int gidx = 0; gidx < 32; ++gidx) {
            const float* p = Ppart + ((size_t)(b * 32 + gidx) * 4096 + j) * 2;
            sr += p[0];
            si += p[1];
        }
        buf[__brev(j) >> 20] = make_float2(sr, -si);  // conj for inverse transform
    }
    __syncthreads();
    fft4096_lds(buf, tid);
    const float scale = 1.0f / (4096.0f * 512.0f);  // irfft 1/L  and  mean over H*E
    for (int j = tid; j < 4096; j += 256) mv[(size_t)b * 4096 + j] = buf[j].x * scale;
}

// single block: batch-mean, iterative top-8 argmax (lower-index tie-break), per-batch softmax
__global__ __launch_bounds__(256) void topk_softmax(const float* __restrict__ mv,
                                                    int* __restrict__ idxO,
                                                    float* __restrict__ tcO) {
    __shared__ float vals[4096];
    __shared__ float rv[256];
    __shared__ int ri[256];
    __shared__ int sidx[TOPK];
    const int tid = threadIdx.x;
    for (int j = tid; j < 4096; j += 256) {
        float s = 0.f;
        for (int b = 0; b < BB; ++b) s += mv[(size_t)b * 4096 + j];
        vals[j] = s * 0.125f;
    }
    __syncthreads();
    for (int k = 0; k < TOPK; ++k) {
        float best = -INFINITY;
        int bi = 0x7fffffff;
        for (int j = tid; j < 4096; j += 256) {
            float v = vals[j];
            if (v > best) { best = v; bi = j; }
        }
        rv[tid] = best; ri[tid] = bi;
        __syncthreads();
        for (int off = 128; off > 0; off >>= 1) {
            if (tid < off) {
                float ov = rv[tid + off]; int oi = ri[tid + off];
                if (ov > rv[tid] || (ov == rv[tid] && oi < ri[tid])) { rv[tid] = ov; ri[tid] = oi; }
            }
            __syncthreads();
        }
        if (tid == 0) {
            sidx[k] = ri[0];
            idxO[k] = ri[0];
            vals[ri[0]] = -INFINITY;
        }
        __syncthreads();
    }
    if (tid < BB) {
        float w[TOPK];
        float m = -INFINITY;
        for (int k = 0; k < TOPK; ++k) {
            w[k] = mv[(size_t)tid * 4096 + sidx[k]];
            m = fmaxf(m, w[k]);
        }
        float s = 0.f;
        for (int k = 0; k < TOPK; ++k) { w[k] = expf(w[k] - m); s += w[k]; }
        float inv = 1.0f / s;
        for (int k = 0; k < TOPK; ++k) tcO[tid * TOPK + k] = w[k] * inv;
    }
}

// agg[b,l,d] = sum_k tc[b,k] * V[b,(l+idx[k])%L,d]  — float4 per thread
__global__ __launch_bounds__(256) void gather_agg(const float* __restrict__ V,
                                                  const int* __restrict__ idx,
                                                  const float* __restrict__ tc,
                                                  float* __restrict__ agg) {
    const int e = blockIdx.x * 256 + threadIdx.x;  // float4 index
    const int d4 = e & 127;
    const int l = (e >> 7) & 4095;
    const int b = e >> 19;
    float4 s = make_float4(0.f, 0.f, 0.f, 0.f);
#pragma unroll
    for (int k = 0; k < TOPK; ++k) {
        int src = (l + idx[k]) & 4095;
        float w = tc[b * TOPK + k];
        float4 v = *(const float4*)&V[((size_t)b * 4096 + src) * 512 + d4 * 4];
        s.x += w * v.x; s.y += w * v.y; s.z += w * v.z; s.w += w * v.w;
    }
    *(float4*)&agg[((size_t)b * 4096 + l) * 512 + d4 * 4] = s;
}

extern "C" void kernel_launch(void* const* d_in, const int* in_sizes, int n_in,
                              void* d_out, int out_size, void* d_ws, size_t ws_size,
                              hipStream_t stream) {
    const float* queries = (const float*)d_in[0];
    const float* keys    = (const float*)d_in[1];
    const float* values  = (const float*)d_in[2];
    const float* Wq = (const float*)d_in[3];
    const float* bq = (const float*)d_in[4];
    const float* Wk = (const float*)d_in[5];
    const float* bk = (const float*)d_in[6];
    const float* Wv = (const float*)d_in[7];
    const float* bv = (const float*)d_in[8];
    const float* Wo = (const float*)d_in[9];
    const float* bo = (const float*)d_in[10];
    float* out = (float*)d_out;

    float* ws = (float*)d_ws;
    const size_t SZ = (size_t)BB * LSEQ * DMODEL;  // 16,777,216 floats
    float* Qp    = ws;                  // 64 MB
    float* Kp    = ws + SZ;             // 64 MB
    float* Vp    = ws + 2 * SZ;         // 64 MB
    float* Ppart = ws + 3 * SZ;         // 8*32*4096*2 floats = 8 MB
    float* mv    = Ppart + (size_t)BB * 32 * 4096 * 2;  // 32768 floats
    int*   idx   = (int*)(mv + (size_t)BB * 4096);
    float* tc    = (float*)(idx + 16);  // 64 floats
    float* agg   = ws;                  // reuse Q's space (Q dead after fft_cross)

    dim3 ggrid(512 / 64, (BB * LSEQ) / 64);
    dim3 gblk(256);

    gemm_bias<<<ggrid, gblk, 0, stream>>>(queries, Wq, bq, Qp);
    gemm_bias<<<ggrid, gblk, 0, stream>>>(keys,    Wk, bk, Kp);
    gemm_bias<<<ggrid, gblk, 0, stream>>>(values,  Wv, bv, Vp);

    fft_cross<<<dim3(BB * 32), gblk, 0, stream>>>(Qp, Kp, Ppart);
    ifft_mean<<<dim3(BB), gblk, 0, stream>>>(Ppart, mv);
    topk_softmax<<<dim3(1), gblk, 0, stream>>>(mv, idx, tc);

    gather_agg<<<dim3((BB * LSEQ * (DMODEL / 4)) / 256), gblk, 0, stream>>>(Vp, idx, tc, agg);

    gemm_bias<<<ggrid, gblk, 0, stream>>>(agg, Wo, bo, out);
}

// Round 2
// 1296.597 us; speedup vs baseline: 1.3673x; 1.3673x over previous
//
#include <hip/hip_runtime.h>
#include <math.h>

#define LSEQ 4096
#define DMODEL 512
#define BB 8
#define TOPK 8
#define ML (BB * LSEQ)        // 32768 rows total
#define FFT_CH 8              // channels per fft_cross block
#define NGRP (DMODEL / FFT_CH)  // 64 groups per batch

// ---------------- fp32 tiled GEMM: C = A[M,512] @ W[512,512] + bias ----------------
// TOUT=false: C[M,512] row-major.  TOUT=true: C^T stored as CT[512][ML] (CT[n][m]).
template <bool TOUT>
__global__ __launch_bounds__(256) void gemm_bias_k(const float* __restrict__ A,
                                                   const float* __restrict__ W,
                                                   const float* __restrict__ bias,
                                                   float* __restrict__ C) {
    __shared__ float As[16][64];   // [k][m]
    __shared__ float Ws[16][64];   // [k][n]
    const int tid = threadIdx.x;
    const int tx = tid & 15, ty = tid >> 4;
    const int bm = blockIdx.y * 64, bn = blockIdx.x * 64;

    float acc[4][4] = {};
    const int arow = tid >> 2, ak4 = tid & 3;      // A tile: 64 rows x 16 k
    const int wrow = tid >> 4, wc4 = tid & 15;     // W tile: 16 k x 64 n

    for (int k0 = 0; k0 < 512; k0 += 16) {
        float4 av = *(const float4*)&A[(size_t)(bm + arow) * 512 + k0 + ak4 * 4];
        float4 wv = *(const float4*)&W[(size_t)(k0 + wrow) * 512 + bn + wc4 * 4];
        __syncthreads();
        As[ak4 * 4 + 0][arow] = av.x;
        As[ak4 * 4 + 1][arow] = av.y;
        As[ak4 * 4 + 2][arow] = av.z;
        As[ak4 * 4 + 3][arow] = av.w;
        *(float4*)&Ws[wrow][wc4 * 4] = wv;
        __syncthreads();
#pragma unroll
        for (int k = 0; k < 16; ++k) {
            float4 a = *(const float4*)&As[k][ty * 4];
            float4 b = *(const float4*)&Ws[k][tx * 4];
            acc[0][0] += a.x * b.x; acc[0][1] += a.x * b.y; acc[0][2] += a.x * b.z; acc[0][3] += a.x * b.w;
            acc[1][0] += a.y * b.x; acc[1][1] += a.y * b.y; acc[1][2] += a.y * b.z; acc[1][3] += a.y * b.w;
            acc[2][0] += a.z * b.x; acc[2][1] += a.z * b.y; acc[2][2] += a.z * b.z; acc[2][3] += a.z * b.w;
            acc[3][0] += a.w * b.x; acc[3][1] += a.w * b.y; acc[3][2] += a.w * b.z; acc[3][3] += a.w * b.w;
        }
    }
    float4 bv = *(const float4*)&bias[bn + tx * 4];

    if constexpr (!TOUT) {
#pragma unroll
        for (int i = 0; i < 4; ++i) {
            float4 o;
            o.x = acc[i][0] + bv.x; o.y = acc[i][1] + bv.y;
            o.z = acc[i][2] + bv.z; o.w = acc[i][3] + bv.w;
            *(float4*)&C[(size_t)(bm + ty * 4 + i) * 512 + bn + tx * 4] = o;
        }
    } else {
        __shared__ float Ts[64][65];   // [m_local][n_local], pad 65 -> conflict-free transpose
        __syncthreads();               // As/Ws reads done before Ts overlaps (different mem, but keep ordered)
        float bvv[4] = {bv.x, bv.y, bv.z, bv.w};
#pragma unroll
        for (int i = 0; i < 4; ++i)
#pragma unroll
            for (int j = 0; j < 4; ++j)
                Ts[ty * 4 + i][tx * 4 + j] = acc[i][j] + bvv[j];
        __syncthreads();
        const int n_local = tid >> 2;       // 0..63
        const int mq = tid & 3;             // 0..3
#pragma unroll
        for (int p = 0; p < 4; ++p) {
            const int m0 = mq * 4 + p * 16;
            float4 o;
            o.x = Ts[m0 + 0][n_local];
            o.y = Ts[m0 + 1][n_local];
            o.z = Ts[m0 + 2][n_local];
            o.w = Ts[m0 + 3][n_local];
            *(float4*)&C[(size_t)(bn + n_local) * ML + bm + m0] = o;
        }
    }
}

// ---------------- in-LDS radix-2 4096-pt complex FFT, table twiddles ----------------
__device__ __forceinline__ void fft4096_lds_tw(float2* buf, const float2* tw, int tid) {
    for (int s = 0; s < 12; ++s) {
        const int half = 1 << s;
        const int tsh = 11 - s;
#pragma unroll 8
        for (int u = tid; u < 2048; u += 256) {
            int pos = u & (half - 1);
            int i0 = ((u >> s) << (s + 1)) + pos;
            int i1 = i0 + half;
            float2 w = tw[pos << tsh];
            float2 x0 = buf[i0], x1 = buf[i1];
            float tr = w.x * x1.x - w.y * x1.y;
            float ti = w.x * x1.y + w.y * x1.x;
            buf[i0] = make_float2(x0.x + tr, x0.y + ti);
            buf[i1] = make_float2(x0.x - tr, x0.y - ti);
        }
        __syncthreads();
    }
}

__device__ __forceinline__ void init_twiddle(float2* tw, int tid) {
    for (int k = tid; k < 2048; k += 256) {
        float s, c;
        __sincosf(-3.14159265358979f * (float)k / 2048.0f, &s, &c);
        tw[k] = make_float2(c, s);
    }
}

// grid: BB*NGRP blocks. Block (b,g): channels d = g*FFT_CH .. +FFT_CH-1.
// Qt/Kt layout: [d][b*4096 + l] (contiguous per channel). Cross-spectrum acc in REGISTERS.
__global__ __launch_bounds__(256) void fft_cross(const float* __restrict__ Qt,
                                                 const float* __restrict__ Kt,
                                                 float* __restrict__ Ppart) {
    __shared__ float2 buf[4096];
    __shared__ float2 tw[2048];
    const int tid = threadIdx.x;
    const int b = blockIdx.x / NGRP;
    const int g = blockIdx.x % NGRP;

    float2 acc[16];
#pragma unroll
    for (int i = 0; i < 16; ++i) acc[i] = make_float2(0.f, 0.f);
    init_twiddle(tw, tid);

    for (int c = 0; c < FFT_CH; ++c) {
        const int d = g * FFT_CH + c;
        const float* qb = Qt + (size_t)d * ML + b * LSEQ;
        const float* kb = Kt + (size_t)d * ML + b * LSEQ;
        __syncthreads();   // previous iteration's buf reads done (also orders tw init)
        for (int j = tid; j < 4096; j += 256) {
            int r = __brev(j) >> 20;
            buf[r] = make_float2(qb[j], kb[j]);
        }
        __syncthreads();
        fft4096_lds_tw(buf, tw, tid);
#pragma unroll
        for (int i = 0; i < 16; ++i) {
            const int j = i * 256 + tid;
            float2 zf = buf[j];
            float2 zn = buf[(4096 - j) & 4095];
            float qr = 0.5f * (zf.x + zn.x);
            float qi = 0.5f * (zf.y - zn.y);
            float kr = 0.5f * (zf.y + zn.y);
            float ki = -0.5f * (zf.x - zn.x);
            acc[i].x += qr * kr + qi * ki;   // Re(Qf * conj(Kf))
            acc[i].y += qi * kr - qr * ki;   // Im(Qf * conj(Kf))
        }
    }
    float2* Pp = (float2*)Ppart + (size_t)blockIdx.x * 4096;
#pragma unroll
    for (int i = 0; i < 16; ++i) Pp[i * 256 + tid] = acc[i];
}

// grid: BB blocks. Sum NGRP partial spectra, inverse FFT (conj->fft->Re), scale.
__global__ __launch_bounds__(256) void ifft_mean(const float* __restrict__ Ppart,
                                                 float* __restrict__ mv) {
    __shared__ float2 buf[4096];
    __shared__ float2 tw[2048];
    const int tid = threadIdx.x;
    const int b = blockIdx.x;
    init_twiddle(tw, tid);
    for (int j = tid; j < 4096; j += 256) {
        float sr = 0.f, si = 0.f;
        for (int gidx = 0; gidx < NGRP; ++gidx) {
            const float2 p = ((const float2*)Ppart)[(size_t)(b * NGRP + gidx) * 4096 + j];
            sr += p.x;
            si += p.y;
        }
        buf[__brev(j) >> 20] = make_float2(sr, -si);  // conj for inverse transform
    }
    __syncthreads();
    fft4096_lds_tw(buf, tw, tid);
    const float scale = 1.0f / (4096.0f * 512.0f);  // irfft 1/L and mean over H*E
    for (int j = tid; j < 4096; j += 256) mv[(size_t)b * 4096 + j] = buf[j].x * scale;
}

// single block: batch-mean, iterative top-8 argmax (lower-index tie-break), per-batch softmax
__global__ __launch_bounds__(256) void topk_softmax(const float* __restrict__ mv,
                                                    int* __restrict__ idxO,
                                                    float* __restrict__ tcO) {
    __shared__ float vals[4096];
    __shared__ float rv[256];
    __shared__ int ri[256];
    __shared__ int sidx[TOPK];
    const int tid = threadIdx.x;
    for (int j = tid; j < 4096; j += 256) {
        float s = 0.f;
        for (int b = 0; b < BB; ++b) s += mv[(size_t)b * 4096 + j];
        vals[j] = s * 0.125f;
    }
    __syncthreads();
    for (int k = 0; k < TOPK; ++k) {
        float best = -INFINITY;
        int bi = 0x7fffffff;
        for (int j = tid; j < 4096; j += 256) {
            float v = vals[j];
            if (v > best) { best = v; bi = j; }
        }
        rv[tid] = best; ri[tid] = bi;
        __syncthreads();
        for (int off = 128; off > 0; off >>= 1) {
            if (tid < off) {
                float ov = rv[tid + off]; int oi = ri[tid + off];
                if (ov > rv[tid] || (ov == rv[tid] && oi < ri[tid])) { rv[tid] = ov; ri[tid] = oi; }
            }
            __syncthreads();
        }
        if (tid == 0) {
            sidx[k] = ri[0];
            idxO[k] = ri[0];
            vals[ri[0]] = -INFINITY;
        }
        __syncthreads();
    }
    if (tid < BB) {
        float w[TOPK];
        float m = -INFINITY;
        for (int k = 0; k < TOPK; ++k) {
            w[k] = mv[(size_t)tid * 4096 + sidx[k]];
            m = fmaxf(m, w[k]);
        }
        float s = 0.f;
        for (int k = 0; k < TOPK; ++k) { w[k] = expf(w[k] - m); s += w[k]; }
        float inv = 1.0f / s;
        for (int k = 0; k < TOPK; ++k) tcO[tid * TOPK + k] = w[k] * inv;
    }
}

// agg[b,l,d] = sum_k tc[b,k] * V[b,(l+idx[k])%L,d]  — float4 per thread
__global__ __launch_bounds__(256) void gather_agg(const float* __restrict__ V,
                                                  const int* __restrict__ idx,
                                                  const float* __restrict__ tc,
                                                  float* __restrict__ agg) {
    const int e = blockIdx.x * 256 + threadIdx.x;  // float4 index
    const int d4 = e & 127;
    const int l = (e >> 7) & 4095;
    const int b = e >> 19;
    float4 s = make_float4(0.f, 0.f, 0.f, 0.f);
#pragma unroll
    for (int k = 0; k < TOPK; ++k) {
        int src = (l + idx[k]) & 4095;
        float w = tc[b * TOPK + k];
        float4 v = *(const float4*)&V[((size_t)b * 4096 + src) * 512 + d4 * 4];
        s.x += w * v.x; s.y += w * v.y; s.z += w * v.z; s.w += w * v.w;
    }
    *(float4*)&agg[((size_t)b * 4096 + l) * 512 + d4 * 4] = s;
}

extern "C" void kernel_launch(void* const* d_in, const int* in_sizes, int n_in,
                              void* d_out, int out_size, void* d_ws, size_t ws_size,
                              hipStream_t stream) {
    const float* queries = (const float*)d_in[0];
    const float* keys    = (const float*)d_in[1];
    const float* values  = (const float*)d_in[2];
    const float* Wq = (const float*)d_in[3];
    const float* bq = (const float*)d_in[4];
    const float* Wk = (const float*)d_in[5];
    const float* bk = (const float*)d_in[6];
    const float* Wv = (const float*)d_in[7];
    const float* bv = (const float*)d_in[8];
    const float* Wo = (const float*)d_in[9];
    const float* bo = (const float*)d_in[10];
    float* out = (float*)d_out;

    float* ws = (float*)d_ws;
    const size_t SZ = (size_t)ML * DMODEL;  // 16,777,216 floats = 64 MB
    float* Qt    = ws;                       // [512][32768] transposed Q
    float* Kt    = ws + SZ;                  // [512][32768] transposed K
    float* Vp    = ws + 2 * SZ;              // [b][l][d] normal V
    float* Ppart = ws + 3 * SZ;              // BB*NGRP*4096*2 floats = 16 MB
    float* mv    = Ppart + (size_t)BB * NGRP * 4096 * 2;
    int*   idx   = (int*)(mv + (size_t)BB * 4096);
    float* tc    = (float*)(idx + 16);
    float* agg   = ws;                       // reuse Qt space (dead after fft_cross)

    dim3 ggrid(512 / 64, ML / 64);
    dim3 gblk(256);

    gemm_bias_k<true ><<<ggrid, gblk, 0, stream>>>(queries, Wq, bq, Qt);
    gemm_bias_k<true ><<<ggrid, gblk, 0, stream>>>(keys,    Wk, bk, Kt);
    gemm_bias_k<false><<<ggrid, gblk, 0, stream>>>(values,  Wv, bv, Vp);

    fft_cross<<<dim3(BB * NGRP), gblk, 0, stream>>>(Qt, Kt, Ppart);
    ifft_mean<<<dim3(BB), gblk, 0, stream>>>(Ppart, mv);
    topk_softmax<<<dim3(1), gblk, 0, stream>>>(mv, idx, tc);

    gather_agg<<<dim3((BB * LSEQ * (DMODEL / 4)) / 256), gblk, 0, stream>>>(Vp, idx, tc, agg);

    gemm_bias_k<false><<<ggrid, gblk, 0, stream>>>(agg, Wo, bo, out);
}

// Round 3
// 528.892 us; speedup vs baseline: 3.3520x; 2.4515x over previous
//
#include <hip/hip_runtime.h>
#include <math.h>

#define LSEQ 4096
#define DMODEL 512
#define BB 8
#define TOPK 8
#define ML (BB * LSEQ)          // 32768 rows
#define FFT_CH 8
#define NGRP (DMODEL / FFT_CH)  // 64

typedef unsigned short u16;
typedef unsigned int u32;
typedef float f32x4 __attribute__((ext_vector_type(4)));
typedef short s16x8 __attribute__((ext_vector_type(8)));
typedef u16 u16x8 __attribute__((ext_vector_type(8)));

// ============ split-bf16 3-pass MFMA GEMM: C = A[M,512] @ W[512,512] + bias ============
// A fp32 row-major. W pre-split+transposed: Bhi/Blo are [N][K] bf16 (ushort bits).
// TOUT=false: C[M][512] row-major.  TOUT=true: C^T as CT[512][ML].
// BM=128, BN=128, BK=64, 256 threads (4 waves, 2x2), wave tile 64x64.
template <bool TOUT>
__global__ __launch_bounds__(256, 2) void gemm_split(const float* __restrict__ A,
                                                     const u16* __restrict__ Bhi,
                                                     const u16* __restrict__ Blo,
                                                     const float* __restrict__ bias,
                                                     float* __restrict__ C) {
    __shared__ u16 sAhi[128 * 64];
    __shared__ u16 sAlo[128 * 64];
    __shared__ u16 sBhi[128 * 64];
    __shared__ u16 sBlo[128 * 64];

    const int tid = threadIdx.x;
    // bijective XCD-chunked swizzle: grid 1024, 8 XCDs, 128 per XCD
    const int lin = blockIdx.x;
    const int t = (lin & 7) * 128 + (lin >> 3);
    const int bm = (t >> 2) * 128;
    const int bn = (t & 3) * 128;

    const int lane = tid & 63, wid = tid >> 6;
    const int wm = wid >> 1, wn = wid & 1;
    const int l15 = lane & 15, kg = lane >> 4;

    f32x4 acc[4][4] = {};

    for (int k0 = 0; k0 < 512; k0 += 64) {
        __syncthreads();
        // ---- stage A (fp32 -> hi/lo bf16), 128 rows x 8 chunks of 8 elems ----
#pragma unroll
        for (int it = 0; it < 4; ++it) {
            const int ch = it * 256 + tid;
            const int row = ch >> 3, c = ch & 7;
            const float* ga = A + (size_t)(bm + row) * 512 + k0 + c * 8;
            float4 f0 = *(const float4*)ga;
            float4 f1 = *(const float4*)(ga + 4);
            float fs[8] = {f0.x, f0.y, f0.z, f0.w, f1.x, f1.y, f1.z, f1.w};
            u16x8 hv, lv;
#pragma unroll
            for (int i = 0; i < 8; ++i) {
                u32 u = __float_as_uint(fs[i]);
                hv[i] = (u16)(u >> 16);
                float rem = fs[i] - __uint_as_float(u & 0xFFFF0000u);
                lv[i] = (u16)(__float_as_uint(rem) >> 16);
            }
            const int off = row * 64 + ((c ^ (row & 7)) << 3);
            *(u16x8*)&sAhi[off] = hv;
            *(u16x8*)&sAlo[off] = lv;
        }
        // ---- stage B (pre-split bf16), 128 rows x 8 chunks ----
#pragma unroll
        for (int it = 0; it < 4; ++it) {
            const int ch = it * 256 + tid;
            const int row = ch >> 3, c = ch & 7;
            const int off = row * 64 + ((c ^ (row & 7)) << 3);
            const size_t g = (size_t)(bn + row) * 512 + k0 + c * 8;
            *(u16x8*)&sBhi[off] = *(const u16x8*)&Bhi[g];
            *(u16x8*)&sBlo[off] = *(const u16x8*)&Blo[g];
        }
        __syncthreads();
        // ---- compute: 2 k-chunks of 32 ----
#pragma unroll
        for (int kk = 0; kk < 2; ++kk) {
            const int cbase = kk * 4 + kg;
            s16x8 ah[4], al[4], bh[4], bl[4];
#pragma unroll
            for (int mi = 0; mi < 4; ++mi) {
                const int row = wm * 64 + mi * 16 + l15;
                const int off = row * 64 + (((cbase ^ (row & 7))) << 3);
                ah[mi] = *(const s16x8*)&sAhi[off];
                al[mi] = *(const s16x8*)&sAlo[off];
            }
#pragma unroll
            for (int ni = 0; ni < 4; ++ni) {
                const int row = wn * 64 + ni * 16 + l15;
                const int off = row * 64 + (((cbase ^ (row & 7))) << 3);
                bh[ni] = *(const s16x8*)&sBhi[off];
                bl[ni] = *(const s16x8*)&sBlo[off];
            }
#pragma unroll
            for (int ni = 0; ni < 4; ++ni)
#pragma unroll
                for (int mi = 0; mi < 4; ++mi) {
                    acc[mi][ni] = __builtin_amdgcn_mfma_f32_16x16x32_bf16(ah[mi], bh[ni], acc[mi][ni], 0, 0, 0);
                    acc[mi][ni] = __builtin_amdgcn_mfma_f32_16x16x32_bf16(ah[mi], bl[ni], acc[mi][ni], 0, 0, 0);
                    acc[mi][ni] = __builtin_amdgcn_mfma_f32_16x16x32_bf16(al[mi], bh[ni], acc[mi][ni], 0, 0, 0);
                }
        }
    }
    // ---- epilogue (C/D layout: col = lane&15, row = (lane>>4)*4 + reg) ----
    if constexpr (TOUT) {
#pragma unroll
        for (int ni = 0; ni < 4; ++ni) {
            const int d = bn + wn * 64 + ni * 16 + l15;
            const float bv = bias[d];
#pragma unroll
            for (int mi = 0; mi < 4; ++mi) {
                const int rb = bm + wm * 64 + mi * 16 + (kg << 2);
                float4 o;
                o.x = acc[mi][ni][0] + bv; o.y = acc[mi][ni][1] + bv;
                o.z = acc[mi][ni][2] + bv; o.w = acc[mi][ni][3] + bv;
                *(float4*)&C[(size_t)d * ML + rb] = o;
            }
        }
    } else {
#pragma unroll
        for (int ni = 0; ni < 4; ++ni) {
            const int col = bn + wn * 64 + ni * 16 + l15;
            const float bv = bias[col];
#pragma unroll
            for (int mi = 0; mi < 4; ++mi) {
                const int rb = bm + wm * 64 + mi * 16 + (kg << 2);
#pragma unroll
                for (int r = 0; r < 4; ++r)
                    C[(size_t)(rb + r) * 512 + col] = acc[mi][ni][r] + bv;
            }
        }
    }
}

// ============ tiny fp32 GEMM (512x512x512): Wc = Wv @ Wo ============
__global__ __launch_bounds__(256) void gemm_plain512(const float* __restrict__ A,
                                                     const float* __restrict__ W,
                                                     float* __restrict__ C) {
    __shared__ float As[16][64];
    __shared__ float Ws[16][64];
    const int tid = threadIdx.x;
    const int tx = tid & 15, ty = tid >> 4;
    const int bm = blockIdx.y * 64, bn = blockIdx.x * 64;
    float acc[4][4] = {};
    const int arow = tid >> 2, ak4 = tid & 3;
    const int wrow = tid >> 4, wc4 = tid & 15;
    for (int k0 = 0; k0 < 512; k0 += 16) {
        float4 av = *(const float4*)&A[(size_t)(bm + arow) * 512 + k0 + ak4 * 4];
        float4 wv = *(const float4*)&W[(size_t)(k0 + wrow) * 512 + bn + wc4 * 4];
        __syncthreads();
        As[ak4 * 4 + 0][arow] = av.x;
        As[ak4 * 4 + 1][arow] = av.y;
        As[ak4 * 4 + 2][arow] = av.z;
        As[ak4 * 4 + 3][arow] = av.w;
        *(float4*)&Ws[wrow][wc4 * 4] = wv;
        __syncthreads();
#pragma unroll
        for (int k = 0; k < 16; ++k) {
            float4 a = *(const float4*)&As[k][ty * 4];
            float4 b = *(const float4*)&Ws[k][tx * 4];
            acc[0][0] += a.x * b.x; acc[0][1] += a.x * b.y; acc[0][2] += a.x * b.z; acc[0][3] += a.x * b.w;
            acc[1][0] += a.y * b.x; acc[1][1] += a.y * b.y; acc[1][2] += a.y * b.z; acc[1][3] += a.y * b.w;
            acc[2][0] += a.z * b.x; acc[2][1] += a.z * b.y; acc[2][2] += a.z * b.z; acc[2][3] += a.z * b.w;
            acc[3][0] += a.w * b.x; acc[3][1] += a.w * b.y; acc[3][2] += a.w * b.z; acc[3][3] += a.w * b.w;
        }
    }
#pragma unroll
    for (int i = 0; i < 4; ++i) {
        float4 o;
        o.x = acc[i][0]; o.y = acc[i][1]; o.z = acc[i][2]; o.w = acc[i][3];
        *(float4*)&C[(size_t)(bm + ty * 4 + i) * 512 + bn + tx * 4] = o;
    }
}

// bc[n] = sum_j bv[j]*Wo[j][n] + bo[n]
__global__ __launch_bounds__(256) void bc_kernel(const float* __restrict__ bv,
                                                 const float* __restrict__ Wo,
                                                 const float* __restrict__ bo,
                                                 float* __restrict__ bc) {
    const int n = blockIdx.x * 256 + threadIdx.x;
    if (n < 512) {
        float s = bo[n];
        for (int j = 0; j < 512; ++j) s += bv[j] * Wo[(size_t)j * 512 + n];
        bc[n] = s;
    }
}

// transpose + hi/lo split of the three weight matrices -> [N][K] bf16 bits
__global__ __launch_bounds__(256) void prep_split(const float* __restrict__ Wq,
                                                  const float* __restrict__ Wk,
                                                  const float* __restrict__ Wc,
                                                  u16* __restrict__ Wqh, u16* __restrict__ Wql,
                                                  u16* __restrict__ Wkh, u16* __restrict__ Wkl,
                                                  u16* __restrict__ Wch, u16* __restrict__ Wcl) {
    const int n = blockIdx.x;
    const int which = blockIdx.y;
    const float* src = (which == 0) ? Wq : (which == 1) ? Wk : Wc;
    u16* dh = (which == 0) ? Wqh : (which == 1) ? Wkh : Wch;
    u16* dl = (which == 0) ? Wql : (which == 1) ? Wkl : Wcl;
    for (int k = threadIdx.x; k < 512; k += 256) {
        float f = src[(size_t)k * 512 + n];
        u32 u = __float_as_uint(f);
        u16 h = (u16)(u >> 16);
        float rem = f - __uint_as_float(u & 0xFFFF0000u);
        u32 ur = __float_as_uint(rem);
        u16 l = (u16)((ur + 0x7FFF + ((ur >> 16) & 1)) >> 16);
        dh[(size_t)n * 512 + k] = h;
        dl[(size_t)n * 512 + k] = l;
    }
}

// ============ FFT machinery (unchanged from round 2) ============
__device__ __forceinline__ void fft4096_lds_tw(float2* buf, const float2* tw, int tid) {
    for (int s = 0; s < 12; ++s) {
        const int half = 1 << s;
        const int tsh = 11 - s;
#pragma unroll 8
        for (int u = tid; u < 2048; u += 256) {
            int pos = u & (half - 1);
            int i0 = ((u >> s) << (s + 1)) + pos;
            int i1 = i0 + half;
            float2 w = tw[pos << tsh];
            float2 x0 = buf[i0], x1 = buf[i1];
            float tr = w.x * x1.x - w.y * x1.y;
            float ti = w.x * x1.y + w.y * x1.x;
            buf[i0] = make_float2(x0.x + tr, x0.y + ti);
            buf[i1] = make_float2(x0.x - tr, x0.y - ti);
        }
        __syncthreads();
    }
}

__device__ __forceinline__ void init_twiddle(float2* tw, int tid) {
    for (int k = tid; k < 2048; k += 256) {
        float s, c;
        __sincosf(-3.14159265358979f * (float)k / 2048.0f, &s, &c);
        tw[k] = make_float2(c, s);
    }
}

__global__ __launch_bounds__(256) void fft_cross(const float* __restrict__ Qt,
                                                 const float* __restrict__ Kt,
                                                 float* __restrict__ Ppart) {
    __shared__ float2 buf[4096];
    __shared__ float2 tw[2048];
    const int tid = threadIdx.x;
    const int b = blockIdx.x / NGRP;
    const int g = blockIdx.x % NGRP;
    float2 acc[16];
#pragma unroll
    for (int i = 0; i < 16; ++i) acc[i] = make_float2(0.f, 0.f);
    init_twiddle(tw, tid);
    for (int c = 0; c < FFT_CH; ++c) {
        const int d = g * FFT_CH + c;
        const float* qb = Qt + (size_t)d * ML + b * LSEQ;
        const float* kb = Kt + (size_t)d * ML + b * LSEQ;
        __syncthreads();
        for (int j = tid; j < 4096; j += 256) {
            int r = __brev(j) >> 20;
            buf[r] = make_float2(qb[j], kb[j]);
        }
        __syncthreads();
        fft4096_lds_tw(buf, tw, tid);
#pragma unroll
        for (int i = 0; i < 16; ++i) {
            const int j = i * 256 + tid;
            float2 zf = buf[j];
            float2 zn = buf[(4096 - j) & 4095];
            float qr = 0.5f * (zf.x + zn.x);
            float qi = 0.5f * (zf.y - zn.y);
            float kr = 0.5f * (zf.y + zn.y);
            float ki = -0.5f * (zf.x - zn.x);
            acc[i].x += qr * kr + qi * ki;
            acc[i].y += qi * kr - qr * ki;
        }
    }
    float2* Pp = (float2*)Ppart + (size_t)blockIdx.x * 4096;
#pragma unroll
    for (int i = 0; i < 16; ++i) Pp[i * 256 + tid] = acc[i];
}

// wide deterministic reduction of the NGRP partial spectra
__global__ __launch_bounds__(256) void reduce_ppart(const float2* __restrict__ Pp,
                                                    float2* __restrict__ Pred) {
    const int i = blockIdx.x * 256 + threadIdx.x;  // 0..32767
    const int b = i >> 12, j = i & 4095;
    float sr = 0.f, si = 0.f;
    const float2* base = Pp + (size_t)b * NGRP * 4096 + j;
    for (int g = 0; g < NGRP; ++g) {
        float2 p = base[(size_t)g * 4096];
        sr += p.x;
        si += p.y;
    }
    Pred[i] = make_float2(sr, si);
}

__global__ __launch_bounds__(256) void ifft_mean(const float2* __restrict__ Pred,
                                                 float* __restrict__ mv) {
    __shared__ float2 buf[4096];
    __shared__ float2 tw[2048];
    const int tid = threadIdx.x;
    const int b = blockIdx.x;
    init_twiddle(tw, tid);
    for (int j = tid; j < 4096; j += 256) {
        float2 p = Pred[(size_t)b * 4096 + j];
        buf[__brev(j) >> 20] = make_float2(p.x, -p.y);
    }
    __syncthreads();
    fft4096_lds_tw(buf, tw, tid);
    const float scale = 1.0f / (4096.0f * 512.0f);
    for (int j = tid; j < 4096; j += 256) mv[(size_t)b * 4096 + j] = buf[j].x * scale;
}

__global__ __launch_bounds__(256) void topk_softmax(const float* __restrict__ mv,
                                                    int* __restrict__ idxO,
                                                    float* __restrict__ tcO) {
    __shared__ float vals[4096];
    __shared__ float rv[256];
    __shared__ int ri[256];
    __shared__ int sidx[TOPK];
    const int tid = threadIdx.x;
    for (int j = tid; j < 4096; j += 256) {
        float s = 0.f;
        for (int b = 0; b < BB; ++b) s += mv[(size_t)b * 4096 + j];
        vals[j] = s * 0.125f;
    }
    __syncthreads();
    for (int k = 0; k < TOPK; ++k) {
        float best = -INFINITY;
        int bi = 0x7fffffff;
        for (int j = tid; j < 4096; j += 256) {
            float v = vals[j];
            if (v > best) { best = v; bi = j; }
        }
        rv[tid] = best; ri[tid] = bi;
        __syncthreads();
        for (int off = 128; off > 0; off >>= 1) {
            if (tid < off) {
                float ov = rv[tid + off]; int oi = ri[tid + off];
                if (ov > rv[tid] || (ov == rv[tid] && oi < ri[tid])) { rv[tid] = ov; ri[tid] = oi; }
            }
            __syncthreads();
        }
        if (tid == 0) {
            sidx[k] = ri[0];
            idxO[k] = ri[0];
            vals[ri[0]] = -INFINITY;
        }
        __syncthreads();
    }
    if (tid < BB) {
        float w[TOPK];
        float m = -INFINITY;
        for (int k = 0; k < TOPK; ++k) {
            w[k] = mv[(size_t)tid * 4096 + sidx[k]];
            m = fmaxf(m, w[k]);
        }
        float s = 0.f;
        for (int k = 0; k < TOPK; ++k) { w[k] = expf(w[k] - m); s += w[k]; }
        float inv = 1.0f / s;
        for (int k = 0; k < TOPK; ++k) tcO[tid * TOPK + k] = w[k] * inv;
    }
}

// out[b,l,:] = sum_k tc[b,k] * VO[b,(l+idx[k])%L,:]   (bias folded into VO, sum tc = 1)
__global__ __launch_bounds__(256) void gather_out(const float* __restrict__ VO,
                                                  const int* __restrict__ idx,
                                                  const float* __restrict__ tc,
                                                  float* __restrict__ out) {
    const int e = blockIdx.x * 256 + threadIdx.x;
    const int d4 = e & 127;
    const int l = (e >> 7) & 4095;
    const int b = e >> 19;
    float4 s = make_float4(0.f, 0.f, 0.f, 0.f);
#pragma unroll
    for (int k = 0; k < TOPK; ++k) {
        int src = (l + idx[k]) & 4095;
        float w = tc[b * TOPK + k];
        float4 v = *(const float4*)&VO[((size_t)b * 4096 + src) * 512 + d4 * 4];
        s.x += w * v.x; s.y += w * v.y; s.z += w * v.z; s.w += w * v.w;
    }
    *(float4*)&out[((size_t)b * 4096 + l) * 512 + d4 * 4] = s;
}

extern "C" void kernel_launch(void* const* d_in, const int* in_sizes, int n_in,
                              void* d_out, int out_size, void* d_ws, size_t ws_size,
                              hipStream_t stream) {
    const float* queries = (const float*)d_in[0];
    const float* keys    = (const float*)d_in[1];
    const float* values  = (const float*)d_in[2];
    const float* Wq = (const float*)d_in[3];
    const float* bq = (const float*)d_in[4];
    const float* Wk = (const float*)d_in[5];
    const float* bk = (const float*)d_in[6];
    const float* Wv = (const float*)d_in[7];
    const float* bv = (const float*)d_in[8];
    const float* Wo = (const float*)d_in[9];
    const float* bo = (const float*)d_in[10];
    float* out = (float*)d_out;

    float* ws = (float*)d_ws;
    const size_t SZ = (size_t)ML * DMODEL;          // 16,777,216 floats
    float* Qt   = ws;                                // [512][ML]; reused as VO later
    float* Kt   = ws + SZ;
    float* Pp   = ws + 2 * SZ;                       // 8*64*4096*2 = 4,194,304 floats
    float* Pred = Pp + (size_t)BB * NGRP * 4096 * 2; // 65536 floats
    float* mv   = Pred + (size_t)BB * 4096 * 2;      // 32768
    int*   idx  = (int*)(mv + 32768);                // 16
    float* tc   = mv + 32768 + 16;                   // 64 (pad to 96)
    float* Wc   = mv + 32768 + 96;                   // 262144 floats
    float* bc   = Wc + 262144;                       // 512
    u16* Wqh = (u16*)(bc + 512);
    u16* Wql = Wqh + 262144;
    u16* Wkh = Wql + 262144;
    u16* Wkl = Wkh + 262144;
    u16* Wch = Wkl + 262144;
    u16* Wcl = Wch + 262144;
    float* VO = Qt;  // reuse (Qt dead after fft_cross)

    dim3 blk(256);

    // weight prep: Wc = Wv@Wo, bc = bv@Wo + bo, transpose+split Wq/Wk/Wc
    gemm_plain512<<<dim3(8, 8), blk, 0, stream>>>(Wv, Wo, Wc);
    bc_kernel<<<dim3(2), blk, 0, stream>>>(bv, Wo, bo, bc);
    prep_split<<<dim3(512, 3), blk, 0, stream>>>(Wq, Wk, Wc, Wqh, Wql, Wkh, Wkl, Wch, Wcl);

    // projections (split-bf16 3-pass MFMA)
    gemm_split<true ><<<dim3(1024), blk, 0, stream>>>(queries, Wqh, Wql, bq, Qt);
    gemm_split<true ><<<dim3(1024), blk, 0, stream>>>(keys,    Wkh, Wkl, bk, Kt);

    // correlation path
    fft_cross<<<dim3(BB * NGRP), blk, 0, stream>>>(Qt, Kt, Pp);
    reduce_ppart<<<dim3(128), blk, 0, stream>>>((const float2*)Pp, (float2*)Pred);
    ifft_mean<<<dim3(BB), blk, 0, stream>>>((const float2*)Pred, mv);
    topk_softmax<<<dim3(1), blk, 0, stream>>>(mv, idx, tc);

    // V path: VO = values @ (Wv Wo) + (bv Wo + bo)  [overwrites Qt]
    gemm_split<false><<<dim3(1024), blk, 0, stream>>>(values, Wch, Wcl, bc, VO);

    gather_out<<<dim3((BB * LSEQ * (DMODEL / 4)) / 256), blk, 0, stream>>>(VO, idx, tc, out);
}

// Round 4
// 428.707 us; speedup vs baseline: 4.1354x; 1.2337x over previous
//
#include <hip/hip_runtime.h>
#include <math.h>

#define LSEQ 4096
#define DMODEL 512
#define BB 8
#define TOPK 8
#define ML (BB * LSEQ)          // 32768 rows
#define FFT_CH 8
#define NGRP (DMODEL / FFT_CH)  // 64

typedef unsigned short u16;
typedef unsigned int u32;
typedef float f32x4 __attribute__((ext_vector_type(4)));
typedef short s16x8 __attribute__((ext_vector_type(8)));
typedef u16 u16x8 __attribute__((ext_vector_type(8)));

// ==================== 16-pt FFT, fully unrolled DIF (output bit-reversed in regs) ====================
// After fft16, register r holds Z[brev4(r)].
__device__ __forceinline__ void fft16(float (&zr)[16], float (&zi)[16]) {
    const float C1 = 0.92387953251128674f, S1 = 0.38268343236508978f, R2 = 0.70710678118654752f;
#define BF0(i, j) { float ar=zr[i],ai=zi[i],br=zr[j],bi=zi[j]; zr[i]=ar+br; zi[i]=ai+bi; zr[j]=ar-br; zi[j]=ai-bi; }
#define BFW(i, j, wr, wi) { float ar=zr[i],ai=zi[i],br=zr[j],bi=zi[j]; zr[i]=ar+br; zi[i]=ai+bi; float dr=ar-br, di=ai-bi; zr[j]=dr*(wr)-di*(wi); zi[j]=dr*(wi)+di*(wr); }
#define BFI(i, j) { float ar=zr[i],ai=zi[i],br=zr[j],bi=zi[j]; zr[i]=ar+br; zi[i]=ai+bi; float dr=ar-br, di=ai-bi; zr[j]=di; zi[j]=-dr; }
    // stage 1 (span 8), twiddles W16^j
    BF0(0, 8); BFW(1, 9, C1, -S1); BFW(2, 10, R2, -R2); BFW(3, 11, S1, -C1);
    BFI(4, 12); BFW(5, 13, -S1, -C1); BFW(6, 14, -R2, -R2); BFW(7, 15, -C1, -S1);
    // stage 2 (span 4), twiddles W8^j
    BF0(0, 4); BFW(1, 5, R2, -R2); BFI(2, 6); BFW(3, 7, -R2, -R2);
    BF0(8, 12); BFW(9, 13, R2, -R2); BFI(10, 14); BFW(11, 15, -R2, -R2);
    // stage 3 (span 2), twiddles W4^j
    BF0(0, 2); BFI(1, 3); BF0(4, 6); BFI(5, 7);
    BF0(8, 10); BFI(9, 11); BF0(12, 14); BFI(13, 15);
    // stage 4 (span 1)
    BF0(0, 1); BF0(2, 3); BF0(4, 5); BF0(6, 7);
    BF0(8, 9); BF0(10, 11); BF0(12, 13); BF0(14, 15);
#undef BF0
#undef BFW
#undef BFI
}

// tw[k] = W_4096^k for k < 2048; W^{e} for e in [0,4096) via sign trick
__device__ __forceinline__ float2 twl(const float2* tw, int e) {
    float2 w = tw[e & 2047];
    float s = (e & 2048) ? -1.0f : 1.0f;
    return make_float2(w.x * s, w.y * s);
}

// LDS physical swizzle: phys(n) = n ^ ((key&3)<<2) ^ ((key&1)<<4), key = (n>>8)&15
// keeps float4 blocks intact (bits >= 2 only); gives <=2-way conflicts at all 3 levels.

// grid: BB*NGRP blocks; block (b,g) handles channels d = g*FFT_CH..+7.
// Qt/Kt: [d][b*4096+l]. 3-level radix-16 FFT of z=q+ik; cross-spectrum acc in registers.
__global__ __launch_bounds__(256) void fft_cross(const float* __restrict__ Qt,
                                                 const float* __restrict__ Kt,
                                                 float* __restrict__ Ppart) {
    __shared__ float lre[4096];
    __shared__ float lim[4096];
    __shared__ float2 tw[2048];
    const int t = threadIdx.x;
    const int b = blockIdx.x / NGRP;
    const int g = blockIdx.x % NGRP;
    constexpr int REV16[16] = {0, 8, 4, 12, 2, 10, 6, 14, 1, 9, 5, 13, 3, 11, 7, 15};

    for (int k = t; k < 2048; k += 256) {
        float s, c;
        __sincosf(-3.14159265358979f * (float)k / 2048.0f, &s, &c);
        tw[k] = make_float2(c, s);
    }

    float2 acc[16];
#pragma unroll
    for (int i = 0; i < 16; ++i) acc[i] = make_float2(0.f, 0.f);

    const float4* q4 = (const float4*)(Qt + (size_t)(g * FFT_CH) * ML + (size_t)b * LSEQ);
    const float4* k4 = (const float4*)(Kt + (size_t)(g * FFT_CH) * ML + (size_t)b * LSEQ);

    float4 pq[4], pk[4];
#pragma unroll
    for (int i = 0; i < 4; ++i) {
        pq[i] = q4[t + 256 * i];
        pk[i] = k4[t + 256 * i];
    }

    for (int c = 0; c < FFT_CH; ++c) {
        __syncthreads();  // prev channel's cross-reads done; tw ready (1st iter)
        // ---- stage input (phys-swizzled b128 writes) ----
#pragma unroll
        for (int i = 0; i < 4; ++i) {
            int v = t + 256 * i;
            int key = (v >> 6) & 15;
            int p4 = v ^ (key & 3) ^ ((key & 1) << 2);
            *(float4*)&lre[4 * p4] = pq[i];
            *(float4*)&lim[4 * p4] = pk[i];
        }
        // ---- prefetch next channel into registers ----
        if (c + 1 < FFT_CH) {
            const float4* qn = q4 + (size_t)(c + 1) * (ML >> 2);
            const float4* kn = k4 + (size_t)(c + 1) * (ML >> 2);
#pragma unroll
            for (int i = 0; i < 4; ++i) {
                pq[i] = qn[t + 256 * i];
                pk[i] = kn[t + 256 * i];
            }
        }
        __syncthreads();

        float zr[16], zi[16];
        // ---- level A: DFT16 over n0 (stride 256), twiddle W_256^{n1*k0} ----
#pragma unroll
        for (int gg = 0; gg < 16; ++gg) {
            int n = 256 * gg + t;
            int p = n ^ ((gg & 3) << 2) ^ ((gg & 1) << 4);
            zr[gg] = lre[p]; zi[gg] = lim[p];
        }
        fft16(zr, zi);
        {
            const int n1 = t >> 4;
#pragma unroll
            for (int r = 0; r < 16; ++r) {
                const int k0 = REV16[r];
                float vr = zr[r], vi = zi[r];
                if (k0 != 0) {
                    float2 w = twl(tw, (16 * k0) * n1);
                    float nr = vr * w.x - vi * w.y;
                    vi = vr * w.y + vi * w.x;
                    vr = nr;
                }
                int n = 256 * k0 + t;
                int p = n ^ ((k0 & 3) << 2) ^ ((k0 & 1) << 4);
                lre[p] = vr; lim[p] = vi;
            }
        }
        __syncthreads();
        // ---- level B: DFT16 over n1 (stride 16), twiddle W_4096^{n2*(k0+16k1)} ----
        {
            const int k0 = t >> 4, n2 = t & 15;
            const int x0 = ((k0 & 3) << 2) | ((k0 & 1) << 4);
#pragma unroll
            for (int gg = 0; gg < 16; ++gg) {
                int n = 256 * k0 + 16 * gg + n2;
                zr[gg] = lre[n ^ x0]; zi[gg] = lim[n ^ x0];
            }
            fft16(zr, zi);
#pragma unroll
            for (int r = 0; r < 16; ++r) {
                const int k1 = REV16[r];
                float2 w = twl(tw, n2 * (k0 + 16 * k1));
                float vr = zr[r] * w.x - zi[r] * w.y;
                float vi = zr[r] * w.y + zi[r] * w.x;
                int n = 256 * k0 + 16 * k1 + n2;
                lre[n ^ x0] = vr; lim[n ^ x0] = vi;
            }
        }
        __syncthreads();
        // ---- level C: DFT16 over n2 (stride 1, b128 reads); output natural order ----
        {
            const int k0 = t & 15, k1 = t >> 4;
            const int nb4 = 64 * k0 + 4 * k1;
            const int xv = (k0 & 3) | ((k0 & 1) << 2);
#pragma unroll
            for (int i = 0; i < 4; ++i) {
                int p4 = (nb4 + i) ^ xv;
                float4 fr = *(const float4*)&lre[4 * p4];
                float4 fi = *(const float4*)&lim[4 * p4];
                zr[4 * i + 0] = fr.x; zr[4 * i + 1] = fr.y; zr[4 * i + 2] = fr.z; zr[4 * i + 3] = fr.w;
                zi[4 * i + 0] = fi.x; zi[4 * i + 1] = fi.y; zi[4 * i + 2] = fi.z; zi[4 * i + 3] = fi.w;
            }
            fft16(zr, zi);
            __syncthreads();  // all phys reads done before natural overwrite
#pragma unroll
            for (int r = 0; r < 16; ++r) {
                const int k2 = REV16[r];
                lre[t + 256 * k2] = zr[r];
                lim[t + 256 * k2] = zi[r];
            }
        }
        __syncthreads();
        // ---- cross-spectrum accumulate: Qf * conj(Kf) from packed z = q + i*k ----
#pragma unroll
        for (int i = 0; i < 16; ++i) {
            const int j = i * 256 + t;
            const int nj = (4096 - j) & 4095;
            float zfr = lre[j], zfi = lim[j];
            float znr = lre[nj], zni = lim[nj];
            float qr = 0.5f * (zfr + znr);
            float qi = 0.5f * (zfi - zni);
            float kr = 0.5f * (zfi + zni);
            float ki = -0.5f * (zfr - znr);
            acc[i].x += qr * kr + qi * ki;
            acc[i].y += qi * kr - qr * ki;
        }
    }
    float2* Pp = (float2*)Ppart + (size_t)blockIdx.x * 4096;
#pragma unroll
    for (int i = 0; i < 16; ++i) Pp[i * 256 + t] = acc[i];
}

// ============ split-bf16 3-pass MFMA GEMM: C = A[M,512] @ W[512,512] + bias ============
template <bool TOUT>
__global__ __launch_bounds__(256, 2) void gemm_split(const float* __restrict__ A,
                                                     const u16* __restrict__ Bhi,
                                                     const u16* __restrict__ Blo,
                                                     const float* __restrict__ bias,
                                                     float* __restrict__ C) {
    __shared__ u16 sAhi[128 * 64];
    __shared__ u16 sAlo[128 * 64];
    __shared__ u16 sBhi[128 * 64];
    __shared__ u16 sBlo[128 * 64];

    const int tid = threadIdx.x;
    const int lin = blockIdx.x;
    const int t = (lin & 7) * 128 + (lin >> 3);
    const int bm = (t >> 2) * 128;
    const int bn = (t & 3) * 128;

    const int lane = tid & 63, wid = tid >> 6;
    const int wm = wid >> 1, wn = wid & 1;
    const int l15 = lane & 15, kg = lane >> 4;

    f32x4 acc[4][4] = {};

    for (int k0 = 0; k0 < 512; k0 += 64) {
        __syncthreads();
        // ---- stage A: fp32 -> hi/lo bf16 via v_perm packing ----
#pragma unroll
        for (int it = 0; it < 4; ++it) {
            const int ch = it * 256 + tid;
            const int row = ch >> 3, c = ch & 7;
            const float* ga = A + (size_t)(bm + row) * 512 + k0 + c * 8;
            float4 f0 = *(const float4*)ga;
            float4 f1 = *(const float4*)(ga + 4);
            float fs[8] = {f0.x, f0.y, f0.z, f0.w, f1.x, f1.y, f1.z, f1.w};
            u32 h[4], l[4];
#pragma unroll
            for (int p = 0; p < 4; ++p) {
                u32 u0 = __float_as_uint(fs[2 * p]);
                u32 u1 = __float_as_uint(fs[2 * p + 1]);
                h[p] = __builtin_amdgcn_perm(u1, u0, 0x07060302u);
                float r0 = fs[2 * p]     - __uint_as_float(u0 & 0xFFFF0000u);
                float r1 = fs[2 * p + 1] - __uint_as_float(u1 & 0xFFFF0000u);
                l[p] = __builtin_amdgcn_perm(__float_as_uint(r1), __float_as_uint(r0), 0x07060302u);
            }
            const int off = row * 64 + ((c ^ (row & 7)) << 3);
            *(uint4*)&sAhi[off] = make_uint4(h[0], h[1], h[2], h[3]);
            *(uint4*)&sAlo[off] = make_uint4(l[0], l[1], l[2], l[3]);
        }
        // ---- stage B (pre-split bf16) ----
#pragma unroll
        for (int it = 0; it < 4; ++it) {
            const int ch = it * 256 + tid;
            const int row = ch >> 3, c = ch & 7;
            const int off = row * 64 + ((c ^ (row & 7)) << 3);
            const size_t gg = (size_t)(bn + row) * 512 + k0 + c * 8;
            *(u16x8*)&sBhi[off] = *(const u16x8*)&Bhi[gg];
            *(u16x8*)&sBlo[off] = *(const u16x8*)&Blo[gg];
        }
        __syncthreads();
#pragma unroll
        for (int kk = 0; kk < 2; ++kk) {
            const int cbase = kk * 4 + kg;
            s16x8 ah[4], al[4], bh[4], bl[4];
#pragma unroll
            for (int mi = 0; mi < 4; ++mi) {
                const int row = wm * 64 + mi * 16 + l15;
                const int off = row * 64 + (((cbase ^ (row & 7))) << 3);
                ah[mi] = *(const s16x8*)&sAhi[off];
                al[mi] = *(const s16x8*)&sAlo[off];
            }
#pragma unroll
            for (int ni = 0; ni < 4; ++ni) {
                const int row = wn * 64 + ni * 16 + l15;
                const int off = row * 64 + (((cbase ^ (row & 7))) << 3);
                bh[ni] = *(const s16x8*)&sBhi[off];
                bl[ni] = *(const s16x8*)&sBlo[off];
            }
#pragma unroll
            for (int ni = 0; ni < 4; ++ni)
#pragma unroll
                for (int mi = 0; mi < 4; ++mi) {
                    acc[mi][ni] = __builtin_amdgcn_mfma_f32_16x16x32_bf16(ah[mi], bh[ni], acc[mi][ni], 0, 0, 0);
                    acc[mi][ni] = __builtin_amdgcn_mfma_f32_16x16x32_bf16(ah[mi], bl[ni], acc[mi][ni], 0, 0, 0);
                    acc[mi][ni] = __builtin_amdgcn_mfma_f32_16x16x32_bf16(al[mi], bh[ni], acc[mi][ni], 0, 0, 0);
                }
        }
    }
    if constexpr (TOUT) {
#pragma unroll
        for (int ni = 0; ni < 4; ++ni) {
            const int d = bn + wn * 64 + ni * 16 + l15;
            const float bv = bias[d];
#pragma unroll
            for (int mi = 0; mi < 4; ++mi) {
                const int rb = bm + wm * 64 + mi * 16 + (kg << 2);
                float4 o;
                o.x = acc[mi][ni][0] + bv; o.y = acc[mi][ni][1] + bv;
                o.z = acc[mi][ni][2] + bv; o.w = acc[mi][ni][3] + bv;
                *(float4*)&C[(size_t)d * ML + rb] = o;
            }
        }
    } else {
#pragma unroll
        for (int ni = 0; ni < 4; ++ni) {
            const int col = bn + wn * 64 + ni * 16 + l15;
            const float bv = bias[col];
#pragma unroll
            for (int mi = 0; mi < 4; ++mi) {
                const int rb = bm + wm * 64 + mi * 16 + (kg << 2);
#pragma unroll
                for (int r = 0; r < 4; ++r)
                    C[(size_t)(rb + r) * 512 + col] = acc[mi][ni][r] + bv;
            }
        }
    }
}

// ============ tiny fp32 GEMM (512^3): Wc = Wv @ Wo ============
__global__ __launch_bounds__(256) void gemm_plain512(const float* __restrict__ A,
                                                     const float* __restrict__ W,
                                                     float* __restrict__ C) {
    __shared__ float As[16][64];
    __shared__ float Ws[16][64];
    const int tid = threadIdx.x;
    const int tx = tid & 15, ty = tid >> 4;
    const int bm = blockIdx.y * 64, bn = blockIdx.x * 64;
    float acc[4][4] = {};
    const int arow = tid >> 2, ak4 = tid & 3;
    const int wrow = tid >> 4, wc4 = tid & 15;
    for (int k0 = 0; k0 < 512; k0 += 16) {
        float4 av = *(const float4*)&A[(size_t)(bm + arow) * 512 + k0 + ak4 * 4];
        float4 wv = *(const float4*)&W[(size_t)(k0 + wrow) * 512 + bn + wc4 * 4];
        __syncthreads();
        As[ak4 * 4 + 0][arow] = av.x;
        As[ak4 * 4 + 1][arow] = av.y;
        As[ak4 * 4 + 2][arow] = av.z;
        As[ak4 * 4 + 3][arow] = av.w;
        *(float4*)&Ws[wrow][wc4 * 4] = wv;
        __syncthreads();
#pragma unroll
        for (int k = 0; k < 16; ++k) {
            float4 a = *(const float4*)&As[k][ty * 4];
            float4 b = *(const float4*)&Ws[k][tx * 4];
            acc[0][0] += a.x * b.x; acc[0][1] += a.x * b.y; acc[0][2] += a.x * b.z; acc[0][3] += a.x * b.w;
            acc[1][0] += a.y * b.x; acc[1][1] += a.y * b.y; acc[1][2] += a.y * b.z; acc[1][3] += a.y * b.w;
            acc[2][0] += a.z * b.x; acc[2][1] += a.z * b.y; acc[2][2] += a.z * b.z; acc[2][3] += a.z * b.w;
            acc[3][0] += a.w * b.x; acc[3][1] += a.w * b.y; acc[3][2] += a.w * b.z; acc[3][3] += a.w * b.w;
        }
    }
#pragma unroll
    for (int i = 0; i < 4; ++i) {
        float4 o;
        o.x = acc[i][0]; o.y = acc[i][1]; o.z = acc[i][2]; o.w = acc[i][3];
        *(float4*)&C[(size_t)(bm + ty * 4 + i) * 512 + bn + tx * 4] = o;
    }
}

__global__ __launch_bounds__(256) void bc_kernel(const float* __restrict__ bv,
                                                 const float* __restrict__ Wo,
                                                 const float* __restrict__ bo,
                                                 float* __restrict__ bc) {
    const int n = blockIdx.x * 256 + threadIdx.x;
    if (n < 512) {
        float s = bo[n];
        for (int j = 0; j < 512; ++j) s += bv[j] * Wo[(size_t)j * 512 + n];
        bc[n] = s;
    }
}

__global__ __launch_bounds__(256) void prep_split(const float* __restrict__ Wq,
                                                  const float* __restrict__ Wk,
                                                  const float* __restrict__ Wc,
                                                  u16* __restrict__ Wqh, u16* __restrict__ Wql,
                                                  u16* __restrict__ Wkh, u16* __restrict__ Wkl,
                                                  u16* __restrict__ Wch, u16* __restrict__ Wcl) {
    const int n = blockIdx.x;
    const int which = blockIdx.y;
    const float* src = (which == 0) ? Wq : (which == 1) ? Wk : Wc;
    u16* dh = (which == 0) ? Wqh : (which == 1) ? Wkh : Wch;
    u16* dl = (which == 0) ? Wql : (which == 1) ? Wkl : Wcl;
    for (int k = threadIdx.x; k < 512; k += 256) {
        float f = src[(size_t)k * 512 + n];
        u32 u = __float_as_uint(f);
        u16 h = (u16)(u >> 16);
        float rem = f - __uint_as_float(u & 0xFFFF0000u);
        u32 ur = __float_as_uint(rem);
        u16 l = (u16)((ur + 0x7FFF + ((ur >> 16) & 1)) >> 16);
        dh[(size_t)n * 512 + k] = h;
        dl[(size_t)n * 512 + k] = l;
    }
}

// ============ radix-2 in-LDS FFT (kept for ifft_mean: only 8 blocks, not hot) ============
__device__ __forceinline__ void fft4096_lds_tw(float2* buf, const float2* tw, int tid) {
    for (int s = 0; s < 12; ++s) {
        const int half = 1 << s;
        const int tsh = 11 - s;
#pragma unroll 8
        for (int u = tid; u < 2048; u += 256) {
            int pos = u & (half - 1);
            int i0 = ((u >> s) << (s + 1)) + pos;
            int i1 = i0 + half;
            float2 w = tw[pos << tsh];
            float2 x0 = buf[i0], x1 = buf[i1];
            float tr = w.x * x1.x - w.y * x1.y;
            float ti = w.x * x1.y + w.y * x1.x;
            buf[i0] = make_float2(x0.x + tr, x0.y + ti);
            buf[i1] = make_float2(x0.x - tr, x0.y - ti);
        }
        __syncthreads();
    }
}

__device__ __forceinline__ void init_twiddle(float2* tw, int tid) {
    for (int k = tid; k < 2048; k += 256) {
        float s, c;
        __sincosf(-3.14159265358979f * (float)k / 2048.0f, &s, &c);
        tw[k] = make_float2(c, s);
    }
}

__global__ __launch_bounds__(256) void reduce_ppart(const float2* __restrict__ Pp,
                                                    float2* __restrict__ Pred) {
    const int i = blockIdx.x * 256 + threadIdx.x;
    const int b = i >> 12, j = i & 4095;
    float sr = 0.f, si = 0.f;
    const float2* base = Pp + (size_t)b * NGRP * 4096 + j;
    for (int g = 0; g < NGRP; ++g) {
        float2 p = base[(size_t)g * 4096];
        sr += p.x;
        si += p.y;
    }
    Pred[i] = make_float2(sr, si);
}

__global__ __launch_bounds__(256) void ifft_mean(const float2* __restrict__ Pred,
                                                 float* __restrict__ mv) {
    __shared__ float2 buf[4096];
    __shared__ float2 tw[2048];
    const int tid = threadIdx.x;
    const int b = blockIdx.x;
    init_twiddle(tw, tid);
    for (int j = tid; j < 4096; j += 256) {
        float2 p = Pred[(size_t)b * 4096 + j];
        buf[__brev(j) >> 20] = make_float2(p.x, -p.y);
    }
    __syncthreads();
    fft4096_lds_tw(buf, tw, tid);
    const float scale = 1.0f / (4096.0f * 512.0f);
    for (int j = tid; j < 4096; j += 256) mv[(size_t)b * 4096 + j] = buf[j].x * scale;
}

__global__ __launch_bounds__(256) void topk_softmax(const float* __restrict__ mv,
                                                    int* __restrict__ idxO,
                                                    float* __restrict__ tcO) {
    __shared__ float vals[4096];
    __shared__ float rv[256];
    __shared__ int ri[256];
    __shared__ int sidx[TOPK];
    const int tid = threadIdx.x;
    for (int j = tid; j < 4096; j += 256) {
        float s = 0.f;
        for (int b = 0; b < BB; ++b) s += mv[(size_t)b * 4096 + j];
        vals[j] = s * 0.125f;
    }
    __syncthreads();
    for (int k = 0; k < TOPK; ++k) {
        float best = -INFINITY;
        int bi = 0x7fffffff;
        for (int j = tid; j < 4096; j += 256) {
            float v = vals[j];
            if (v > best) { best = v; bi = j; }
        }
        rv[tid] = best; ri[tid] = bi;
        __syncthreads();
        for (int off = 128; off > 0; off >>= 1) {
            if (tid < off) {
                float ov = rv[tid + off]; int oi = ri[tid + off];
                if (ov > rv[tid] || (ov == rv[tid] && oi < ri[tid])) { rv[tid] = ov; ri[tid] = oi; }
            }
            __syncthreads();
        }
        if (tid == 0) {
            sidx[k] = ri[0];
            idxO[k] = ri[0];
            vals[ri[0]] = -INFINITY;
        }
        __syncthreads();
    }
    if (tid < BB) {
        float w[TOPK];
        float m = -INFINITY;
        for (int k = 0; k < TOPK; ++k) {
            w[k] = mv[(size_t)tid * 4096 + sidx[k]];
            m = fmaxf(m, w[k]);
        }
        float s = 0.f;
        for (int k = 0; k < TOPK; ++k) { w[k] = expf(w[k] - m); s += w[k]; }
        float inv = 1.0f / s;
        for (int k = 0; k < TOPK; ++k) tcO[tid * TOPK + k] = w[k] * inv;
    }
}

__global__ __launch_bounds__(256) void gather_out(const float* __restrict__ VO,
                                                  const int* __restrict__ idx,
                                                  const float* __restrict__ tc,
                                                  float* __restrict__ out) {
    const int e = blockIdx.x * 256 + threadIdx.x;
    const int d4 = e & 127;
    const int l = (e >> 7) & 4095;
    const int b = e >> 19;
    float4 s = make_float4(0.f, 0.f, 0.f, 0.f);
#pragma unroll
    for (int k = 0; k < TOPK; ++k) {
        int src = (l + idx[k]) & 4095;
        float w = tc[b * TOPK + k];
        float4 v = *(const float4*)&VO[((size_t)b * 4096 + src) * 512 + d4 * 4];
        s.x += w * v.x; s.y += w * v.y; s.z += w * v.z; s.w += w * v.w;
    }
    *(float4*)&out[((size_t)b * 4096 + l) * 512 + d4 * 4] = s;
}

extern "C" void kernel_launch(void* const* d_in, const int* in_sizes, int n_in,
                              void* d_out, int out_size, void* d_ws, size_t ws_size,
                              hipStream_t stream) {
    const float* queries = (const float*)d_in[0];
    const float* keys    = (const float*)d_in[1];
    const float* values  = (const float*)d_in[2];
    const float* Wq = (const float*)d_in[3];
    const float* bq = (const float*)d_in[4];
    const float* Wk = (const float*)d_in[5];
    const float* bk = (const float*)d_in[6];
    const float* Wv = (const float*)d_in[7];
    const float* bv = (const float*)d_in[8];
    const float* Wo = (const float*)d_in[9];
    const float* bo = (const float*)d_in[10];
    float* out = (float*)d_out;

    float* ws = (float*)d_ws;
    const size_t SZ = (size_t)ML * DMODEL;
    float* Qt   = ws;
    float* Kt   = ws + SZ;
    float* Pp   = ws + 2 * SZ;
    float* Pred = Pp + (size_t)BB * NGRP * 4096 * 2;
    float* mv   = Pred + (size_t)BB * 4096 * 2;
    int*   idx  = (int*)(mv + 32768);
    float* tc   = mv + 32768 + 16;
    float* Wc   = mv + 32768 + 96;
    float* bc   = Wc + 262144;
    u16* Wqh = (u16*)(bc + 512);
    u16* Wql = Wqh + 262144;
    u16* Wkh = Wql + 262144;
    u16* Wkl = Wkh + 262144;
    u16* Wch = Wkl + 262144;
    u16* Wcl = Wch + 262144;
    float* VO = Qt;

    dim3 blk(256);

    gemm_plain512<<<dim3(8, 8), blk, 0, stream>>>(Wv, Wo, Wc);
    bc_kernel<<<dim3(2), blk, 0, stream>>>(bv, Wo, bo, bc);
    prep_split<<<dim3(512, 3), blk, 0, stream>>>(Wq, Wk, Wc, Wqh, Wql, Wkh, Wkl, Wch, Wcl);

    gemm_split<true ><<<dim3(1024), blk, 0, stream>>>(queries, Wqh, Wql, bq, Qt);
    gemm_split<true ><<<dim3(1024), blk, 0, stream>>>(keys,    Wkh, Wkl, bk, Kt);

    fft_cross<<<dim3(BB * NGRP), blk, 0, stream>>>(Qt, Kt, Pp);
    reduce_ppart<<<dim3(128), blk, 0, stream>>>((const float2*)Pp, (float2*)Pred);
    ifft_mean<<<dim3(BB), blk, 0, stream>>>((const float2*)Pred, mv);
    topk_softmax<<<dim3(1), blk, 0, stream>>>(mv, idx, tc);

    gemm_split<false><<<dim3(1024), blk, 0, stream>>>(values, Wch, Wcl, bc, VO);

    gather_out<<<dim3((BB * LSEQ * (DMODEL / 4)) / 256), blk, 0, stream>>>(VO, idx, tc, out);
}

// Round 5
// 408.682 us; speedup vs baseline: 4.3380x; 1.0490x over previous
//
#include <hip/hip_runtime.h>
#include <math.h>

#define LSEQ 4096
#define DMODEL 512
#define BB 8
#define TOPK 8
#define ML (BB * LSEQ)          // 32768 rows
#define FFT_CH 4                // channels per fft_cross block
#define NGRP (DMODEL / FFT_CH)  // 128 groups per batch

typedef unsigned short u16;
typedef unsigned int u32;
typedef float f32x4 __attribute__((ext_vector_type(4)));
typedef short s16x8 __attribute__((ext_vector_type(8)));
typedef u16 u16x8 __attribute__((ext_vector_type(8)));

// ==================== 16-pt FFT, fully unrolled DIF (output bit-reversed in regs) ====================
__device__ __forceinline__ void fft16(float (&zr)[16], float (&zi)[16]) {
    const float C1 = 0.92387953251128674f, S1 = 0.38268343236508978f, R2 = 0.70710678118654752f;
#define BF0(i, j) { float ar=zr[i],ai=zi[i],br=zr[j],bi=zi[j]; zr[i]=ar+br; zi[i]=ai+bi; zr[j]=ar-br; zi[j]=ai-bi; }
#define BFW(i, j, wr, wi) { float ar=zr[i],ai=zi[i],br=zr[j],bi=zi[j]; zr[i]=ar+br; zi[i]=ai+bi; float dr=ar-br, di=ai-bi; zr[j]=dr*(wr)-di*(wi); zi[j]=dr*(wi)+di*(wr); }
#define BFI(i, j) { float ar=zr[i],ai=zi[i],br=zr[j],bi=zi[j]; zr[i]=ar+br; zi[i]=ai+bi; float dr=ar-br, di=ai-bi; zr[j]=di; zi[j]=-dr; }
    BF0(0, 8); BFW(1, 9, C1, -S1); BFW(2, 10, R2, -R2); BFW(3, 11, S1, -C1);
    BFI(4, 12); BFW(5, 13, -S1, -C1); BFW(6, 14, -R2, -R2); BFW(7, 15, -C1, -S1);
    BF0(0, 4); BFW(1, 5, R2, -R2); BFI(2, 6); BFW(3, 7, -R2, -R2);
    BF0(8, 12); BFW(9, 13, R2, -R2); BFI(10, 14); BFW(11, 15, -R2, -R2);
    BF0(0, 2); BFI(1, 3); BF0(4, 6); BFI(5, 7);
    BF0(8, 10); BFI(9, 11); BF0(12, 14); BFI(13, 15);
    BF0(0, 1); BF0(2, 3); BF0(4, 5); BF0(6, 7);
    BF0(8, 9); BF0(10, 11); BF0(12, 13); BF0(14, 15);
#undef BF0
#undef BFW
#undef BFI
}

// quarter-wave table: tw[k] = W_4096^k, k<1024. twl reconstructs any e in [0,4096).
__device__ __forceinline__ void init_tw1024(float2* tw, int t) {
    for (int k = t; k < 1024; k += 256) {
        float s, c;
        __sincosf(-1.5707963267948966f * (float)k / 1024.0f, &s, &c);
        tw[k] = make_float2(c, s);
    }
}

__device__ __forceinline__ float2 twl(const float2* tw, int e) {
    int q = (e >> 10) & 3;
    float2 w = tw[e & 1023];
    float rx = (q & 1) ? w.y : w.x;
    float ry = (q & 1) ? -w.x : w.y;
    if (q & 2) { rx = -rx; ry = -ry; }
    return make_float2(rx, ry);
}

// 3-level radix-16 4096-pt FFT core. Input: staged in phys-swizzled LDS layout
// phys(n) = n ^ (((n>>8)&3)<<2) ^ (((n>>8)&1)<<4)  (swizzle keeps float4 blocks intact).
// Output: natural order in lre/lim, synced.
__device__ __forceinline__ void fft4096_r16_core(float* __restrict__ lre, float* __restrict__ lim,
                                                 const float2* __restrict__ tw, int t) {
    constexpr int REV16[16] = {0, 8, 4, 12, 2, 10, 6, 14, 1, 9, 5, 13, 3, 11, 7, 15};
    float zr[16], zi[16];
    // level A: DFT16 over n0 (stride 256), twiddle W_256^{n1*k0}
#pragma unroll
    for (int gg = 0; gg < 16; ++gg) {
        int n = 256 * gg + t;
        int p = n ^ ((gg & 3) << 2) ^ ((gg & 1) << 4);
        zr[gg] = lre[p]; zi[gg] = lim[p];
    }
    fft16(zr, zi);
    {
        const int n1 = t >> 4;
#pragma unroll
        for (int r = 0; r < 16; ++r) {
            const int k0 = REV16[r];
            float vr = zr[r], vi = zi[r];
            if (k0 != 0) {
                float2 w = twl(tw, (16 * k0) * n1);
                float nr = vr * w.x - vi * w.y;
                vi = vr * w.y + vi * w.x;
                vr = nr;
            }
            int n = 256 * k0 + t;
            int p = n ^ ((k0 & 3) << 2) ^ ((k0 & 1) << 4);
            lre[p] = vr; lim[p] = vi;
        }
    }
    __syncthreads();
    // level B: DFT16 over n1 (stride 16), twiddle W_4096^{n2*(k0+16k1)}
    {
        const int k0 = t >> 4, n2 = t & 15;
        const int x0 = ((k0 & 3) << 2) | ((k0 & 1) << 4);
#pragma unroll
        for (int gg = 0; gg < 16; ++gg) {
            int n = 256 * k0 + 16 * gg + n2;
            zr[gg] = lre[n ^ x0]; zi[gg] = lim[n ^ x0];
        }
        fft16(zr, zi);
#pragma unroll
        for (int r = 0; r < 16; ++r) {
            const int k1 = REV16[r];
            float2 w = twl(tw, n2 * (k0 + 16 * k1));
            float vr = zr[r] * w.x - zi[r] * w.y;
            float vi = zr[r] * w.y + zi[r] * w.x;
            int n = 256 * k0 + 16 * k1 + n2;
            lre[n ^ x0] = vr; lim[n ^ x0] = vi;
        }
    }
    __syncthreads();
    // level C: DFT16 over n2 (stride 1, b128 reads); output natural order
    {
        const int k0 = t & 15, k1 = t >> 4;
        const int nb4 = 64 * k0 + 4 * k1;
        const int xv = (k0 & 3) | ((k0 & 1) << 2);
#pragma unroll
        for (int i = 0; i < 4; ++i) {
            int p4 = (nb4 + i) ^ xv;
            float4 fr = *(const float4*)&lre[4 * p4];
            float4 fi = *(const float4*)&lim[4 * p4];
            zr[4 * i + 0] = fr.x; zr[4 * i + 1] = fr.y; zr[4 * i + 2] = fr.z; zr[4 * i + 3] = fr.w;
            zi[4 * i + 0] = fi.x; zi[4 * i + 1] = fi.y; zi[4 * i + 2] = fi.z; zi[4 * i + 3] = fi.w;
        }
        fft16(zr, zi);
        __syncthreads();  // all phys reads done before natural overwrite
#pragma unroll
        for (int r = 0; r < 16; ++r) {
            const int k2 = REV16[r];
            lre[t + 256 * k2] = zr[r];
            lim[t + 256 * k2] = zi[r];
        }
    }
    __syncthreads();
}

// grid: BB*NGRP blocks; block (b,g) handles channels d = g*FFT_CH..+3.
// Qt = (queries @ WqWk^T)^T, Kt = keys^T, both [d][b*4096+l].
__global__ __launch_bounds__(256) void fft_cross(const float* __restrict__ Qt,
                                                 const float* __restrict__ Kt,
                                                 float* __restrict__ Ppart) {
    __shared__ float lre[4096];
    __shared__ float lim[4096];
    __shared__ float2 tw[1024];
    const int t = threadIdx.x;
    const int b = blockIdx.x / NGRP;
    const int g = blockIdx.x % NGRP;

    init_tw1024(tw, t);

    float2 acc[16];
#pragma unroll
    for (int i = 0; i < 16; ++i) acc[i] = make_float2(0.f, 0.f);

    const float4* q4 = (const float4*)(Qt + (size_t)(g * FFT_CH) * ML + (size_t)b * LSEQ);
    const float4* k4 = (const float4*)(Kt + (size_t)(g * FFT_CH) * ML + (size_t)b * LSEQ);

    float4 pq[4], pk[4];
#pragma unroll
    for (int i = 0; i < 4; ++i) {
        pq[i] = q4[t + 256 * i];
        pk[i] = k4[t + 256 * i];
    }

    for (int c = 0; c < FFT_CH; ++c) {
        __syncthreads();  // prev channel's cross-reads done; tw ready (1st iter)
#pragma unroll
        for (int i = 0; i < 4; ++i) {
            int v = t + 256 * i;                 // float4-block index (n>>2)
            int key = (v >> 6) & 15;
            int p4 = v ^ (key & 3) ^ ((key & 1) << 2);
            *(float4*)&lre[4 * p4] = pq[i];
            *(float4*)&lim[4 * p4] = pk[i];
        }
        if (c + 1 < FFT_CH) {
            const float4* qn = q4 + (size_t)(c + 1) * (ML >> 2);
            const float4* kn = k4 + (size_t)(c + 1) * (ML >> 2);
#pragma unroll
            for (int i = 0; i < 4; ++i) {
                pq[i] = qn[t + 256 * i];
                pk[i] = kn[t + 256 * i];
            }
        }
        __syncthreads();
        fft4096_r16_core(lre, lim, tw, t);
        // cross-spectrum accumulate: Qf * conj(Kf) from packed z = q + i*k
#pragma unroll
        for (int i = 0; i < 16; ++i) {
            const int j = i * 256 + t;
            const int nj = (4096 - j) & 4095;
            float zfr = lre[j], zfi = lim[j];
            float znr = lre[nj], zni = lim[nj];
            float qr = 0.5f * (zfr + znr);
            float qi = 0.5f * (zfi - zni);
            float kr = 0.5f * (zfi + zni);
            float ki = -0.5f * (zfr - znr);
            acc[i].x += qr * kr + qi * ki;
            acc[i].y += qi * kr - qr * ki;
        }
    }
    float2* Pp = (float2*)Ppart + (size_t)blockIdx.x * 4096;
#pragma unroll
    for (int i = 0; i < 16; ++i) Pp[i * 256 + t] = acc[i];
}

// ============ split-bf16 MFMA GEMM: C = A[M,512] @ W[512,512] (+ bias) ============
// PASSES=3: hi*hi + hi*lo + lo*hi (fp32-class, for the top-k path)
// PASSES=1: RNE-bf16 single pass (V path)
template <bool TOUT, int PASSES, bool BIAS>
__global__ __launch_bounds__(256, 2) void gemm_split(const float* __restrict__ A,
                                                     const u16* __restrict__ Bhi,
                                                     const u16* __restrict__ Blo,
                                                     const float* __restrict__ bias,
                                                     float* __restrict__ C) {
    __shared__ u16 sAhi[128 * 64];
    __shared__ u16 sAlo[PASSES == 3 ? 128 * 64 : 64];
    __shared__ u16 sBhi[128 * 64];
    __shared__ u16 sBlo[PASSES == 3 ? 128 * 64 : 64];

    const int tid = threadIdx.x;
    const int lin = blockIdx.x;
    const int t = (lin & 7) * 128 + (lin >> 3);
    const int bm = (t >> 2) * 128;
    const int bn = (t & 3) * 128;

    const int lane = tid & 63, wid = tid >> 6;
    const int wm = wid >> 1, wn = wid & 1;
    const int l15 = lane & 15, kg = lane >> 4;

    f32x4 acc[4][4] = {};

    for (int k0 = 0; k0 < 512; k0 += 64) {
        __syncthreads();
        // ---- stage A: fp32 -> bf16 (split or RNE) with v_perm packing ----
#pragma unroll
        for (int it = 0; it < 4; ++it) {
            const int ch = it * 256 + tid;
            const int row = ch >> 3, c = ch & 7;
            const float* ga = A + (size_t)(bm + row) * 512 + k0 + c * 8;
            float4 f0 = *(const float4*)ga;
            float4 f1 = *(const float4*)(ga + 4);
            float fs[8] = {f0.x, f0.y, f0.z, f0.w, f1.x, f1.y, f1.z, f1.w};
            u32 h[4], l[4];
#pragma unroll
            for (int p = 0; p < 4; ++p) {
                u32 u0 = __float_as_uint(fs[2 * p]);
                u32 u1 = __float_as_uint(fs[2 * p + 1]);
                if constexpr (PASSES == 3) {
                    h[p] = __builtin_amdgcn_perm(u1, u0, 0x07060302u);
                    float r0 = fs[2 * p]     - __uint_as_float(u0 & 0xFFFF0000u);
                    float r1 = fs[2 * p + 1] - __uint_as_float(u1 & 0xFFFF0000u);
                    l[p] = __builtin_amdgcn_perm(__float_as_uint(r1), __float_as_uint(r0), 0x07060302u);
                } else {
                    u32 h0 = u0 + 0x7FFF + ((u0 >> 16) & 1);
                    u32 h1 = u1 + 0x7FFF + ((u1 >> 16) & 1);
                    h[p] = __builtin_amdgcn_perm(h1, h0, 0x07060302u);
                }
            }
            const int off = row * 64 + ((c ^ (row & 7)) << 3);
            *(uint4*)&sAhi[off] = make_uint4(h[0], h[1], h[2], h[3]);
            if constexpr (PASSES == 3) *(uint4*)&sAlo[off] = make_uint4(l[0], l[1], l[2], l[3]);
        }
        // ---- stage B (pre-split bf16) ----
#pragma unroll
        for (int it = 0; it < 4; ++it) {
            const int ch = it * 256 + tid;
            const int row = ch >> 3, c = ch & 7;
            const int off = row * 64 + ((c ^ (row & 7)) << 3);
            const size_t gg = (size_t)(bn + row) * 512 + k0 + c * 8;
            *(u16x8*)&sBhi[off] = *(const u16x8*)&Bhi[gg];
            if constexpr (PASSES == 3) *(u16x8*)&sBlo[off] = *(const u16x8*)&Blo[gg];
        }
        __syncthreads();
#pragma unroll
        for (int kk = 0; kk < 2; ++kk) {
            const int cbase = kk * 4 + kg;
            s16x8 ah[4], al[4], bh[4], bl[4];
#pragma unroll
            for (int mi = 0; mi < 4; ++mi) {
                const int row = wm * 64 + mi * 16 + l15;
                const int off = row * 64 + (((cbase ^ (row & 7))) << 3);
                ah[mi] = *(const s16x8*)&sAhi[off];
                if constexpr (PASSES == 3) al[mi] = *(const s16x8*)&sAlo[off];
            }
#pragma unroll
            for (int ni = 0; ni < 4; ++ni) {
                const int row = wn * 64 + ni * 16 + l15;
                const int off = row * 64 + (((cbase ^ (row & 7))) << 3);
                bh[ni] = *(const s16x8*)&sBhi[off];
                if constexpr (PASSES == 3) bl[ni] = *(const s16x8*)&sBlo[off];
            }
#pragma unroll
            for (int ni = 0; ni < 4; ++ni)
#pragma unroll
                for (int mi = 0; mi < 4; ++mi) {
                    acc[mi][ni] = __builtin_amdgcn_mfma_f32_16x16x32_bf16(ah[mi], bh[ni], acc[mi][ni], 0, 0, 0);
                    if constexpr (PASSES == 3) {
                        acc[mi][ni] = __builtin_amdgcn_mfma_f32_16x16x32_bf16(ah[mi], bl[ni], acc[mi][ni], 0, 0, 0);
                        acc[mi][ni] = __builtin_amdgcn_mfma_f32_16x16x32_bf16(al[mi], bh[ni], acc[mi][ni], 0, 0, 0);
                    }
                }
        }
    }
    // ---- epilogue (C/D layout: col = lane&15, row = (lane>>4)*4 + reg) ----
    if constexpr (TOUT) {
#pragma unroll
        for (int ni = 0; ni < 4; ++ni) {
            const int d = bn + wn * 64 + ni * 16 + l15;
            const float bv = BIAS ? bias[d] : 0.0f;
#pragma unroll
            for (int mi = 0; mi < 4; ++mi) {
                const int rb = bm + wm * 64 + mi * 16 + (kg << 2);
                float4 o;
                o.x = acc[mi][ni][0] + bv; o.y = acc[mi][ni][1] + bv;
                o.z = acc[mi][ni][2] + bv; o.w = acc[mi][ni][3] + bv;
                *(float4*)&C[(size_t)d * ML + rb] = o;
            }
        }
    } else {
#pragma unroll
        for (int ni = 0; ni < 4; ++ni) {
            const int col = bn + wn * 64 + ni * 16 + l15;
            const float bv = BIAS ? bias[col] : 0.0f;
#pragma unroll
            for (int mi = 0; mi < 4; ++mi) {
                const int rb = bm + wm * 64 + mi * 16 + (kg << 2);
#pragma unroll
                for (int r = 0; r < 4; ++r)
                    C[(size_t)(rb + r) * 512 + col] = acc[mi][ni][r] + bv;
            }
        }
    }
}

// ============ tiny fp32 GEMMs (512^3) ============
__global__ __launch_bounds__(256) void gemm_plain512(const float* __restrict__ A,
                                                     const float* __restrict__ W,
                                                     float* __restrict__ C) {
    __shared__ float As[16][64];
    __shared__ float Ws[16][64];
    const int tid = threadIdx.x;
    const int tx = tid & 15, ty = tid >> 4;
    const int bm = blockIdx.y * 64, bn = blockIdx.x * 64;
    float acc[4][4] = {};
    const int arow = tid >> 2, ak4 = tid & 3;
    const int wrow = tid >> 4, wc4 = tid & 15;
    for (int k0 = 0; k0 < 512; k0 += 16) {
        float4 av = *(const float4*)&A[(size_t)(bm + arow) * 512 + k0 + ak4 * 4];
        float4 wv = *(const float4*)&W[(size_t)(k0 + wrow) * 512 + bn + wc4 * 4];
        __syncthreads();
        As[ak4 * 4 + 0][arow] = av.x;
        As[ak4 * 4 + 1][arow] = av.y;
        As[ak4 * 4 + 2][arow] = av.z;
        As[ak4 * 4 + 3][arow] = av.w;
        *(float4*)&Ws[wrow][wc4 * 4] = wv;
        __syncthreads();
#pragma unroll
        for (int k = 0; k < 16; ++k) {
            float4 a = *(const float4*)&As[k][ty * 4];
            float4 b = *(const float4*)&Ws[k][tx * 4];
            acc[0][0] += a.x * b.x; acc[0][1] += a.x * b.y; acc[0][2] += a.x * b.z; acc[0][3] += a.x * b.w;
            acc[1][0] += a.y * b.x; acc[1][1] += a.y * b.y; acc[1][2] += a.y * b.z; acc[1][3] += a.y * b.w;
            acc[2][0] += a.z * b.x; acc[2][1] += a.z * b.y; acc[2][2] += a.z * b.z; acc[2][3] += a.z * b.w;
            acc[3][0] += a.w * b.x; acc[3][1] += a.w * b.y; acc[3][2] += a.w * b.z; acc[3][3] += a.w * b.w;
        }
    }
#pragma unroll
    for (int i = 0; i < 4; ++i) {
        float4 o;
        o.x = acc[i][0]; o.y = acc[i][1]; o.z = acc[i][2]; o.w = acc[i][3];
        *(float4*)&C[(size_t)(bm + ty * 4 + i) * 512 + bn + tx * 4] = o;
    }
}

// C = A @ B^T (for M = Wq @ Wk^T)
__global__ __launch_bounds__(256) void gemm_plain512_bt(const float* __restrict__ A,
                                                        const float* __restrict__ B,
                                                        float* __restrict__ C) {
    __shared__ float As[16][64];
    __shared__ float Ws[16][64];
    const int tid = threadIdx.x;
    const int tx = tid & 15, ty = tid >> 4;
    const int bm = blockIdx.y * 64, bn = blockIdx.x * 64;
    float acc[4][4] = {};
    const int arow = tid >> 2, ak4 = tid & 3;
    for (int k0 = 0; k0 < 512; k0 += 16) {
        float4 av = *(const float4*)&A[(size_t)(bm + arow) * 512 + k0 + ak4 * 4];
        float4 bv = *(const float4*)&B[(size_t)(bn + arow) * 512 + k0 + ak4 * 4];
        __syncthreads();
        As[ak4 * 4 + 0][arow] = av.x;
        As[ak4 * 4 + 1][arow] = av.y;
        As[ak4 * 4 + 2][arow] = av.z;
        As[ak4 * 4 + 3][arow] = av.w;
        Ws[ak4 * 4 + 0][arow] = bv.x;
        Ws[ak4 * 4 + 1][arow] = bv.y;
        Ws[ak4 * 4 + 2][arow] = bv.z;
        Ws[ak4 * 4 + 3][arow] = bv.w;
        __syncthreads();
#pragma unroll
        for (int k = 0; k < 16; ++k) {
            float4 a = *(const float4*)&As[k][ty * 4];
            float4 b = *(const float4*)&Ws[k][tx * 4];
            acc[0][0] += a.x * b.x; acc[0][1] += a.x * b.y; acc[0][2] += a.x * b.z; acc[0][3] += a.x * b.w;
            acc[1][0] += a.y * b.x; acc[1][1] += a.y * b.y; acc[1][2] += a.y * b.z; acc[1][3] += a.y * b.w;
            acc[2][0] += a.z * b.x; acc[2][1] += a.z * b.y; acc[2][2] += a.z * b.z; acc[2][3] += a.z * b.w;
            acc[3][0] += a.w * b.x; acc[3][1] += a.w * b.y; acc[3][2] += a.w * b.z; acc[3][3] += a.w * b.w;
        }
    }
#pragma unroll
    for (int i = 0; i < 4; ++i) {
        float4 o;
        o.x = acc[i][0]; o.y = acc[i][1]; o.z = acc[i][2]; o.w = acc[i][3];
        *(float4*)&C[(size_t)(bm + ty * 4 + i) * 512 + bn + tx * 4] = o;
    }
}

__global__ __launch_bounds__(256) void bc_kernel(const float* __restrict__ bv,
                                                 const float* __restrict__ Wo,
                                                 const float* __restrict__ bo,
                                                 float* __restrict__ bc) {
    const int n = blockIdx.x * 256 + threadIdx.x;
    if (n < 512) {
        float s = bo[n];
        for (int j = 0; j < 512; ++j) s += bv[j] * Wo[(size_t)j * 512 + n];
        bc[n] = s;
    }
}

// transpose + hi/lo split: src [K][N] -> dh/dl [N][K] bf16 bits (M and Wc)
__global__ __launch_bounds__(256) void prep_split(const float* __restrict__ M,
                                                  const float* __restrict__ Wc,
                                                  u16* __restrict__ Mh, u16* __restrict__ Ml,
                                                  u16* __restrict__ Wch, u16* __restrict__ Wcl) {
    const int n = blockIdx.x;
    const int which = blockIdx.y;
    const float* src = (which == 0) ? M : Wc;
    u16* dh = (which == 0) ? Mh : Wch;
    u16* dl = (which == 0) ? Ml : Wcl;
    for (int k = threadIdx.x; k < 512; k += 256) {
        float f = src[(size_t)k * 512 + n];
        u32 u = __float_as_uint(f);
        u16 h = (u16)(u >> 16);
        float rem = f - __uint_as_float(u & 0xFFFF0000u);
        u32 ur = __float_as_uint(rem);
        u16 l = (u16)((ur + 0x7FFF + ((ur >> 16) & 1)) >> 16);
        dh[(size_t)n * 512 + k] = h;
        dl[(size_t)n * 512 + k] = l;
    }
}

// keys [ML][512] -> Kt [512][ML]
__global__ __launch_bounds__(256) void transpose_to_dt(const float* __restrict__ X,
                                                       float* __restrict__ XT) {
    __shared__ float Ts[64][65];
    const int bd = blockIdx.x * 64;
    const int bm = blockIdx.y * 64;
    const int t = threadIdx.x;
    const int r = t >> 2, c4 = t & 3;
#pragma unroll
    for (int i = 0; i < 4; ++i) {
        const int c0 = (c4 + 4 * i) * 4;
        float4 v = *(const float4*)&X[(size_t)(bm + r) * DMODEL + bd + c0];
        Ts[r][c0 + 0] = v.x; Ts[r][c0 + 1] = v.y; Ts[r][c0 + 2] = v.z; Ts[r][c0 + 3] = v.w;
    }
    __syncthreads();
    const int dl = t >> 2, m4 = t & 3;
#pragma unroll
    for (int i = 0; i < 4; ++i) {
        const int m0 = (m4 + 4 * i) * 4;
        float4 o;
        o.x = Ts[m0 + 0][dl]; o.y = Ts[m0 + 1][dl]; o.z = Ts[m0 + 2][dl]; o.w = Ts[m0 + 3][dl];
        *(float4*)&XT[(size_t)(bd + dl) * ML + bm + m0] = o;
    }
}

__global__ __launch_bounds__(256) void reduce_ppart(const float2* __restrict__ Pp,
                                                    float2* __restrict__ Pred) {
    const int i = blockIdx.x * 256 + threadIdx.x;
    const int b = i >> 12, j = i & 4095;
    float sr = 0.f, si = 0.f;
    const float2* base = Pp + (size_t)b * NGRP * 4096 + j;
    for (int g = 0; g < NGRP; ++g) {
        float2 p = base[(size_t)g * 4096];
        sr += p.x;
        si += p.y;
    }
    Pred[i] = make_float2(sr, si);
}

// 8 blocks: inverse FFT via conj -> forward radix-16 -> Re, scaled
__global__ __launch_bounds__(256) void ifft_mean(const float2* __restrict__ Pred,
                                                 float* __restrict__ mv) {
    __shared__ float lre[4096];
    __shared__ float lim[4096];
    __shared__ float2 tw[1024];
    const int t = threadIdx.x;
    const int b = blockIdx.x;
    init_tw1024(tw, t);
    for (int j = t; j < 4096; j += 256) {
        float2 p = Pred[(size_t)b * 4096 + j];
        int key = (j >> 8) & 15;
        int ph = j ^ ((key & 3) << 2) ^ ((key & 1) << 4);
        lre[ph] = p.x;
        lim[ph] = -p.y;
    }
    __syncthreads();
    fft4096_r16_core(lre, lim, tw, t);
    const float scale = 1.0f / (4096.0f * 512.0f);
    for (int j = t; j < 4096; j += 256) mv[(size_t)b * 4096 + j] = lre[j] * scale;
}

__global__ __launch_bounds__(256) void topk_softmax(const float* __restrict__ mv,
                                                    int* __restrict__ idxO,
                                                    float* __restrict__ tcO) {
    __shared__ float vals[4096];
    __shared__ float rv[256];
    __shared__ int ri[256];
    __shared__ int sidx[TOPK];
    const int tid = threadIdx.x;
    for (int j = tid; j < 4096; j += 256) {
        float s = 0.f;
        for (int b = 0; b < BB; ++b) s += mv[(size_t)b * 4096 + j];
        vals[j] = s * 0.125f;
    }
    __syncthreads();
    for (int k = 0; k < TOPK; ++k) {
        float best = -INFINITY;
        int bi = 0x7fffffff;
        for (int j = tid; j < 4096; j += 256) {
            float v = vals[j];
            if (v > best) { best = v; bi = j; }
        }
        rv[tid] = best; ri[tid] = bi;
        __syncthreads();
        for (int off = 128; off > 0; off >>= 1) {
            if (tid < off) {
                float ov = rv[tid + off]; int oi = ri[tid + off];
                if (ov > rv[tid] || (ov == rv[tid] && oi < ri[tid])) { rv[tid] = ov; ri[tid] = oi; }
            }
            __syncthreads();
        }
        if (tid == 0) {
            sidx[k] = ri[0];
            idxO[k] = ri[0];
            vals[ri[0]] = -INFINITY;
        }
        __syncthreads();
    }
    if (tid < BB) {
        float w[TOPK];
        float m = -INFINITY;
        for (int k = 0; k < TOPK; ++k) {
            w[k] = mv[(size_t)tid * 4096 + sidx[k]];
            m = fmaxf(m, w[k]);
        }
        float s = 0.f;
        for (int k = 0; k < TOPK; ++k) { w[k] = expf(w[k] - m); s += w[k]; }
        float inv = 1.0f / s;
        for (int k = 0; k < TOPK; ++k) tcO[tid * TOPK + k] = w[k] * inv;
    }
}

__global__ __launch_bounds__(256) void gather_out(const float* __restrict__ VO,
                                                  const int* __restrict__ idx,
                                                  const float* __restrict__ tc,
                                                  float* __restrict__ out) {
    const int e = blockIdx.x * 256 + threadIdx.x;
    const int d4 = e & 127;
    const int l = (e >> 7) & 4095;
    const int b = e >> 19;
    float4 s = make_float4(0.f, 0.f, 0.f, 0.f);
#pragma unroll
    for (int k = 0; k < TOPK; ++k) {
        int src = (l + idx[k]) & 4095;
        float w = tc[b * TOPK + k];
        float4 v = *(const float4*)&VO[((size_t)b * 4096 + src) * 512 + d4 * 4];
        s.x += w * v.x; s.y += w * v.y; s.z += w * v.z; s.w += w * v.w;
    }
    *(float4*)&out[((size_t)b * 4096 + l) * 512 + d4 * 4] = s;
}

extern "C" void kernel_launch(void* const* d_in, const int* in_sizes, int n_in,
                              void* d_out, int out_size, void* d_ws, size_t ws_size,
                              hipStream_t stream) {
    const float* queries = (const float*)d_in[0];
    const float* keys    = (const float*)d_in[1];
    const float* values  = (const float*)d_in[2];
    const float* Wq = (const float*)d_in[3];
    const float* Wk = (const float*)d_in[5];
    const float* Wv = (const float*)d_in[7];
    const float* bv = (const float*)d_in[8];
    const float* Wo = (const float*)d_in[9];
    const float* bo = (const float*)d_in[10];
    float* out = (float*)d_out;

    float* ws = (float*)d_ws;
    const size_t SZ = (size_t)ML * DMODEL;           // 16,777,216 floats
    float* Qt    = ws;                                // q''^T [512][ML]; reused as VO
    float* Kt    = ws + SZ;                           // keys^T
    float* Pp    = ws + 2 * SZ;                       // BB*NGRP*4096*2 = 33.5 MB
    float* Pred  = Pp + (size_t)BB * NGRP * 4096 * 2; // 65536 floats
    float* mv    = Pred + (size_t)BB * 4096 * 2;      // 32768
    int*   idx   = (int*)(mv + 32768);                // 16
    float* tc    = mv + 32768 + 16;                   // 64 (pad 96)
    float* Mfull = mv + 32768 + 96;                   // 262144
    float* Wc    = Mfull + 262144;                    // 262144
    float* bc    = Wc + 262144;                       // 512
    u16* Mh  = (u16*)(bc + 512);
    u16* Ml  = Mh + 262144;
    u16* Wch = Ml + 262144;
    u16* Wcl = Wch + 262144;
    float* VO = Qt;

    dim3 blk(256);

    // weight prep: Wc = Wv@Wo, M = Wq@Wk^T, bc = bv@Wo + bo, transpose+split M/Wc
    gemm_plain512<<<dim3(8, 8), blk, 0, stream>>>(Wv, Wo, Wc);
    gemm_plain512_bt<<<dim3(8, 8), blk, 0, stream>>>(Wq, Wk, Mfull);
    bc_kernel<<<dim3(2), blk, 0, stream>>>(bv, Wo, bo, bc);
    prep_split<<<dim3(512, 2), blk, 0, stream>>>(Mfull, Wc, Mh, Ml, Wch, Wcl);

    // q'' = queries @ M (split-bf16 3-pass, transposed out; biases provably cancel)
    gemm_split<true, 3, false><<<dim3(1024), blk, 0, stream>>>(queries, Mh, Ml, nullptr, Qt);
    // keys^T (raw, exact)
    transpose_to_dt<<<dim3(8, 512), blk, 0, stream>>>(keys, Kt);

    // correlation path
    fft_cross<<<dim3(BB * NGRP), blk, 0, stream>>>(Qt, Kt, Pp);
    reduce_ppart<<<dim3(128), blk, 0, stream>>>((const float2*)Pp, (float2*)Pred);
    ifft_mean<<<dim3(BB), blk, 0, stream>>>((const float2*)Pred, mv);
    topk_softmax<<<dim3(1), blk, 0, stream>>>(mv, idx, tc);

    // V path: VO = values @ (Wv Wo) + (bv Wo + bo)  (1-pass RNE bf16)
    gemm_split<false, 1, true><<<dim3(1024), blk, 0, stream>>>(values, Wch, Wcl, bc, VO);

    gather_out<<<dim3((BB * LSEQ * (DMODEL / 4)) / 256), blk, 0, stream>>>(VO, idx, tc, out);
}

// Round 6
// 376.312 us; speedup vs baseline: 4.7112x; 1.0860x over previous
//
#include <hip/hip_runtime.h>
#include <math.h>

#define LSEQ 4096
#define DMODEL 512
#define BB 8
#define TOPK 8
#define ML (BB * LSEQ)          // 32768 rows
#define FFT_CH 4                // channels per fft_cross block
#define NGRP (DMODEL / FFT_CH)  // 128 groups per batch
#define PPH 2052                // float2 stride of half-spectrum (2049 used, padded)

typedef unsigned short u16;
typedef unsigned int u32;
typedef float f32x4 __attribute__((ext_vector_type(4)));
typedef short s16x8 __attribute__((ext_vector_type(8)));
typedef u16 u16x8 __attribute__((ext_vector_type(8)));

// ==================== 16-pt FFT, fully unrolled DIF (output bit-reversed in regs) ====================
__device__ __forceinline__ void fft16(float (&zr)[16], float (&zi)[16]) {
    const float C1 = 0.92387953251128674f, S1 = 0.38268343236508978f, R2 = 0.70710678118654752f;
#define BF0(i, j) { float ar=zr[i],ai=zi[i],br=zr[j],bi=zi[j]; zr[i]=ar+br; zi[i]=ai+bi; zr[j]=ar-br; zi[j]=ai-bi; }
#define BFW(i, j, wr, wi) { float ar=zr[i],ai=zi[i],br=zr[j],bi=zi[j]; zr[i]=ar+br; zi[i]=ai+bi; float dr=ar-br, di=ai-bi; zr[j]=dr*(wr)-di*(wi); zi[j]=dr*(wi)+di*(wr); }
#define BFI(i, j) { float ar=zr[i],ai=zi[i],br=zr[j],bi=zi[j]; zr[i]=ar+br; zi[i]=ai+bi; float dr=ar-br, di=ai-bi; zr[j]=di; zi[j]=-dr; }
    BF0(0, 8); BFW(1, 9, C1, -S1); BFW(2, 10, R2, -R2); BFW(3, 11, S1, -C1);
    BFI(4, 12); BFW(5, 13, -S1, -C1); BFW(6, 14, -R2, -R2); BFW(7, 15, -C1, -S1);
    BF0(0, 4); BFW(1, 5, R2, -R2); BFI(2, 6); BFW(3, 7, -R2, -R2);
    BF0(8, 12); BFW(9, 13, R2, -R2); BFI(10, 14); BFW(11, 15, -R2, -R2);
    BF0(0, 2); BFI(1, 3); BF0(4, 6); BFI(5, 7);
    BF0(8, 10); BFI(9, 11); BF0(12, 14); BFI(13, 15);
    BF0(0, 1); BF0(2, 3); BF0(4, 5); BF0(6, 7);
    BF0(8, 9); BF0(10, 11); BF0(12, 13); BF0(14, 15);
#undef BF0
#undef BFW
#undef BFI
}

// 3-level radix-16 4096-pt FFT core, twiddles via on-the-fly __sincosf (no LDS table).
// Input staged in phys-swizzled layout phys(n) = n ^ (((n>>8)&3)<<2) ^ (((n>>8)&1)<<4);
// output natural order, synced.
__device__ __forceinline__ void fft4096_r16_core(float* __restrict__ lre, float* __restrict__ lim, int t) {
    constexpr int REV16[16] = {0, 8, 4, 12, 2, 10, 6, 14, 1, 9, 5, 13, 3, 11, 7, 15};
    float zr[16], zi[16];
    // level A: DFT16 over n0 (stride 256), twiddle angle -(pi/128)*n1*k0
#pragma unroll
    for (int gg = 0; gg < 16; ++gg) {
        int n = 256 * gg + t;
        int p = n ^ ((gg & 3) << 2) ^ ((gg & 1) << 4);
        zr[gg] = lre[p]; zi[gg] = lim[p];
    }
    fft16(zr, zi);
    {
        const int n1 = t >> 4;
        const float a1 = -0.0245436926061702596f;  // -pi/128
#pragma unroll
        for (int r = 0; r < 16; ++r) {
            const int k0 = REV16[r];
            float vr = zr[r], vi = zi[r];
            if (k0 != 0) {
                float sw, cw;
                __sincosf(a1 * (float)(n1 * k0), &sw, &cw);
                float nr = vr * cw - vi * sw;
                vi = vr * sw + vi * cw;
                vr = nr;
            }
            int n = 256 * k0 + t;
            int p = n ^ ((k0 & 3) << 2) ^ ((k0 & 1) << 4);
            lre[p] = vr; lim[p] = vi;
        }
    }
    __syncthreads();
    // level B: DFT16 over n1 (stride 16), twiddle angle -(pi/2048)*n2*(k0+16k1)
    {
        const int k0 = t >> 4, n2 = t & 15;
        const int x0 = ((k0 & 3) << 2) | ((k0 & 1) << 4);
        const float a2 = -0.00153398078788564123f;  // -pi/2048
#pragma unroll
        for (int gg = 0; gg < 16; ++gg) {
            int n = 256 * k0 + 16 * gg + n2;
            zr[gg] = lre[n ^ x0]; zi[gg] = lim[n ^ x0];
        }
        fft16(zr, zi);
#pragma unroll
        for (int r = 0; r < 16; ++r) {
            const int k1 = REV16[r];
            float sw, cw;
            __sincosf(a2 * (float)(n2 * (k0 + 16 * k1)), &sw, &cw);
            float vr = zr[r] * cw - zi[r] * sw;
            float vi = zr[r] * sw + zi[r] * cw;
            int n = 256 * k0 + 16 * k1 + n2;
            lre[n ^ x0] = vr; lim[n ^ x0] = vi;
        }
    }
    __syncthreads();
    // level C: DFT16 over n2 (stride 1, b128 reads); output natural order
    {
        const int k0 = t & 15, k1 = t >> 4;
        const int nb4 = 64 * k0 + 4 * k1;
        const int xv = (k0 & 3) | ((k0 & 1) << 2);
#pragma unroll
        for (int i = 0; i < 4; ++i) {
            int p4 = (nb4 + i) ^ xv;
            float4 fr = *(const float4*)&lre[4 * p4];
            float4 fi = *(const float4*)&lim[4 * p4];
            zr[4 * i + 0] = fr.x; zr[4 * i + 1] = fr.y; zr[4 * i + 2] = fr.z; zr[4 * i + 3] = fr.w;
            zi[4 * i + 0] = fi.x; zi[4 * i + 1] = fi.y; zi[4 * i + 2] = fi.z; zi[4 * i + 3] = fi.w;
        }
        fft16(zr, zi);
        __syncthreads();  // all phys reads done before natural overwrite
#pragma unroll
        for (int r = 0; r < 16; ++r) {
            const int k2 = REV16[r];
            lre[t + 256 * k2] = zr[r];
            lim[t + 256 * k2] = zi[r];
        }
    }
    __syncthreads();
}

// grid: BB*NGRP blocks; block (b,g): channels d = g*FFT_CH..+3.
// Qt = (queries @ WqWk^T)^T, Kt = keys^T. Output: Hermitian half-spectrum j=0..2048.
__global__ __launch_bounds__(256) void fft_cross(const float* __restrict__ Qt,
                                                 const float* __restrict__ Kt,
                                                 float* __restrict__ Ppart) {
    __shared__ float lre[4096];
    __shared__ float lim[4096];
    const int t = threadIdx.x;
    const int b = blockIdx.x / NGRP;
    const int g = blockIdx.x % NGRP;

    float2 acc[8];
#pragma unroll
    for (int i = 0; i < 8; ++i) acc[i] = make_float2(0.f, 0.f);
    float accn = 0.f;  // Nyquist bin (j=2048), real

    const float4* q4 = (const float4*)(Qt + (size_t)(g * FFT_CH) * ML + (size_t)b * LSEQ);
    const float4* k4 = (const float4*)(Kt + (size_t)(g * FFT_CH) * ML + (size_t)b * LSEQ);

    float4 pq[4], pk[4];
#pragma unroll
    for (int i = 0; i < 4; ++i) {
        pq[i] = q4[t + 256 * i];
        pk[i] = k4[t + 256 * i];
    }

    for (int c = 0; c < FFT_CH; ++c) {
        __syncthreads();  // prev channel's cross-reads done
#pragma unroll
        for (int i = 0; i < 4; ++i) {
            int v = t + 256 * i;                 // float4-block index (n>>2)
            int key = (v >> 6) & 15;
            int p4 = v ^ (key & 3) ^ ((key & 1) << 2);
            *(float4*)&lre[4 * p4] = pq[i];
            *(float4*)&lim[4 * p4] = pk[i];
        }
        if (c + 1 < FFT_CH) {
            const float4* qn = q4 + (size_t)(c + 1) * (ML >> 2);
            const float4* kn = k4 + (size_t)(c + 1) * (ML >> 2);
#pragma unroll
            for (int i = 0; i < 4; ++i) {
                pq[i] = qn[t + 256 * i];
                pk[i] = kn[t + 256 * i];
            }
        }
        __syncthreads();
        fft4096_r16_core(lre, lim, t);
        // cross-spectrum: Qf * conj(Kf) from packed z = q + i*k, lower half only
#pragma unroll
        for (int i = 0; i < 8; ++i) {
            const int j = i * 256 + t;
            const int nj = (4096 - j) & 4095;
            float zfr = lre[j], zfi = lim[j];
            float znr = lre[nj], zni = lim[nj];
            float qr = 0.5f * (zfr + znr);
            float qi = 0.5f * (zfi - zni);
            float kr = 0.5f * (zfi + zni);
            float ki = -0.5f * (zfr - znr);
            acc[i].x += qr * kr + qi * ki;
            acc[i].y += qi * kr - qr * ki;
        }
        if (t == 0) accn += lre[2048] * lim[2048];
    }
    float2* Pp = (float2*)Ppart + (size_t)blockIdx.x * PPH;
#pragma unroll
    for (int i = 0; i < 8; ++i) Pp[i * 256 + t] = acc[i];
    if (t == 0) Pp[2048] = make_float2(accn, 0.f);
}

// ============ split-bf16 MFMA GEMM: C = A[M,512] @ W[512,512] (+ bias) ============
// PASSES=3: hi*hi + hi*lo + lo*hi (fp32-class).  PASSES=1: RNE bf16.
// B16O: pack output to bf16 (u16) instead of fp32.
template <bool TOUT, int PASSES, bool BIAS, bool B16O>
__global__ __launch_bounds__(256, 2) void gemm_split(const float* __restrict__ A,
                                                     const u16* __restrict__ Bhi,
                                                     const u16* __restrict__ Blo,
                                                     const float* __restrict__ bias,
                                                     void* __restrict__ Cv) {
    __shared__ u16 sAhi[128 * 64];
    __shared__ u16 sAlo[PASSES == 3 ? 128 * 64 : 64];
    __shared__ u16 sBhi[128 * 64];
    __shared__ u16 sBlo[PASSES == 3 ? 128 * 64 : 64];

    const int tid = threadIdx.x;
    const int lin = blockIdx.x;
    const int t = (lin & 7) * 128 + (lin >> 3);
    const int bm = (t >> 2) * 128;
    const int bn = (t & 3) * 128;

    const int lane = tid & 63, wid = tid >> 6;
    const int wm = wid >> 1, wn = wid & 1;
    const int l15 = lane & 15, kg = lane >> 4;

    f32x4 acc[4][4] = {};

    for (int k0 = 0; k0 < 512; k0 += 64) {
        __syncthreads();
#pragma unroll
        for (int it = 0; it < 4; ++it) {
            const int ch = it * 256 + tid;
            const int row = ch >> 3, c = ch & 7;
            const float* ga = A + (size_t)(bm + row) * 512 + k0 + c * 8;
            float4 f0 = *(const float4*)ga;
            float4 f1 = *(const float4*)(ga + 4);
            float fs[8] = {f0.x, f0.y, f0.z, f0.w, f1.x, f1.y, f1.z, f1.w};
            u32 h[4], l[4];
#pragma unroll
            for (int p = 0; p < 4; ++p) {
                u32 u0 = __float_as_uint(fs[2 * p]);
                u32 u1 = __float_as_uint(fs[2 * p + 1]);
                if constexpr (PASSES == 3) {
                    h[p] = __builtin_amdgcn_perm(u1, u0, 0x07060302u);
                    float r0 = fs[2 * p]     - __uint_as_float(u0 & 0xFFFF0000u);
                    float r1 = fs[2 * p + 1] - __uint_as_float(u1 & 0xFFFF0000u);
                    l[p] = __builtin_amdgcn_perm(__float_as_uint(r1), __float_as_uint(r0), 0x07060302u);
                } else {
                    u32 h0 = u0 + 0x7FFF + ((u0 >> 16) & 1);
                    u32 h1 = u1 + 0x7FFF + ((u1 >> 16) & 1);
                    h[p] = __builtin_amdgcn_perm(h1, h0, 0x07060302u);
                }
            }
            const int off = row * 64 + ((c ^ (row & 7)) << 3);
            *(uint4*)&sAhi[off] = make_uint4(h[0], h[1], h[2], h[3]);
            if constexpr (PASSES == 3) *(uint4*)&sAlo[off] = make_uint4(l[0], l[1], l[2], l[3]);
        }
#pragma unroll
        for (int it = 0; it < 4; ++it) {
            const int ch = it * 256 + tid;
            const int row = ch >> 3, c = ch & 7;
            const int off = row * 64 + ((c ^ (row & 7)) << 3);
            const size_t gg = (size_t)(bn + row) * 512 + k0 + c * 8;
            *(u16x8*)&sBhi[off] = *(const u16x8*)&Bhi[gg];
            if constexpr (PASSES == 3) *(u16x8*)&sBlo[off] = *(const u16x8*)&Blo[gg];
        }
        __syncthreads();
#pragma unroll
        for (int kk = 0; kk < 2; ++kk) {
            const int cbase = kk * 4 + kg;
            s16x8 ah[4], al[4], bh[4], bl[4];
#pragma unroll
            for (int mi = 0; mi < 4; ++mi) {
                const int row = wm * 64 + mi * 16 + l15;
                const int off = row * 64 + (((cbase ^ (row & 7))) << 3);
                ah[mi] = *(const s16x8*)&sAhi[off];
                if constexpr (PASSES == 3) al[mi] = *(const s16x8*)&sAlo[off];
            }
#pragma unroll
            for (int ni = 0; ni < 4; ++ni) {
                const int row = wn * 64 + ni * 16 + l15;
                const int off = row * 64 + (((cbase ^ (row & 7))) << 3);
                bh[ni] = *(const s16x8*)&sBhi[off];
                if constexpr (PASSES == 3) bl[ni] = *(const s16x8*)&sBlo[off];
            }
#pragma unroll
            for (int ni = 0; ni < 4; ++ni)
#pragma unroll
                for (int mi = 0; mi < 4; ++mi) {
                    acc[mi][ni] = __builtin_amdgcn_mfma_f32_16x16x32_bf16(ah[mi], bh[ni], acc[mi][ni], 0, 0, 0);
                    if constexpr (PASSES == 3) {
                        acc[mi][ni] = __builtin_amdgcn_mfma_f32_16x16x32_bf16(ah[mi], bl[ni], acc[mi][ni], 0, 0, 0);
                        acc[mi][ni] = __builtin_amdgcn_mfma_f32_16x16x32_bf16(al[mi], bh[ni], acc[mi][ni], 0, 0, 0);
                    }
                }
        }
    }
    // epilogue (C/D layout: col = lane&15, row = (lane>>4)*4 + reg)
    if constexpr (TOUT) {
        float* C = (float*)Cv;
#pragma unroll
        for (int ni = 0; ni < 4; ++ni) {
            const int d = bn + wn * 64 + ni * 16 + l15;
            const float bv = BIAS ? bias[d] : 0.0f;
#pragma unroll
            for (int mi = 0; mi < 4; ++mi) {
                const int rb = bm + wm * 64 + mi * 16 + (kg << 2);
                float4 o;
                o.x = acc[mi][ni][0] + bv; o.y = acc[mi][ni][1] + bv;
                o.z = acc[mi][ni][2] + bv; o.w = acc[mi][ni][3] + bv;
                *(float4*)&C[(size_t)d * ML + rb] = o;
            }
        }
    } else {
#pragma unroll
        for (int ni = 0; ni < 4; ++ni) {
            const int col = bn + wn * 64 + ni * 16 + l15;
            const float bv = BIAS ? bias[col] : 0.0f;
#pragma unroll
            for (int mi = 0; mi < 4; ++mi) {
                const int rb = bm + wm * 64 + mi * 16 + (kg << 2);
#pragma unroll
                for (int r = 0; r < 4; ++r) {
                    float f = acc[mi][ni][r] + bv;
                    if constexpr (B16O) {
                        u32 u = __float_as_uint(f);
                        ((u16*)Cv)[(size_t)(rb + r) * 512 + col] = (u16)((u + 0x7FFF + ((u >> 16) & 1)) >> 16);
                    } else {
                        ((float*)Cv)[(size_t)(rb + r) * 512 + col] = f;
                    }
                }
            }
        }
    }
}

// ============ tiny fp32 GEMMs (512^3) ============
__global__ __launch_bounds__(256) void gemm_plain512(const float* __restrict__ A,
                                                     const float* __restrict__ W,
                                                     float* __restrict__ C) {
    __shared__ float As[16][64];
    __shared__ float Ws[16][64];
    const int tid = threadIdx.x;
    const int tx = tid & 15, ty = tid >> 4;
    const int bm = blockIdx.y * 64, bn = blockIdx.x * 64;
    float acc[4][4] = {};
    const int arow = tid >> 2, ak4 = tid & 3;
    const int wrow = tid >> 4, wc4 = tid & 15;
    for (int k0 = 0; k0 < 512; k0 += 16) {
        float4 av = *(const float4*)&A[(size_t)(bm + arow) * 512 + k0 + ak4 * 4];
        float4 wv = *(const float4*)&W[(size_t)(k0 + wrow) * 512 + bn + wc4 * 4];
        __syncthreads();
        As[ak4 * 4 + 0][arow] = av.x;
        As[ak4 * 4 + 1][arow] = av.y;
        As[ak4 * 4 + 2][arow] = av.z;
        As[ak4 * 4 + 3][arow] = av.w;
        *(float4*)&Ws[wrow][wc4 * 4] = wv;
        __syncthreads();
#pragma unroll
        for (int k = 0; k < 16; ++k) {
            float4 a = *(const float4*)&As[k][ty * 4];
            float4 b = *(const float4*)&Ws[k][tx * 4];
            acc[0][0] += a.x * b.x; acc[0][1] += a.x * b.y; acc[0][2] += a.x * b.z; acc[0][3] += a.x * b.w;
            acc[1][0] += a.y * b.x; acc[1][1] += a.y * b.y; acc[1][2] += a.y * b.z; acc[1][3] += a.y * b.w;
            acc[2][0] += a.z * b.x; acc[2][1] += a.z * b.y; acc[2][2] += a.z * b.z; acc[2][3] += a.z * b.w;
            acc[3][0] += a.w * b.x; acc[3][1] += a.w * b.y; acc[3][2] += a.w * b.z; acc[3][3] += a.w * b.w;
        }
    }
#pragma unroll
    for (int i = 0; i < 4; ++i) {
        float4 o;
        o.x = acc[i][0]; o.y = acc[i][1]; o.z = acc[i][2]; o.w = acc[i][3];
        *(float4*)&C[(size_t)(bm + ty * 4 + i) * 512 + bn + tx * 4] = o;
    }
}

// C = A @ B^T (for M = Wq @ Wk^T)
__global__ __launch_bounds__(256) void gemm_plain512_bt(const float* __restrict__ A,
                                                        const float* __restrict__ B,
                                                        float* __restrict__ C) {
    __shared__ float As[16][64];
    __shared__ float Ws[16][64];
    const int tid = threadIdx.x;
    const int tx = tid & 15, ty = tid >> 4;
    const int bm = blockIdx.y * 64, bn = blockIdx.x * 64;
    float acc[4][4] = {};
    const int arow = tid >> 2, ak4 = tid & 3;
    for (int k0 = 0; k0 < 512; k0 += 16) {
        float4 av = *(const float4*)&A[(size_t)(bm + arow) * 512 + k0 + ak4 * 4];
        float4 bv = *(const float4*)&B[(size_t)(bn + arow) * 512 + k0 + ak4 * 4];
        __syncthreads();
        As[ak4 * 4 + 0][arow] = av.x;
        As[ak4 * 4 + 1][arow] = av.y;
        As[ak4 * 4 + 2][arow] = av.z;
        As[ak4 * 4 + 3][arow] = av.w;
        Ws[ak4 * 4 + 0][arow] = bv.x;
        Ws[ak4 * 4 + 1][arow] = bv.y;
        Ws[ak4 * 4 + 2][arow] = bv.z;
        Ws[ak4 * 4 + 3][arow] = bv.w;
        __syncthreads();
#pragma unroll
        for (int k = 0; k < 16; ++k) {
            float4 a = *(const float4*)&As[k][ty * 4];
            float4 b = *(const float4*)&Ws[k][tx * 4];
            acc[0][0] += a.x * b.x; acc[0][1] += a.x * b.y; acc[0][2] += a.x * b.z; acc[0][3] += a.x * b.w;
            acc[1][0] += a.y * b.x; acc[1][1] += a.y * b.y; acc[1][2] += a.y * b.z; acc[1][3] += a.y * b.w;
            acc[2][0] += a.z * b.x; acc[2][1] += a.z * b.y; acc[2][2] += a.z * b.z; acc[2][3] += a.z * b.w;
            acc[3][0] += a.w * b.x; acc[3][1] += a.w * b.y; acc[3][2] += a.w * b.z; acc[3][3] += a.w * b.w;
        }
    }
#pragma unroll
    for (int i = 0; i < 4; ++i) {
        float4 o;
        o.x = acc[i][0]; o.y = acc[i][1]; o.z = acc[i][2]; o.w = acc[i][3];
        *(float4*)&C[(size_t)(bm + ty * 4 + i) * 512 + bn + tx * 4] = o;
    }
}

__global__ __launch_bounds__(256) void bc_kernel(const float* __restrict__ bv,
                                                 const float* __restrict__ Wo,
                                                 const float* __restrict__ bo,
                                                 float* __restrict__ bc) {
    const int n = blockIdx.x * 256 + threadIdx.x;
    if (n < 512) {
        float s = bo[n];
        for (int j = 0; j < 512; ++j) s += bv[j] * Wo[(size_t)j * 512 + n];
        bc[n] = s;
    }
}

// transpose + hi/lo split: src [K][N] -> dh/dl [N][K] bf16 bits (M and Wc)
__global__ __launch_bounds__(256) void prep_split(const float* __restrict__ M,
                                                  const float* __restrict__ Wc,
                                                  u16* __restrict__ Mh, u16* __restrict__ Ml,
                                                  u16* __restrict__ Wch, u16* __restrict__ Wcl) {
    const int n = blockIdx.x;
    const int which = blockIdx.y;
    const float* src = (which == 0) ? M : Wc;
    u16* dh = (which == 0) ? Mh : Wch;
    u16* dl = (which == 0) ? Ml : Wcl;
    for (int k = threadIdx.x; k < 512; k += 256) {
        float f = src[(size_t)k * 512 + n];
        u32 u = __float_as_uint(f);
        u16 h = (u16)(u >> 16);
        float rem = f - __uint_as_float(u & 0xFFFF0000u);
        u32 ur = __float_as_uint(rem);
        u16 l = (u16)((ur + 0x7FFF + ((ur >> 16) & 1)) >> 16);
        dh[(size_t)n * 512 + k] = h;
        dl[(size_t)n * 512 + k] = l;
    }
}

// keys [ML][512] -> Kt [512][ML]
__global__ __launch_bounds__(256) void transpose_to_dt(const float* __restrict__ X,
                                                       float* __restrict__ XT) {
    __shared__ float Ts[64][65];
    const int bd = blockIdx.x * 64;
    const int bm = blockIdx.y * 64;
    const int t = threadIdx.x;
    const int r = t >> 2, c4 = t & 3;
#pragma unroll
    for (int i = 0; i < 4; ++i) {
        const int c0 = (c4 + 4 * i) * 4;
        float4 v = *(const float4*)&X[(size_t)(bm + r) * DMODEL + bd + c0];
        Ts[r][c0 + 0] = v.x; Ts[r][c0 + 1] = v.y; Ts[r][c0 + 2] = v.z; Ts[r][c0 + 3] = v.w;
    }
    __syncthreads();
    const int dl = t >> 2, m4 = t & 3;
#pragma unroll
    for (int i = 0; i < 4; ++i) {
        const int m0 = (m4 + 4 * i) * 4;
        float4 o;
        o.x = Ts[m0 + 0][dl]; o.y = Ts[m0 + 1][dl]; o.z = Ts[m0 + 2][dl]; o.w = Ts[m0 + 3][dl];
        *(float4*)&XT[(size_t)(bd + dl) * ML + bm + m0] = o;
    }
}

// sum NGRP half-spectra. grid (9, BB); j <= 2048 guarded.
__global__ __launch_bounds__(256) void reduce_ppart(const float2* __restrict__ Pp,
                                                    float2* __restrict__ Pred) {
    const int j = blockIdx.x * 256 + threadIdx.x;
    const int b = blockIdx.y;
    if (j > 2048) return;
    float sr = 0.f, si = 0.f;
    const float2* base = Pp + (size_t)b * NGRP * PPH + j;
    for (int g = 0; g < NGRP; ++g) {
        float2 p = base[(size_t)g * PPH];
        sr += p.x;
        si += p.y;
    }
    Pred[(size_t)b * PPH + j] = make_float2(sr, si);
}

// 8 blocks: Hermitian reconstruction + inverse FFT (conj->fwd->Re), scaled
__global__ __launch_bounds__(256) void ifft_mean(const float2* __restrict__ Pred,
                                                 float* __restrict__ mv) {
    __shared__ float lre[4096];
    __shared__ float lim[4096];
    const int t = threadIdx.x;
    const int b = blockIdx.x;
    for (int j = t; j < 4096; j += 256) {
        float2 p;
        if (j <= 2048) {
            p = Pred[(size_t)b * PPH + j];
        } else {
            p = Pred[(size_t)b * PPH + (4096 - j)];
            p.y = -p.y;  // Hermitian mirror
        }
        int key = (j >> 8) & 15;
        int ph = j ^ ((key & 3) << 2) ^ ((key & 1) << 4);
        lre[ph] = p.x;
        lim[ph] = -p.y;  // conj for inverse transform
    }
    __syncthreads();
    fft4096_r16_core(lre, lim, t);
    const float scale = 1.0f / (4096.0f * 512.0f);
    for (int j = t; j < 4096; j += 256) mv[(size_t)b * 4096 + j] = lre[j] * scale;
}

__global__ __launch_bounds__(256) void topk_softmax(const float* __restrict__ mv,
                                                    int* __restrict__ idxO,
                                                    float* __restrict__ tcO) {
    __shared__ float vals[4096];
    __shared__ float rv[256];
    __shared__ int ri[256];
    __shared__ int sidx[TOPK];
    const int tid = threadIdx.x;
    for (int j = tid; j < 4096; j += 256) {
        float s = 0.f;
        for (int b = 0; b < BB; ++b) s += mv[(size_t)b * 4096 + j];
        vals[j] = s * 0.125f;
    }
    __syncthreads();
    for (int k = 0; k < TOPK; ++k) {
        float best = -INFINITY;
        int bi = 0x7fffffff;
        for (int j = tid; j < 4096; j += 256) {
            float v = vals[j];
            if (v > best) { best = v; bi = j; }
        }
        rv[tid] = best; ri[tid] = bi;
        __syncthreads();
        for (int off = 128; off > 0; off >>= 1) {
            if (tid < off) {
                float ov = rv[tid + off]; int oi = ri[tid + off];
                if (ov > rv[tid] || (ov == rv[tid] && oi < ri[tid])) { rv[tid] = ov; ri[tid] = oi; }
            }
            __syncthreads();
        }
        if (tid == 0) {
            sidx[k] = ri[0];
            idxO[k] = ri[0];
            vals[ri[0]] = -INFINITY;
        }
        __syncthreads();
    }
    if (tid < BB) {
        float w[TOPK];
        float m = -INFINITY;
        for (int k = 0; k < TOPK; ++k) {
            w[k] = mv[(size_t)tid * 4096 + sidx[k]];
            m = fmaxf(m, w[k]);
        }
        float s = 0.f;
        for (int k = 0; k < TOPK; ++k) { w[k] = expf(w[k] - m); s += w[k]; }
        float inv = 1.0f / s;
        for (int k = 0; k < TOPK; ++k) tcO[tid * TOPK + k] = w[k] * inv;
    }
}

// out[b,l,:] = sum_k tc[b,k] * VO_bf16[b,(l+idx[k])%L,:]  — 8 bf16/thread via uint4
__global__ __launch_bounds__(256) void gather_out(const u16* __restrict__ VO,
                                                  const int* __restrict__ idx,
                                                  const float* __restrict__ tc,
                                                  float* __restrict__ out) {
    const int e = blockIdx.x * 256 + threadIdx.x;
    const int d8 = e & 63;           // 8-elem chunk within row
    const int l = (e >> 6) & 4095;
    const int b = e >> 18;
    float s[8] = {};
#pragma unroll
    for (int k = 0; k < TOPK; ++k) {
        const int src = (l + idx[k]) & 4095;
        const float w = tc[b * TOPK + k];
        uint4 v = *(const uint4*)&VO[((size_t)(b * 4096 + src)) * 512 + d8 * 8];
        s[0] += w * __uint_as_float(v.x << 16);
        s[1] += w * __uint_as_float(v.x & 0xFFFF0000u);
        s[2] += w * __uint_as_float(v.y << 16);
        s[3] += w * __uint_as_float(v.y & 0xFFFF0000u);
        s[4] += w * __uint_as_float(v.z << 16);
        s[5] += w * __uint_as_float(v.z & 0xFFFF0000u);
        s[6] += w * __uint_as_float(v.w << 16);
        s[7] += w * __uint_as_float(v.w & 0xFFFF0000u);
    }
    const size_t ob = ((size_t)(b * 4096 + l)) * 512 + d8 * 8;
    *(float4*)&out[ob]     = make_float4(s[0], s[1], s[2], s[3]);
    *(float4*)&out[ob + 4] = make_float4(s[4], s[5], s[6], s[7]);
}

extern "C" void kernel_launch(void* const* d_in, const int* in_sizes, int n_in,
                              void* d_out, int out_size, void* d_ws, size_t ws_size,
                              hipStream_t stream) {
    const float* queries = (const float*)d_in[0];
    const float* keys    = (const float*)d_in[1];
    const float* values  = (const float*)d_in[2];
    const float* Wq = (const float*)d_in[3];
    const float* Wk = (const float*)d_in[5];
    const float* Wv = (const float*)d_in[7];
    const float* bv = (const float*)d_in[8];
    const float* Wo = (const float*)d_in[9];
    const float* bo = (const float*)d_in[10];
    float* out = (float*)d_out;

    float* ws = (float*)d_ws;
    const size_t SZ = (size_t)ML * DMODEL;           // 16,777,216 floats
    float* Qt    = ws;                                // q''^T [512][ML]; reused as VO (bf16)
    float* Kt    = ws + SZ;                           // keys^T
    float* Pp    = ws + 2 * SZ;                       // BB*NGRP*PPH*2 floats ~ 16.8 MB
    float* Pred  = Pp + (size_t)BB * NGRP * PPH * 2;  // BB*PPH*2 floats
    float* mv    = Pred + (size_t)BB * PPH * 2;       // 32768
    int*   idx   = (int*)(mv + 32768);                // 16
    float* tc    = mv + 32768 + 16;                   // 64 (pad 96)
    float* Mfull = mv + 32768 + 96;                   // 262144
    float* Wc    = Mfull + 262144;                    // 262144
    float* bc    = Wc + 262144;                       // 512
    u16* Mh  = (u16*)(bc + 512);
    u16* Ml  = Mh + 262144;
    u16* Wch = Ml + 262144;
    u16* Wcl = Wch + 262144;
    u16* VOb = (u16*)Qt;  // bf16 VO, reuses Qt (dead after fft_cross)

    dim3 blk(256);

    // weight prep: Wc = Wv@Wo, M = Wq@Wk^T, bc = bv@Wo + bo, transpose+split M/Wc
    gemm_plain512<<<dim3(8, 8), blk, 0, stream>>>(Wv, Wo, Wc);
    gemm_plain512_bt<<<dim3(8, 8), blk, 0, stream>>>(Wq, Wk, Mfull);
    bc_kernel<<<dim3(2), blk, 0, stream>>>(bv, Wo, bo, bc);
    prep_split<<<dim3(512, 2), blk, 0, stream>>>(Mfull, Wc, Mh, Ml, Wch, Wcl);

    // q'' = queries @ M (split-bf16 3-pass, transposed out; biases provably cancel)
    gemm_split<true, 3, false, false><<<dim3(1024), blk, 0, stream>>>(queries, Mh, Ml, nullptr, Qt);
    // keys^T (raw, exact)
    transpose_to_dt<<<dim3(8, 512), blk, 0, stream>>>(keys, Kt);

    // correlation path (Hermitian half-spectrum)
    fft_cross<<<dim3(BB * NGRP), blk, 0, stream>>>(Qt, Kt, Pp);
    reduce_ppart<<<dim3(9, BB), blk, 0, stream>>>((const float2*)Pp, (float2*)Pred);
    ifft_mean<<<dim3(BB), blk, 0, stream>>>((const float2*)Pred, mv);
    topk_softmax<<<dim3(1), blk, 0, stream>>>(mv, idx, tc);

    // V path: VO = values @ (Wv Wo) + (bv Wo + bo), packed bf16 (overwrites Qt)
    gemm_split<false, 1, true, true><<<dim3(1024), blk, 0, stream>>>(values, Wch, Wcl, bc, VOb);

    gather_out<<<dim3((BB * LSEQ * (DMODEL / 8)) / 256), blk, 0, stream>>>(VOb, idx, tc, out);
}

// Round 7
// 369.604 us; speedup vs baseline: 4.7967x; 1.0181x over previous
//
#include <hip/hip_runtime.h>
#include <math.h>

#define LSEQ 4096
#define DMODEL 512
#define BB 8
#define TOPK 8
#define ML (BB * LSEQ)          // 32768 rows
#define FFT_CH 2                // channels per fft_cross block
#define NGRP (DMODEL / FFT_CH)  // 256 groups per batch
#define PPH 2052                // float2 stride of half-spectrum (2049 used, padded)

typedef unsigned short u16;
typedef unsigned int u32;
typedef float f32x4 __attribute__((ext_vector_type(4)));
typedef short s16x8 __attribute__((ext_vector_type(8)));
typedef u16 u16x8 __attribute__((ext_vector_type(8)));

// ==================== 16-pt FFT, fully unrolled DIF (output bit-reversed in regs) ====================
__device__ __forceinline__ void fft16(float (&zr)[16], float (&zi)[16]) {
    const float C1 = 0.92387953251128674f, S1 = 0.38268343236508978f, R2 = 0.70710678118654752f;
#define BF0(i, j) { float ar=zr[i],ai=zi[i],br=zr[j],bi=zi[j]; zr[i]=ar+br; zi[i]=ai+bi; zr[j]=ar-br; zi[j]=ai-bi; }
#define BFW(i, j, wr, wi) { float ar=zr[i],ai=zi[i],br=zr[j],bi=zi[j]; zr[i]=ar+br; zi[i]=ai+bi; float dr=ar-br, di=ai-bi; zr[j]=dr*(wr)-di*(wi); zi[j]=dr*(wi)+di*(wr); }
#define BFI(i, j) { float ar=zr[i],ai=zi[i],br=zr[j],bi=zi[j]; zr[i]=ar+br; zi[i]=ai+bi; float dr=ar-br, di=ai-bi; zr[j]=di; zi[j]=-dr; }
    BF0(0, 8); BFW(1, 9, C1, -S1); BFW(2, 10, R2, -R2); BFW(3, 11, S1, -C1);
    BFI(4, 12); BFW(5, 13, -S1, -C1); BFW(6, 14, -R2, -R2); BFW(7, 15, -C1, -S1);
    BF0(0, 4); BFW(1, 5, R2, -R2); BFI(2, 6); BFW(3, 7, -R2, -R2);
    BF0(8, 12); BFW(9, 13, R2, -R2); BFI(10, 14); BFW(11, 15, -R2, -R2);
    BF0(0, 2); BFI(1, 3); BF0(4, 6); BFI(5, 7);
    BF0(8, 10); BFI(9, 11); BF0(12, 14); BFI(13, 15);
    BF0(0, 1); BF0(2, 3); BF0(4, 5); BF0(6, 7);
    BF0(8, 9); BF0(10, 11); BF0(12, 13); BF0(14, 15);
#undef BF0
#undef BFW
#undef BFI
}

// 3-level radix-16 4096-pt FFT core. Twiddles CHAINED (geometric series): iterate
// outputs in natural k-order (REV16 is self-inverse -> register index REV16[k]),
// 1-2 __sincosf per level total, w *= step each iteration (drift ~2e-6, harmless).
// Input staged in phys-swizzled layout phys(n) = n ^ (((n>>8)&3)<<2) ^ (((n>>8)&1)<<4);
// output natural order, synced.
__device__ __forceinline__ void fft4096_r16_core(float* __restrict__ lre, float* __restrict__ lim, int t) {
    constexpr int REV16[16] = {0, 8, 4, 12, 2, 10, 6, 14, 1, 9, 5, 13, 3, 11, 7, 15};
    float zr[16], zi[16];
    // level A: DFT16 over n0 (stride 256); twiddle W^(16*k0*n1), step w1 = exp(-i*pi*n1/128)
#pragma unroll
    for (int gg = 0; gg < 16; ++gg) {
        int n = 256 * gg + t;
        int p = n ^ ((gg & 3) << 2) ^ ((gg & 1) << 4);
        zr[gg] = lre[p]; zi[gg] = lim[p];
    }
    fft16(zr, zi);
    {
        const int n1 = t >> 4;
        float w1i, w1r;
        __sincosf(-0.0245436926061702596f * (float)n1, &w1i, &w1r);  // -pi/128 * n1
        float wr = 1.f, wi = 0.f;
#pragma unroll
        for (int k0 = 0; k0 < 16; ++k0) {
            float vr = zr[REV16[k0]], vi = zi[REV16[k0]];
            if (k0) {
                float nr = wr * w1r - wi * w1i;
                wi = wr * w1i + wi * w1r;
                wr = nr;
                float tr = vr * wr - vi * wi;
                vi = vr * wi + vi * wr;
                vr = tr;
            }
            int n = 256 * k0 + t;
            int p = n ^ ((k0 & 3) << 2) ^ ((k0 & 1) << 4);
            lre[p] = vr; lim[p] = vi;
        }
    }
    __syncthreads();
    // level B: DFT16 over n1 (stride 16); twiddle W^(n2*(k0+16k1)) = wb * ws^k1,
    // wb = exp(-i*pi*n2*k0/2048), ws = exp(-i*pi*n2/128)
    {
        const int k0 = t >> 4, n2 = t & 15;
        const int x0 = ((k0 & 3) << 2) | ((k0 & 1) << 4);
#pragma unroll
        for (int gg = 0; gg < 16; ++gg) {
            int n = 256 * k0 + 16 * gg + n2;
            zr[gg] = lre[n ^ x0]; zi[gg] = lim[n ^ x0];
        }
        fft16(zr, zi);
        float wbi, wbr, wsi, wsr;
        __sincosf(-0.00153398078788564123f * (float)(n2 * k0), &wbi, &wbr);  // -pi/2048 * n2*k0
        __sincosf(-0.0245436926061702596f * (float)n2, &wsi, &wsr);          // -pi/128 * n2
        float wr = wbr, wi = wbi;
#pragma unroll
        for (int k1 = 0; k1 < 16; ++k1) {
            float vr = zr[REV16[k1]], vi = zi[REV16[k1]];
            if (k1) {
                float nr = wr * wsr - wi * wsi;
                wi = wr * wsi + wi * wsr;
                wr = nr;
            }
            float tr = vr * wr - vi * wi;
            vi = vr * wi + vi * wr;
            vr = tr;
            int n = 256 * k0 + 16 * k1 + n2;
            lre[n ^ x0] = vr; lim[n ^ x0] = vi;
        }
    }
    __syncthreads();
    // level C: DFT16 over n2 (stride 1, b128 reads), no twiddles; output natural order
    {
        const int k0 = t & 15, k1 = t >> 4;
        const int nb4 = 64 * k0 + 4 * k1;
        const int xv = (k0 & 3) | ((k0 & 1) << 2);
#pragma unroll
        for (int i = 0; i < 4; ++i) {
            int p4 = (nb4 + i) ^ xv;
            float4 fr = *(const float4*)&lre[4 * p4];
            float4 fi = *(const float4*)&lim[4 * p4];
            zr[4 * i + 0] = fr.x; zr[4 * i + 1] = fr.y; zr[4 * i + 2] = fr.z; zr[4 * i + 3] = fr.w;
            zi[4 * i + 0] = fi.x; zi[4 * i + 1] = fi.y; zi[4 * i + 2] = fi.z; zi[4 * i + 3] = fi.w;
        }
        fft16(zr, zi);
        __syncthreads();  // all phys reads done before natural overwrite
#pragma unroll
        for (int r = 0; r < 16; ++r) {
            const int k2 = REV16[r];
            lre[t + 256 * k2] = zr[r];
            lim[t + 256 * k2] = zi[r];
        }
    }
    __syncthreads();
}

// grid: BB*NGRP blocks; block (b,g): channels d = g*FFT_CH..+1.
// Qt = (queries @ WqWk^T)^T, Kt = keys^T. Output: Hermitian half-spectrum j=0..2048.
__global__ __launch_bounds__(256) void fft_cross(const float* __restrict__ Qt,
                                                 const float* __restrict__ Kt,
                                                 float* __restrict__ Ppart) {
    __shared__ float lre[4096];
    __shared__ float lim[4096];
    const int t = threadIdx.x;
    const int b = blockIdx.x / NGRP;
    const int g = blockIdx.x % NGRP;

    float2 acc[8];
#pragma unroll
    for (int i = 0; i < 8; ++i) acc[i] = make_float2(0.f, 0.f);
    float accn = 0.f;  // Nyquist bin (j=2048), real

    const float4* q4 = (const float4*)(Qt + (size_t)(g * FFT_CH) * ML + (size_t)b * LSEQ);
    const float4* k4 = (const float4*)(Kt + (size_t)(g * FFT_CH) * ML + (size_t)b * LSEQ);

    float4 pq[4], pk[4];
#pragma unroll
    for (int i = 0; i < 4; ++i) {
        pq[i] = q4[t + 256 * i];
        pk[i] = k4[t + 256 * i];
    }

    for (int c = 0; c < FFT_CH; ++c) {
        __syncthreads();  // prev channel's cross-reads done
#pragma unroll
        for (int i = 0; i < 4; ++i) {
            int v = t + 256 * i;                 // float4-block index (n>>2)
            int key = (v >> 6) & 15;
            int p4 = v ^ (key & 3) ^ ((key & 1) << 2);
            *(float4*)&lre[4 * p4] = pq[i];
            *(float4*)&lim[4 * p4] = pk[i];
        }
        if (c + 1 < FFT_CH) {
            const float4* qn = q4 + (size_t)(c + 1) * (ML >> 2);
            const float4* kn = k4 + (size_t)(c + 1) * (ML >> 2);
#pragma unroll
            for (int i = 0; i < 4; ++i) {
                pq[i] = qn[t + 256 * i];
                pk[i] = kn[t + 256 * i];
            }
        }
        __syncthreads();
        fft4096_r16_core(lre, lim, t);
        // cross-spectrum: Qf * conj(Kf) from packed z = q + i*k, lower half only
#pragma unroll
        for (int i = 0; i < 8; ++i) {
            const int j = i * 256 + t;
            const int nj = (4096 - j) & 4095;
            float zfr = lre[j], zfi = lim[j];
            float znr = lre[nj], zni = lim[nj];
            float qr = 0.5f * (zfr + znr);
            float qi = 0.5f * (zfi - zni);
            float kr = 0.5f * (zfi + zni);
            float ki = -0.5f * (zfr - znr);
            acc[i].x += qr * kr + qi * ki;
            acc[i].y += qi * kr - qr * ki;
        }
        if (t == 0) accn += lre[2048] * lim[2048];
    }
    float2* Pp = (float2*)Ppart + (size_t)blockIdx.x * PPH;
#pragma unroll
    for (int i = 0; i < 8; ++i) Pp[i * 256 + t] = acc[i];
    if (t == 0) Pp[2048] = make_float2(accn, 0.f);
}

// ============ split-bf16 MFMA GEMM: C = A[M,512] @ W[512,512] (+ bias) ============
// PASSES=3: hi*hi + hi*lo + lo*hi (fp32-class).  PASSES=1: RNE bf16.
// B16O: pack output to bf16 (u16) instead of fp32.
template <bool TOUT, int PASSES, bool BIAS, bool B16O>
__global__ __launch_bounds__(256, 2) void gemm_split(const float* __restrict__ A,
                                                     const u16* __restrict__ Bhi,
                                                     const u16* __restrict__ Blo,
                                                     const float* __restrict__ bias,
                                                     void* __restrict__ Cv) {
    __shared__ u16 sAhi[128 * 64];
    __shared__ u16 sAlo[PASSES == 3 ? 128 * 64 : 64];
    __shared__ u16 sBhi[128 * 64];
    __shared__ u16 sBlo[PASSES == 3 ? 128 * 64 : 64];

    const int tid = threadIdx.x;
    const int lin = blockIdx.x;
    const int t = (lin & 7) * 128 + (lin >> 3);
    const int bm = (t >> 2) * 128;
    const int bn = (t & 3) * 128;

    const int lane = tid & 63, wid = tid >> 6;
    const int wm = wid >> 1, wn = wid & 1;
    const int l15 = lane & 15, kg = lane >> 4;

    f32x4 acc[4][4] = {};

    for (int k0 = 0; k0 < 512; k0 += 64) {
        __syncthreads();
#pragma unroll
        for (int it = 0; it < 4; ++it) {
            const int ch = it * 256 + tid;
            const int row = ch >> 3, c = ch & 7;
            const float* ga = A + (size_t)(bm + row) * 512 + k0 + c * 8;
            float4 f0 = *(const float4*)ga;
            float4 f1 = *(const float4*)(ga + 4);
            float fs[8] = {f0.x, f0.y, f0.z, f0.w, f1.x, f1.y, f1.z, f1.w};
            u32 h[4], l[4];
#pragma unroll
            for (int p = 0; p < 4; ++p) {
                u32 u0 = __float_as_uint(fs[2 * p]);
                u32 u1 = __float_as_uint(fs[2 * p + 1]);
                if constexpr (PASSES == 3) {
                    h[p] = __builtin_amdgcn_perm(u1, u0, 0x07060302u);
                    float r0 = fs[2 * p]     - __uint_as_float(u0 & 0xFFFF0000u);
                    float r1 = fs[2 * p + 1] - __uint_as_float(u1 & 0xFFFF0000u);
                    l[p] = __builtin_amdgcn_perm(__float_as_uint(r1), __float_as_uint(r0), 0x07060302u);
                } else {
                    u32 h0 = u0 + 0x7FFF + ((u0 >> 16) & 1);
                    u32 h1 = u1 + 0x7FFF + ((u1 >> 16) & 1);
                    h[p] = __builtin_amdgcn_perm(h1, h0, 0x07060302u);
                }
            }
            const int off = row * 64 + ((c ^ (row & 7)) << 3);
            *(uint4*)&sAhi[off] = make_uint4(h[0], h[1], h[2], h[3]);
            if constexpr (PASSES == 3) *(uint4*)&sAlo[off] = make_uint4(l[0], l[1], l[2], l[3]);
        }
#pragma unroll
        for (int it = 0; it < 4; ++it) {
            const int ch = it * 256 + tid;
            const int row = ch >> 3, c = ch & 7;
            const int off = row * 64 + ((c ^ (row & 7)) << 3);
            const size_t gg = (size_t)(bn + row) * 512 + k0 + c * 8;
            *(u16x8*)&sBhi[off] = *(const u16x8*)&Bhi[gg];
            if constexpr (PASSES == 3) *(u16x8*)&sBlo[off] = *(const u16x8*)&Blo[gg];
        }
        __syncthreads();
#pragma unroll
        for (int kk = 0; kk < 2; ++kk) {
            const int cbase = kk * 4 + kg;
            s16x8 ah[4], al[4], bh[4], bl[4];
#pragma unroll
            for (int mi = 0; mi < 4; ++mi) {
                const int row = wm * 64 + mi * 16 + l15;
                const int off = row * 64 + (((cbase ^ (row & 7))) << 3);
                ah[mi] = *(const s16x8*)&sAhi[off];
                if constexpr (PASSES == 3) al[mi] = *(const s16x8*)&sAlo[off];
            }
#pragma unroll
            for (int ni = 0; ni < 4; ++ni) {
                const int row = wn * 64 + ni * 16 + l15;
                const int off = row * 64 + (((cbase ^ (row & 7))) << 3);
                bh[ni] = *(const s16x8*)&sBhi[off];
                if constexpr (PASSES == 3) bl[ni] = *(const s16x8*)&sBlo[off];
            }
#pragma unroll
            for (int ni = 0; ni < 4; ++ni)
#pragma unroll
                for (int mi = 0; mi < 4; ++mi) {
                    acc[mi][ni] = __builtin_amdgcn_mfma_f32_16x16x32_bf16(ah[mi], bh[ni], acc[mi][ni], 0, 0, 0);
                    if constexpr (PASSES == 3) {
                        acc[mi][ni] = __builtin_amdgcn_mfma_f32_16x16x32_bf16(ah[mi], bl[ni], acc[mi][ni], 0, 0, 0);
                        acc[mi][ni] = __builtin_amdgcn_mfma_f32_16x16x32_bf16(al[mi], bh[ni], acc[mi][ni], 0, 0, 0);
                    }
                }
        }
    }
    // epilogue (C/D layout: col = lane&15, row = (lane>>4)*4 + reg)
    if constexpr (TOUT) {
        float* C = (float*)Cv;
#pragma unroll
        for (int ni = 0; ni < 4; ++ni) {
            const int d = bn + wn * 64 + ni * 16 + l15;
            const float bv = BIAS ? bias[d] : 0.0f;
#pragma unroll
            for (int mi = 0; mi < 4; ++mi) {
                const int rb = bm + wm * 64 + mi * 16 + (kg << 2);
                float4 o;
                o.x = acc[mi][ni][0] + bv; o.y = acc[mi][ni][1] + bv;
                o.z = acc[mi][ni][2] + bv; o.w = acc[mi][ni][3] + bv;
                *(float4*)&C[(size_t)d * ML + rb] = o;
            }
        }
    } else {
#pragma unroll
        for (int ni = 0; ni < 4; ++ni) {
            const int col = bn + wn * 64 + ni * 16 + l15;
            const float bv = BIAS ? bias[col] : 0.0f;
#pragma unroll
            for (int mi = 0; mi < 4; ++mi) {
                const int rb = bm + wm * 64 + mi * 16 + (kg << 2);
#pragma unroll
                for (int r = 0; r < 4; ++r) {
                    float f = acc[mi][ni][r] + bv;
                    if constexpr (B16O) {
                        u32 u = __float_as_uint(f);
                        ((u16*)Cv)[(size_t)(rb + r) * 512 + col] = (u16)((u + 0x7FFF + ((u >> 16) & 1)) >> 16);
                    } else {
                        ((float*)Cv)[(size_t)(rb + r) * 512 + col] = f;
                    }
                }
            }
        }
    }
}

// ============ tiny fp32 GEMMs (512^3) ============
__global__ __launch_bounds__(256) void gemm_plain512(const float* __restrict__ A,
                                                     const float* __restrict__ W,
                                                     float* __restrict__ C) {
    __shared__ float As[16][64];
    __shared__ float Ws[16][64];
    const int tid = threadIdx.x;
    const int tx = tid & 15, ty = tid >> 4;
    const int bm = blockIdx.y * 64, bn = blockIdx.x * 64;
    float acc[4][4] = {};
    const int arow = tid >> 2, ak4 = tid & 3;
    const int wrow = tid >> 4, wc4 = tid & 15;
    for (int k0 = 0; k0 < 512; k0 += 16) {
        float4 av = *(const float4*)&A[(size_t)(bm + arow) * 512 + k0 + ak4 * 4];
        float4 wv = *(const float4*)&W[(size_t)(k0 + wrow) * 512 + bn + wc4 * 4];
        __syncthreads();
        As[ak4 * 4 + 0][arow] = av.x;
        As[ak4 * 4 + 1][arow] = av.y;
        As[ak4 * 4 + 2][arow] = av.z;
        As[ak4 * 4 + 3][arow] = av.w;
        *(float4*)&Ws[wrow][wc4 * 4] = wv;
        __syncthreads();
#pragma unroll
        for (int k = 0; k < 16; ++k) {
            float4 a = *(const float4*)&As[k][ty * 4];
            float4 b = *(const float4*)&Ws[k][tx * 4];
            acc[0][0] += a.x * b.x; acc[0][1] += a.x * b.y; acc[0][2] += a.x * b.z; acc[0][3] += a.x * b.w;
            acc[1][0] += a.y * b.x; acc[1][1] += a.y * b.y; acc[1][2] += a.y * b.z; acc[1][3] += a.y * b.w;
            acc[2][0] += a.z * b.x; acc[2][1] += a.z * b.y; acc[2][2] += a.z * b.z; acc[2][3] += a.z * b.w;
            acc[3][0] += a.w * b.x; acc[3][1] += a.w * b.y; acc[3][2] += a.w * b.z; acc[3][3] += a.w * b.w;
        }
    }
#pragma unroll
    for (int i = 0; i < 4; ++i) {
        float4 o;
        o.x = acc[i][0]; o.y = acc[i][1]; o.z = acc[i][2]; o.w = acc[i][3];
        *(float4*)&C[(size_t)(bm + ty * 4 + i) * 512 + bn + tx * 4] = o;
    }
}

// C = A @ B^T (for M = Wq @ Wk^T)
__global__ __launch_bounds__(256) void gemm_plain512_bt(const float* __restrict__ A,
                                                        const float* __restrict__ B,
                                                        float* __restrict__ C) {
    __shared__ float As[16][64];
    __shared__ float Ws[16][64];
    const int tid = threadIdx.x;
    const int tx = tid & 15, ty = tid >> 4;
    const int bm = blockIdx.y * 64, bn = blockIdx.x * 64;
    float acc[4][4] = {};
    const int arow = tid >> 2, ak4 = tid & 3;
    for (int k0 = 0; k0 < 512; k0 += 16) {
        float4 av = *(const float4*)&A[(size_t)(bm + arow) * 512 + k0 + ak4 * 4];
        float4 bv = *(const float4*)&B[(size_t)(bn + arow) * 512 + k0 + ak4 * 4];
        __syncthreads();
        As[ak4 * 4 + 0][arow] = av.x;
        As[ak4 * 4 + 1][arow] = av.y;
        As[ak4 * 4 + 2][arow] = av.z;
        As[ak4 * 4 + 3][arow] = av.w;
        Ws[ak4 * 4 + 0][arow] = bv.x;
        Ws[ak4 * 4 + 1][arow] = bv.y;
        Ws[ak4 * 4 + 2][arow] = bv.z;
        Ws[ak4 * 4 + 3][arow] = bv.w;
        __syncthreads();
#pragma unroll
        for (int k = 0; k < 16; ++k) {
            float4 a = *(const float4*)&As[k][ty * 4];
            float4 b = *(const float4*)&Ws[k][tx * 4];
            acc[0][0] += a.x * b.x; acc[0][1] += a.x * b.y; acc[0][2] += a.x * b.z; acc[0][3] += a.x * b.w;
            acc[1][0] += a.y * b.x; acc[1][1] += a.y * b.y; acc[1][2] += a.y * b.z; acc[1][3] += a.y * b.w;
            acc[2][0] += a.z * b.x; acc[2][1] += a.z * b.y; acc[2][2] += a.z * b.z; acc[2][3] += a.z * b.w;
            acc[3][0] += a.w * b.x; acc[3][1] += a.w * b.y; acc[3][2] += a.w * b.z; acc[3][3] += a.w * b.w;
        }
    }
#pragma unroll
    for (int i = 0; i < 4; ++i) {
        float4 o;
        o.x = acc[i][0]; o.y = acc[i][1]; o.z = acc[i][2]; o.w = acc[i][3];
        *(float4*)&C[(size_t)(bm + ty * 4 + i) * 512 + bn + tx * 4] = o;
    }
}

__global__ __launch_bounds__(256) void bc_kernel(const float* __restrict__ bv,
                                                 const float* __restrict__ Wo,
                                                 const float* __restrict__ bo,
                                                 float* __restrict__ bc) {
    const int n = blockIdx.x * 256 + threadIdx.x;
    if (n < 512) {
        float s = bo[n];
        for (int j = 0; j < 512; ++j) s += bv[j] * Wo[(size_t)j * 512 + n];
        bc[n] = s;
    }
}

// transpose + hi/lo split: src [K][N] -> dh/dl [N][K] bf16 bits (M and Wc)
__global__ __launch_bounds__(256) void prep_split(const float* __restrict__ M,
                                                  const float* __restrict__ Wc,
                                                  u16* __restrict__ Mh, u16* __restrict__ Ml,
                                                  u16* __restrict__ Wch, u16* __restrict__ Wcl) {
    const int n = blockIdx.x;
    const int which = blockIdx.y;
    const float* src = (which == 0) ? M : Wc;
    u16* dh = (which == 0) ? Mh : Wch;
    u16* dl = (which == 0) ? Ml : Wcl;
    for (int k = threadIdx.x; k < 512; k += 256) {
        float f = src[(size_t)k * 512 + n];
        u32 u = __float_as_uint(f);
        u16 h = (u16)(u >> 16);
        float rem = f - __uint_as_float(u & 0xFFFF0000u);
        u32 ur = __float_as_uint(rem);
        u16 l = (u16)((ur + 0x7FFF + ((ur >> 16) & 1)) >> 16);
        dh[(size_t)n * 512 + k] = h;
        dl[(size_t)n * 512 + k] = l;
    }
}

// keys [ML][512] -> Kt [512][ML]
__global__ __launch_bounds__(256) void transpose_to_dt(const float* __restrict__ X,
                                                       float* __restrict__ XT) {
    __shared__ float Ts[64][65];
    const int bd = blockIdx.x * 64;
    const int bm = blockIdx.y * 64;
    const int t = threadIdx.x;
    const int r = t >> 2, c4 = t & 3;
#pragma unroll
    for (int i = 0; i < 4; ++i) {
        const int c0 = (c4 + 4 * i) * 4;
        float4 v = *(const float4*)&X[(size_t)(bm + r) * DMODEL + bd + c0];
        Ts[r][c0 + 0] = v.x; Ts[r][c0 + 1] = v.y; Ts[r][c0 + 2] = v.z; Ts[r][c0 + 3] = v.w;
    }
    __syncthreads();
    const int dl = t >> 2, m4 = t & 3;
#pragma unroll
    for (int i = 0; i < 4; ++i) {
        const int m0 = (m4 + 4 * i) * 4;
        float4 o;
        o.x = Ts[m0 + 0][dl]; o.y = Ts[m0 + 1][dl]; o.z = Ts[m0 + 2][dl]; o.w = Ts[m0 + 3][dl];
        *(float4*)&XT[(size_t)(bd + dl) * ML + bm + m0] = o;
    }
}

// sum NGRP half-spectra. grid (9, BB); j <= 2048 guarded.
__global__ __launch_bounds__(256) void reduce_ppart(const float2* __restrict__ Pp,
                                                    float2* __restrict__ Pred) {
    const int j = blockIdx.x * 256 + threadIdx.x;
    const int b = blockIdx.y;
    if (j > 2048) return;
    float sr = 0.f, si = 0.f;
    const float2* base = Pp + (size_t)b * NGRP * PPH + j;
    for (int g = 0; g < NGRP; ++g) {
        float2 p = base[(size_t)g * PPH];
        sr += p.x;
        si += p.y;
    }
    Pred[(size_t)b * PPH + j] = make_float2(sr, si);
}

// 8 blocks: Hermitian reconstruction + inverse FFT (conj->fwd->Re), scaled
__global__ __launch_bounds__(256) void ifft_mean(const float2* __restrict__ Pred,
                                                 float* __restrict__ mv) {
    __shared__ float lre[4096];
    __shared__ float lim[4096];
    const int t = threadIdx.x;
    const int b = blockIdx.x;
    for (int j = t; j < 4096; j += 256) {
        float2 p;
        if (j <= 2048) {
            p = Pred[(size_t)b * PPH + j];
        } else {
            p = Pred[(size_t)b * PPH + (4096 - j)];
            p.y = -p.y;  // Hermitian mirror
        }
        int key = (j >> 8) & 15;
        int ph = j ^ ((key & 3) << 2) ^ ((key & 1) << 4);
        lre[ph] = p.x;
        lim[ph] = -p.y;  // conj for inverse transform
    }
    __syncthreads();
    fft4096_r16_core(lre, lim, t);
    const float scale = 1.0f / (4096.0f * 512.0f);
    for (int j = t; j < 4096; j += 256) mv[(size_t)b * 4096 + j] = lre[j] * scale;
}

// single block, 1024 threads: batch-mean, iterative top-8 argmax via shfl
// (lower-index tie-break matches jax.lax.top_k), per-batch softmax
__global__ __launch_bounds__(1024) void topk_softmax(const float* __restrict__ mv,
                                                     int* __restrict__ idxO,
                                                     float* __restrict__ tcO) {
    __shared__ float vals[4096];
    __shared__ float wv[16];
    __shared__ int wix[16];
    __shared__ int sidx[TOPK];
    const int tid = threadIdx.x;
    const int lane = tid & 63, wvid = tid >> 6;
    for (int j = tid; j < 4096; j += 1024) {
        float s = 0.f;
        for (int b = 0; b < BB; ++b) s += mv[(size_t)b * 4096 + j];
        vals[j] = s * 0.125f;
    }
    __syncthreads();
    for (int k = 0; k < TOPK; ++k) {
        float best = -INFINITY;
        int bi = 0x7fffffff;
        for (int j = tid; j < 4096; j += 1024) {
            float v = vals[j];
            if (v > best) { best = v; bi = j; }  // ascending j -> keeps smallest idx on tie
        }
#pragma unroll
        for (int off = 32; off > 0; off >>= 1) {
            float ov = __shfl_down(best, off);
            int oi = __shfl_down(bi, off);
            if (ov > best || (ov == best && oi < bi)) { best = ov; bi = oi; }
        }
        if (lane == 0) { wv[wvid] = best; wix[wvid] = bi; }
        __syncthreads();
        if (wvid == 0) {
            best = (lane < 16) ? wv[lane] : -INFINITY;
            bi = (lane < 16) ? wix[lane] : 0x7fffffff;
#pragma unroll
            for (int off = 8; off > 0; off >>= 1) {
                float ov = __shfl_down(best, off);
                int oi = __shfl_down(bi, off);
                if (ov > best || (ov == best && oi < bi)) { best = ov; bi = oi; }
            }
            if (lane == 0) {
                sidx[k] = bi;
                idxO[k] = bi;
                vals[bi] = -INFINITY;
            }
        }
        __syncthreads();
    }
    if (tid < BB) {
        float w[TOPK];
        float m = -INFINITY;
        for (int k = 0; k < TOPK; ++k) {
            w[k] = mv[(size_t)tid * 4096 + sidx[k]];
            m = fmaxf(m, w[k]);
        }
        float s = 0.f;
        for (int k = 0; k < TOPK; ++k) { w[k] = expf(w[k] - m); s += w[k]; }
        float inv = 1.0f / s;
        for (int k = 0; k < TOPK; ++k) tcO[tid * TOPK + k] = w[k] * inv;
    }
}

// out[b,l,:] = sum_k tc[b,k] * VO_bf16[b,(l+idx[k])%L,:]  — 8 bf16/thread via uint4
__global__ __launch_bounds__(256) void gather_out(const u16* __restrict__ VO,
                                                  const int* __restrict__ idx,
                                                  const float* __restrict__ tc,
                                                  float* __restrict__ out) {
    const int e = blockIdx.x * 256 + threadIdx.x;
    const int d8 = e & 63;           // 8-elem chunk within row
    const int l = (e >> 6) & 4095;
    const int b = e >> 18;
    float s[8] = {};
#pragma unroll
    for (int k = 0; k < TOPK; ++k) {
        const int src = (l + idx[k]) & 4095;
        const float w = tc[b * TOPK + k];
        uint4 v = *(const uint4*)&VO[((size_t)(b * 4096 + src)) * 512 + d8 * 8];
        s[0] += w * __uint_as_float(v.x << 16);
        s[1] += w * __uint_as_float(v.x & 0xFFFF0000u);
        s[2] += w * __uint_as_float(v.y << 16);
        s[3] += w * __uint_as_float(v.y & 0xFFFF0000u);
        s[4] += w * __uint_as_float(v.z << 16);
        s[5] += w * __uint_as_float(v.z & 0xFFFF0000u);
        s[6] += w * __uint_as_float(v.w << 16);
        s[7] += w * __uint_as_float(v.w & 0xFFFF0000u);
    }
    const size_t ob = ((size_t)(b * 4096 + l)) * 512 + d8 * 8;
    *(float4*)&out[ob]     = make_float4(s[0], s[1], s[2], s[3]);
    *(float4*)&out[ob + 4] = make_float4(s[4], s[5], s[6], s[7]);
}

extern "C" void kernel_launch(void* const* d_in, const int* in_sizes, int n_in,
                              void* d_out, int out_size, void* d_ws, size_t ws_size,
                              hipStream_t stream) {
    const float* queries = (const float*)d_in[0];
    const float* keys    = (const float*)d_in[1];
    const float* values  = (const float*)d_in[2];
    const float* Wq = (const float*)d_in[3];
    const float* Wk = (const float*)d_in[5];
    const float* Wv = (const float*)d_in[7];
    const float* bv = (const float*)d_in[8];
    const float* Wo = (const float*)d_in[9];
    const float* bo = (const float*)d_in[10];
    float* out = (float*)d_out;

    float* ws = (float*)d_ws;
    const size_t SZ = (size_t)ML * DMODEL;           // 16,777,216 floats
    float* Qt    = ws;                                // q''^T [512][ML]; reused as VO (bf16)
    float* Kt    = ws + SZ;                           // keys^T
    float* Pp    = ws + 2 * SZ;                       // BB*NGRP*PPH*2 floats ~ 33.6 MB
    float* Pred  = Pp + (size_t)BB * NGRP * PPH * 2;  // BB*PPH*2 floats
    float* mv    = Pred + (size_t)BB * PPH * 2;       // 32768
    int*   idx   = (int*)(mv + 32768);                // 16
    float* tc    = mv + 32768 + 16;                   // 64 (pad 96)
    float* Mfull = mv + 32768 + 96;                   // 262144
    float* Wc    = Mfull + 262144;                    // 262144
    float* bc    = Wc + 262144;                       // 512
    u16* Mh  = (u16*)(bc + 512);
    u16* Ml  = Mh + 262144;
    u16* Wch = Ml + 262144;
    u16* Wcl = Wch + 262144;
    u16* VOb = (u16*)Qt;  // bf16 VO, reuses Qt (dead after fft_cross)

    dim3 blk(256);

    // weight prep: Wc = Wv@Wo, M = Wq@Wk^T, bc = bv@Wo + bo, transpose+split M/Wc
    gemm_plain512<<<dim3(8, 8), blk, 0, stream>>>(Wv, Wo, Wc);
    gemm_plain512_bt<<<dim3(8, 8), blk, 0, stream>>>(Wq, Wk, Mfull);
    bc_kernel<<<dim3(2), blk, 0, stream>>>(bv, Wo, bo, bc);
    prep_split<<<dim3(512, 2), blk, 0, stream>>>(Mfull, Wc, Mh, Ml, Wch, Wcl);

    // q'' = queries @ M (split-bf16 3-pass, transposed out; biases provably cancel)
    gemm_split<true, 3, false, false><<<dim3(1024), blk, 0, stream>>>(queries, Mh, Ml, nullptr, Qt);
    // keys^T (raw, exact)
    transpose_to_dt<<<dim3(8, 512), blk, 0, stream>>>(keys, Kt);

    // correlation path (Hermitian half-spectrum)
    fft_cross<<<dim3(BB * NGRP), blk, 0, stream>>>(Qt, Kt, Pp);
    reduce_ppart<<<dim3(9, BB), blk, 0, stream>>>((const float2*)Pp, (float2*)Pred);
    ifft_mean<<<dim3(BB), blk, 0, stream>>>((const float2*)Pred, mv);
    topk_softmax<<<dim3(1), dim3(1024), 0, stream>>>(mv, idx, tc);

    // V path: VO = values @ (Wv Wo) + (bv Wo + bo), packed bf16 (overwrites Qt)
    gemm_split<false, 1, true, true><<<dim3(1024), blk, 0, stream>>>(values, Wch, Wcl, bc, VOb);

    gather_out<<<dim3((BB * LSEQ * (DMODEL / 8)) / 256), blk, 0, stream>>>(VOb, idx, tc, out);
}

// Round 8
// 334.811 us; speedup vs baseline: 5.2951x; 1.1039x over previous
//
#include <hip/hip_runtime.h>
#include <math.h>

#define LSEQ 4096
#define DMODEL 512
#define BB 8
#define TOPK 8
#define ML (BB * LSEQ)          // 32768 rows
#define FFT_CH 2                // channels per fft_cross block
#define NGRP (DMODEL / FFT_CH)  // 256 groups per batch
#define PPH 2052                // float2 stride of half-spectrum (2049 used, padded)

typedef unsigned short u16;
typedef unsigned int u32;
typedef float f32x4 __attribute__((ext_vector_type(4)));
typedef short s16x8 __attribute__((ext_vector_type(8)));
typedef u16 u16x8 __attribute__((ext_vector_type(8)));

// ==================== 16-pt FFT, fully unrolled DIF (output bit-reversed in regs) ====================
__device__ __forceinline__ void fft16(float (&zr)[16], float (&zi)[16]) {
    const float C1 = 0.92387953251128674f, S1 = 0.38268343236508978f, R2 = 0.70710678118654752f;
#define BF0(i, j) { float ar=zr[i],ai=zi[i],br=zr[j],bi=zi[j]; zr[i]=ar+br; zi[i]=ai+bi; zr[j]=ar-br; zi[j]=ai-bi; }
#define BFW(i, j, wr, wi) { float ar=zr[i],ai=zi[i],br=zr[j],bi=zi[j]; zr[i]=ar+br; zi[i]=ai+bi; float dr=ar-br, di=ai-bi; zr[j]=dr*(wr)-di*(wi); zi[j]=dr*(wi)+di*(wr); }
#define BFI(i, j) { float ar=zr[i],ai=zi[i],br=zr[j],bi=zi[j]; zr[i]=ar+br; zi[i]=ai+bi; float dr=ar-br, di=ai-bi; zr[j]=di; zi[j]=-dr; }
    BF0(0, 8); BFW(1, 9, C1, -S1); BFW(2, 10, R2, -R2); BFW(3, 11, S1, -C1);
    BFI(4, 12); BFW(5, 13, -S1, -C1); BFW(6, 14, -R2, -R2); BFW(7, 15, -C1, -S1);
    BF0(0, 4); BFW(1, 5, R2, -R2); BFI(2, 6); BFW(3, 7, -R2, -R2);
    BF0(8, 12); BFW(9, 13, R2, -R2); BFI(10, 14); BFW(11, 15, -R2, -R2);
    BF0(0, 2); BFI(1, 3); BF0(4, 6); BFI(5, 7);
    BF0(8, 10); BFI(9, 11); BF0(12, 14); BFI(13, 15);
    BF0(0, 1); BF0(2, 3); BF0(4, 5); BF0(6, 7);
    BF0(8, 9); BF0(10, 11); BF0(12, 13); BF0(14, 15);
#undef BF0
#undef BFW
#undef BFI
}

// 3-level radix-16 4096-pt FFT core, chained twiddles (1-2 sincos/level).
// Input staged phys-swizzled: phys(n) = n ^ (((n>>8)&3)<<2) ^ (((n>>8)&1)<<4).
// Final level's outputs are returned in ozr/ozi: thread t holds Z[t+256*k2] in slot REV16[k2].
// If WRITEBACK: also writes natural order to LDS and syncs (for mirror reads).
template <bool WRITEBACK>
__device__ __forceinline__ void fft4096_r16_core(float* __restrict__ lre, float* __restrict__ lim, int t,
                                                 float (&ozr)[16], float (&ozi)[16]) {
    constexpr int REV16[16] = {0, 8, 4, 12, 2, 10, 6, 14, 1, 9, 5, 13, 3, 11, 7, 15};
    float zr[16], zi[16];
    // level A: DFT16 over n0 (stride 256); twiddle W^(16*k0*n1), chained step exp(-i*pi*n1/128)
#pragma unroll
    for (int gg = 0; gg < 16; ++gg) {
        int n = 256 * gg + t;
        int p = n ^ ((gg & 3) << 2) ^ ((gg & 1) << 4);
        zr[gg] = lre[p]; zi[gg] = lim[p];
    }
    fft16(zr, zi);
    {
        const int n1 = t >> 4;
        float w1i, w1r;
        __sincosf(-0.0245436926061702596f * (float)n1, &w1i, &w1r);  // -pi/128 * n1
        float wr = 1.f, wi = 0.f;
#pragma unroll
        for (int k0 = 0; k0 < 16; ++k0) {
            float vr = zr[REV16[k0]], vi = zi[REV16[k0]];
            if (k0) {
                float nr = wr * w1r - wi * w1i;
                wi = wr * w1i + wi * w1r;
                wr = nr;
                float tr = vr * wr - vi * wi;
                vi = vr * wi + vi * wr;
                vr = tr;
            }
            int n = 256 * k0 + t;
            int p = n ^ ((k0 & 3) << 2) ^ ((k0 & 1) << 4);
            lre[p] = vr; lim[p] = vi;
        }
    }
    __syncthreads();
    // level B: DFT16 over n1 (stride 16); twiddle wb*ws^k1
    {
        const int k0 = t >> 4, n2 = t & 15;
        const int x0 = ((k0 & 3) << 2) | ((k0 & 1) << 4);
#pragma unroll
        for (int gg = 0; gg < 16; ++gg) {
            int n = 256 * k0 + 16 * gg + n2;
            zr[gg] = lre[n ^ x0]; zi[gg] = lim[n ^ x0];
        }
        fft16(zr, zi);
        float wbi, wbr, wsi, wsr;
        __sincosf(-0.00153398078788564123f * (float)(n2 * k0), &wbi, &wbr);  // -pi/2048 * n2*k0
        __sincosf(-0.0245436926061702596f * (float)n2, &wsi, &wsr);          // -pi/128 * n2
        float wr = wbr, wi = wbi;
#pragma unroll
        for (int k1 = 0; k1 < 16; ++k1) {
            float vr = zr[REV16[k1]], vi = zi[REV16[k1]];
            if (k1) {
                float nr = wr * wsr - wi * wsi;
                wi = wr * wsi + wi * wsr;
                wr = nr;
            }
            float tr = vr * wr - vi * wi;
            vi = vr * wi + vi * wr;
            vr = tr;
            int n = 256 * k0 + 16 * k1 + n2;
            lre[n ^ x0] = vr; lim[n ^ x0] = vi;
        }
    }
    __syncthreads();
    // level C: DFT16 over n2 (stride 1, b128 reads), no twiddles; results stay in ozr/ozi
    {
        const int k0 = t & 15, k1 = t >> 4;
        const int nb4 = 64 * k0 + 4 * k1;
        const int xv = (k0 & 3) | ((k0 & 1) << 2);
#pragma unroll
        for (int i = 0; i < 4; ++i) {
            int p4 = (nb4 + i) ^ xv;
            float4 fr = *(const float4*)&lre[4 * p4];
            float4 fi = *(const float4*)&lim[4 * p4];
            ozr[4 * i + 0] = fr.x; ozr[4 * i + 1] = fr.y; ozr[4 * i + 2] = fr.z; ozr[4 * i + 3] = fr.w;
            ozi[4 * i + 0] = fi.x; ozi[4 * i + 1] = fi.y; ozi[4 * i + 2] = fi.z; ozi[4 * i + 3] = fi.w;
        }
        fft16(ozr, ozi);
        if constexpr (WRITEBACK) {
            __syncthreads();  // all phys reads done before natural overwrite
#pragma unroll
            for (int r = 0; r < 16; ++r) {
                const int k2 = REV16[r];
                lre[t + 256 * k2] = ozr[r];
                lim[t + 256 * k2] = ozi[r];
            }
            __syncthreads();
        }
    }
}

// grid: BB*NGRP blocks; block (b,g): channels d = g*FFT_CH..+1.
// Qt = (queries @ WqWk^T)^T, Kt = keys^T. Output: Hermitian half-spectrum j=0..2048.
__global__ __launch_bounds__(256) void fft_cross(const float* __restrict__ Qt,
                                                 const float* __restrict__ Kt,
                                                 float* __restrict__ Ppart) {
    __shared__ float lre[4096];
    __shared__ float lim[4096];
    constexpr int REV16[16] = {0, 8, 4, 12, 2, 10, 6, 14, 1, 9, 5, 13, 3, 11, 7, 15};
    const int t = threadIdx.x;
    const int b = blockIdx.x / NGRP;
    const int g = blockIdx.x % NGRP;

    float2 acc[8];
#pragma unroll
    for (int i = 0; i < 8; ++i) acc[i] = make_float2(0.f, 0.f);
    float accn = 0.f;  // Nyquist bin (j=2048), real

    const float4* q4 = (const float4*)(Qt + (size_t)(g * FFT_CH) * ML + (size_t)b * LSEQ);
    const float4* k4 = (const float4*)(Kt + (size_t)(g * FFT_CH) * ML + (size_t)b * LSEQ);

    float4 pq[4], pk[4];
#pragma unroll
    for (int i = 0; i < 4; ++i) {
        pq[i] = q4[t + 256 * i];
        pk[i] = k4[t + 256 * i];
    }

    for (int c = 0; c < FFT_CH; ++c) {
        __syncthreads();  // prev channel's mirror-reads done
#pragma unroll
        for (int i = 0; i < 4; ++i) {
            int v = t + 256 * i;                 // float4-block index (n>>2)
            int key = (v >> 6) & 15;
            int p4 = v ^ (key & 3) ^ ((key & 1) << 2);
            *(float4*)&lre[4 * p4] = pq[i];
            *(float4*)&lim[4 * p4] = pk[i];
        }
        if (c + 1 < FFT_CH) {
            const float4* qn = q4 + (size_t)(c + 1) * (ML >> 2);
            const float4* kn = k4 + (size_t)(c + 1) * (ML >> 2);
#pragma unroll
            for (int i = 0; i < 4; ++i) {
                pq[i] = qn[t + 256 * i];
                pk[i] = kn[t + 256 * i];
            }
        }
        __syncthreads();
        float ozr[16], ozi[16];
        fft4096_r16_core<true>(lre, lim, t, ozr, ozi);
        // cross-spectrum: own bins from REGISTERS, mirror bins from LDS
#pragma unroll
        for (int i = 0; i < 8; ++i) {
            const int j = i * 256 + t;
            const int nj = (4096 - j) & 4095;
            const int r = REV16[i];         // slot holding Z[t+256*i]
            float zfr = ozr[r], zfi = ozi[r];
            float znr = lre[nj], zni = lim[nj];
            float qr = 0.5f * (zfr + znr);
            float qi = 0.5f * (zfi - zni);
            float kr = 0.5f * (zfi + zni);
            float ki = -0.5f * (zfr - znr);
            acc[i].x += qr * kr + qi * ki;
            acc[i].y += qi * kr - qr * ki;
        }
        if (t == 0) accn += ozr[1] * ozi[1];  // bin 2048 lives in slot REV16[8]=1 of thread 0
    }
    float2* Pp = (float2*)Ppart + (size_t)blockIdx.x * PPH;
#pragma unroll
    for (int i = 0; i < 8; ++i) Pp[i * 256 + t] = acc[i];
    if (t == 0) Pp[2048] = make_float2(accn, 0.f);
}

// ============ device bodies for the fused GEMM kernels ============
// 3-pass split-bf16 MFMA GEMM, transposed output C^T[512][ML], no bias.
__device__ __forceinline__ void gemm3_body(const float* __restrict__ A,
                                           const u16* __restrict__ Bhi,
                                           const u16* __restrict__ Blo,
                                           float* __restrict__ C, int lin, int tid,
                                           u16* sAhi, u16* sAlo, u16* sBhi, u16* sBlo) {
    const int t = (lin & 7) * 128 + (lin >> 3);   // XCD-chunked swizzle (1024 blocks)
    const int bm = (t >> 2) * 128;
    const int bn = (t & 3) * 128;
    const int lane = tid & 63, wid = tid >> 6;
    const int wm = wid >> 1, wn = wid & 1;
    const int l15 = lane & 15, kg = lane >> 4;

    f32x4 acc[4][4] = {};

    for (int k0 = 0; k0 < 512; k0 += 64) {
        __syncthreads();
#pragma unroll
        for (int it = 0; it < 4; ++it) {
            const int ch = it * 256 + tid;
            const int row = ch >> 3, c = ch & 7;
            const float* ga = A + (size_t)(bm + row) * 512 + k0 + c * 8;
            float4 f0 = *(const float4*)ga;
            float4 f1 = *(const float4*)(ga + 4);
            float fs[8] = {f0.x, f0.y, f0.z, f0.w, f1.x, f1.y, f1.z, f1.w};
            u32 h[4], l[4];
#pragma unroll
            for (int p = 0; p < 4; ++p) {
                u32 u0 = __float_as_uint(fs[2 * p]);
                u32 u1 = __float_as_uint(fs[2 * p + 1]);
                h[p] = __builtin_amdgcn_perm(u1, u0, 0x07060302u);
                float r0 = fs[2 * p]     - __uint_as_float(u0 & 0xFFFF0000u);
                float r1 = fs[2 * p + 1] - __uint_as_float(u1 & 0xFFFF0000u);
                l[p] = __builtin_amdgcn_perm(__float_as_uint(r1), __float_as_uint(r0), 0x07060302u);
            }
            const int off = row * 64 + ((c ^ (row & 7)) << 3);
            *(uint4*)&sAhi[off] = make_uint4(h[0], h[1], h[2], h[3]);
            *(uint4*)&sAlo[off] = make_uint4(l[0], l[1], l[2], l[3]);
        }
#pragma unroll
        for (int it = 0; it < 4; ++it) {
            const int ch = it * 256 + tid;
            const int row = ch >> 3, c = ch & 7;
            const int off = row * 64 + ((c ^ (row & 7)) << 3);
            const size_t gg = (size_t)(bn + row) * 512 + k0 + c * 8;
            *(u16x8*)&sBhi[off] = *(const u16x8*)&Bhi[gg];
            *(u16x8*)&sBlo[off] = *(const u16x8*)&Blo[gg];
        }
        __syncthreads();
#pragma unroll
        for (int kk = 0; kk < 2; ++kk) {
            const int cbase = kk * 4 + kg;
            s16x8 ah[4], al[4], bh[4], bl[4];
#pragma unroll
            for (int mi = 0; mi < 4; ++mi) {
                const int row = wm * 64 + mi * 16 + l15;
                const int off = row * 64 + (((cbase ^ (row & 7))) << 3);
                ah[mi] = *(const s16x8*)&sAhi[off];
                al[mi] = *(const s16x8*)&sAlo[off];
            }
#pragma unroll
            for (int ni = 0; ni < 4; ++ni) {
                const int row = wn * 64 + ni * 16 + l15;
                const int off = row * 64 + (((cbase ^ (row & 7))) << 3);
                bh[ni] = *(const s16x8*)&sBhi[off];
                bl[ni] = *(const s16x8*)&sBlo[off];
            }
#pragma unroll
            for (int ni = 0; ni < 4; ++ni)
#pragma unroll
                for (int mi = 0; mi < 4; ++mi) {
                    acc[mi][ni] = __builtin_amdgcn_mfma_f32_16x16x32_bf16(ah[mi], bh[ni], acc[mi][ni], 0, 0, 0);
                    acc[mi][ni] = __builtin_amdgcn_mfma_f32_16x16x32_bf16(ah[mi], bl[ni], acc[mi][ni], 0, 0, 0);
                    acc[mi][ni] = __builtin_amdgcn_mfma_f32_16x16x32_bf16(al[mi], bh[ni], acc[mi][ni], 0, 0, 0);
                }
        }
    }
    // epilogue: transposed store (C/D layout: col = lane&15, row = (lane>>4)*4 + reg)
#pragma unroll
    for (int ni = 0; ni < 4; ++ni) {
        const int d = bn + wn * 64 + ni * 16 + l15;
#pragma unroll
        for (int mi = 0; mi < 4; ++mi) {
            const int rb = bm + wm * 64 + mi * 16 + (kg << 2);
            float4 o;
            o.x = acc[mi][ni][0]; o.y = acc[mi][ni][1];
            o.z = acc[mi][ni][2]; o.w = acc[mi][ni][3];
            *(float4*)&C[(size_t)d * ML + rb] = o;
        }
    }
}

// 1-pass RNE-bf16 MFMA GEMM with bias, bf16-packed row-major output.
__device__ __forceinline__ void gemm1_body(const float* __restrict__ A,
                                           const u16* __restrict__ Bhi,
                                           const float* __restrict__ bias,
                                           u16* __restrict__ Cv, int lin, int tid,
                                           u16* sAhi, u16* sBhi) {
    const int t = (lin & 7) * 128 + (lin >> 3);
    const int bm = (t >> 2) * 128;
    const int bn = (t & 3) * 128;
    const int lane = tid & 63, wid = tid >> 6;
    const int wm = wid >> 1, wn = wid & 1;
    const int l15 = lane & 15, kg = lane >> 4;

    f32x4 acc[4][4] = {};

    for (int k0 = 0; k0 < 512; k0 += 64) {
        __syncthreads();
#pragma unroll
        for (int it = 0; it < 4; ++it) {
            const int ch = it * 256 + tid;
            const int row = ch >> 3, c = ch & 7;
            const float* ga = A + (size_t)(bm + row) * 512 + k0 + c * 8;
            float4 f0 = *(const float4*)ga;
            float4 f1 = *(const float4*)(ga + 4);
            float fs[8] = {f0.x, f0.y, f0.z, f0.w, f1.x, f1.y, f1.z, f1.w};
            u32 h[4];
#pragma unroll
            for (int p = 0; p < 4; ++p) {
                u32 u0 = __float_as_uint(fs[2 * p]);
                u32 u1 = __float_as_uint(fs[2 * p + 1]);
                u32 h0 = u0 + 0x7FFF + ((u0 >> 16) & 1);
                u32 h1 = u1 + 0x7FFF + ((u1 >> 16) & 1);
                h[p] = __builtin_amdgcn_perm(h1, h0, 0x07060302u);
            }
            const int off = row * 64 + ((c ^ (row & 7)) << 3);
            *(uint4*)&sAhi[off] = make_uint4(h[0], h[1], h[2], h[3]);
        }
#pragma unroll
        for (int it = 0; it < 4; ++it) {
            const int ch = it * 256 + tid;
            const int row = ch >> 3, c = ch & 7;
            const int off = row * 64 + ((c ^ (row & 7)) << 3);
            const size_t gg = (size_t)(bn + row) * 512 + k0 + c * 8;
            *(u16x8*)&sBhi[off] = *(const u16x8*)&Bhi[gg];
        }
        __syncthreads();
#pragma unroll
        for (int kk = 0; kk < 2; ++kk) {
            const int cbase = kk * 4 + kg;
            s16x8 ah[4], bh[4];
#pragma unroll
            for (int mi = 0; mi < 4; ++mi) {
                const int row = wm * 64 + mi * 16 + l15;
                const int off = row * 64 + (((cbase ^ (row & 7))) << 3);
                ah[mi] = *(const s16x8*)&sAhi[off];
            }
#pragma unroll
            for (int ni = 0; ni < 4; ++ni) {
                const int row = wn * 64 + ni * 16 + l15;
                const int off = row * 64 + (((cbase ^ (row & 7))) << 3);
                bh[ni] = *(const s16x8*)&sBhi[off];
            }
#pragma unroll
            for (int ni = 0; ni < 4; ++ni)
#pragma unroll
                for (int mi = 0; mi < 4; ++mi)
                    acc[mi][ni] = __builtin_amdgcn_mfma_f32_16x16x32_bf16(ah[mi], bh[ni], acc[mi][ni], 0, 0, 0);
        }
    }
#pragma unroll
    for (int ni = 0; ni < 4; ++ni) {
        const int col = bn + wn * 64 + ni * 16 + l15;
        const float bvv = bias[col];
#pragma unroll
        for (int mi = 0; mi < 4; ++mi) {
            const int rb = bm + wm * 64 + mi * 16 + (kg << 2);
#pragma unroll
            for (int r = 0; r < 4; ++r) {
                float f = acc[mi][ni][r] + bvv;
                u32 u = __float_as_uint(f);
                Cv[(size_t)(rb + r) * 512 + col] = (u16)((u + 0x7FFF + ((u >> 16) & 1)) >> 16);
            }
        }
    }
}

// ============ prep_all: Wc=Wv@Wo and M=Wq@Wk^T tiles computed + split + transposed, plus bc ============
// grid 144: blocks 0..63 -> M tiles, 64..127 -> Wc tiles, 128..143 -> bc
__global__ __launch_bounds__(256) void prep_all(const float* __restrict__ Wq, const float* __restrict__ Wk,
                                                const float* __restrict__ Wv, const float* __restrict__ Wo,
                                                const float* __restrict__ bvec, const float* __restrict__ bo,
                                                u16* __restrict__ Mh, u16* __restrict__ Ml,
                                                u16* __restrict__ Wch, u16* __restrict__ Wcl,
                                                float* __restrict__ bc) {
    __shared__ float As[16][64];
    __shared__ float Ws[16][64];
    __shared__ float red[8][32];
    const int bx = blockIdx.x;
    const int tid = threadIdx.x;
    if (bx < 128) {
        const bool isM = bx < 64;
        const int id = bx & 63;
        const int bm = (id >> 3) * 64, bn = (id & 7) * 64;
        const int tx = tid & 15, ty = tid >> 4;
        float acc[4][4] = {};
        const int arow = tid >> 2, ak4 = tid & 3;
        const int wrow = tid >> 4, wc4 = tid & 15;
        const float* Abase = isM ? Wq : Wv;
        for (int k0 = 0; k0 < 512; k0 += 16) {
            float4 av = *(const float4*)&Abase[(size_t)(bm + arow) * 512 + k0 + ak4 * 4];
            float4 wv4;
            if (isM) wv4 = *(const float4*)&Wk[(size_t)(bn + arow) * 512 + k0 + ak4 * 4];
            else     wv4 = *(const float4*)&Wo[(size_t)(k0 + wrow) * 512 + bn + wc4 * 4];
            __syncthreads();
            As[ak4 * 4 + 0][arow] = av.x;
            As[ak4 * 4 + 1][arow] = av.y;
            As[ak4 * 4 + 2][arow] = av.z;
            As[ak4 * 4 + 3][arow] = av.w;
            if (isM) {
                Ws[ak4 * 4 + 0][arow] = wv4.x;
                Ws[ak4 * 4 + 1][arow] = wv4.y;
                Ws[ak4 * 4 + 2][arow] = wv4.z;
                Ws[ak4 * 4 + 3][arow] = wv4.w;
            } else {
                *(float4*)&Ws[wrow][wc4 * 4] = wv4;
            }
            __syncthreads();
#pragma unroll
            for (int k = 0; k < 16; ++k) {
                float4 a = *(const float4*)&As[k][ty * 4];
                float4 b = *(const float4*)&Ws[k][tx * 4];
                acc[0][0] += a.x * b.x; acc[0][1] += a.x * b.y; acc[0][2] += a.x * b.z; acc[0][3] += a.x * b.w;
                acc[1][0] += a.y * b.x; acc[1][1] += a.y * b.y; acc[1][2] += a.y * b.z; acc[1][3] += a.y * b.w;
                acc[2][0] += a.z * b.x; acc[2][1] += a.z * b.y; acc[2][2] += a.z * b.z; acc[2][3] += a.z * b.w;
                acc[3][0] += a.w * b.x; acc[3][1] += a.w * b.y; acc[3][2] += a.w * b.z; acc[3][3] += a.w * b.w;
            }
        }
        u16* dh = isM ? Mh : Wch;
        u16* dl = isM ? Ml : Wcl;
#pragma unroll
        for (int i = 0; i < 4; ++i)
#pragma unroll
            for (int j = 0; j < 4; ++j) {
                const int a = bm + ty * 4 + i;      // k index
                const int n = bn + tx * 4 + j;      // n index
                float f = acc[i][j];
                u32 u = __float_as_uint(f);
                u16 h = (u16)(u >> 16);
                float rem = f - __uint_as_float(u & 0xFFFF0000u);
                u32 ur = __float_as_uint(rem);
                u16 l = (u16)((ur + 0x7FFF + ((ur >> 16) & 1)) >> 16);
                dh[(size_t)n * 512 + a] = h;
                dl[(size_t)n * 512 + a] = l;
            }
    } else {
        // bc[n] = sum_j bv[j]*Wo[j][n] + bo[n] over n-range of 32
        const int n0 = (bx - 128) * 32;
        const int nl = tid & 31, jg = tid >> 5;
        float partial = 0.f;
        for (int s = 0; s < 64; ++s) {
            int j = jg + 8 * s;
            partial += bvec[j] * Wo[(size_t)j * 512 + n0 + nl];
        }
        red[jg][nl] = partial;
        __syncthreads();
        if (tid < 32) {
            float s2 = 0.f;
            for (int r2 = 0; r2 < 8; ++r2) s2 += red[r2][tid];
            bc[n0 + tid] = s2 + bo[n0 + tid];
        }
    }
}

// ============ proj_trans: q''-GEMM (1024 blocks) + keys-transpose (4096 blocks), 1:4 interleave ============
__global__ __launch_bounds__(256, 2) void proj_trans(const float* __restrict__ queries,
                                                     const u16* __restrict__ Mh, const u16* __restrict__ Ml,
                                                     float* __restrict__ Qt,
                                                     const float* __restrict__ keys,
                                                     float* __restrict__ Kt) {
    __shared__ __align__(16) u16 smem[4 * 128 * 64];  // 64 KB union
    const int g = blockIdx.x;
    const int q = g / 5, r = g % 5;
    const int tid = threadIdx.x;
    if (r == 4) {
        gemm3_body(queries, Mh, Ml, Qt, q, tid,
                   smem, smem + 8192, smem + 16384, smem + 24576);
    } else {
        float* Ts = (float*)smem;  // [64][65]
        const int tb = q * 4 + r;
        const int bd = (tb & 7) * 64;
        const int bm = (tb >> 3) * 64;
        const int rr = tid >> 2, c4 = tid & 3;
#pragma unroll
        for (int i = 0; i < 4; ++i) {
            const int c0 = (c4 + 4 * i) * 4;
            float4 v = *(const float4*)&keys[(size_t)(bm + rr) * DMODEL + bd + c0];
            Ts[rr * 65 + c0 + 0] = v.x; Ts[rr * 65 + c0 + 1] = v.y;
            Ts[rr * 65 + c0 + 2] = v.z; Ts[rr * 65 + c0 + 3] = v.w;
        }
        __syncthreads();
        const int dl = tid >> 2, m4 = tid & 3;
#pragma unroll
        for (int i = 0; i < 4; ++i) {
            const int m0 = (m4 + 4 * i) * 4;
            float4 o;
            o.x = Ts[(m0 + 0) * 65 + dl]; o.y = Ts[(m0 + 1) * 65 + dl];
            o.z = Ts[(m0 + 2) * 65 + dl]; o.w = Ts[(m0 + 3) * 65 + dl];
            *(float4*)&Kt[(size_t)(bd + dl) * ML + bm + m0] = o;
        }
    }
}

// ============ vgemm_reduce: V-GEMM (1024 blocks) + half-spectrum reduce (72 blocks) ============
__global__ __launch_bounds__(256, 2) void vgemm_reduce(const float* __restrict__ values,
                                                       const u16* __restrict__ Wch,
                                                       const float* __restrict__ bc,
                                                       u16* __restrict__ VOb,
                                                       const float2* __restrict__ Pp,
                                                       float2* __restrict__ Pred) {
    __shared__ __align__(16) u16 smem[2 * 128 * 64];  // 32 KB
    const int g = blockIdx.x;
    if (g < 1024) {
        gemm1_body(values, Wch, bc, VOb, g, threadIdx.x, smem, smem + 8192);
    } else {
        const int rb = g - 1024;           // 0..71
        const int b = rb / 9, jb = rb % 9;
        const int j = jb * 256 + threadIdx.x;
        if (j <= 2048) {
            float sr = 0.f, si = 0.f;
            const float2* base = Pp + (size_t)b * NGRP * PPH + j;
            for (int gg = 0; gg < NGRP; ++gg) {
                float2 p = base[(size_t)gg * PPH];
                sr += p.x;
                si += p.y;
            }
            Pred[(size_t)b * PPH + j] = make_float2(sr, si);
        }
    }
}

// 8 blocks: Hermitian reconstruction + inverse FFT (conj->fwd->Re), scaled; no LDS writeback
__global__ __launch_bounds__(256) void ifft_mean(const float2* __restrict__ Pred,
                                                 float* __restrict__ mv) {
    __shared__ float lre[4096];
    __shared__ float lim[4096];
    constexpr int REV16[16] = {0, 8, 4, 12, 2, 10, 6, 14, 1, 9, 5, 13, 3, 11, 7, 15};
    const int t = threadIdx.x;
    const int b = blockIdx.x;
    for (int j = t; j < 4096; j += 256) {
        float2 p;
        if (j <= 2048) {
            p = Pred[(size_t)b * PPH + j];
        } else {
            p = Pred[(size_t)b * PPH + (4096 - j)];
            p.y = -p.y;  // Hermitian mirror
        }
        int key = (j >> 8) & 15;
        int ph = j ^ ((key & 3) << 2) ^ ((key & 1) << 4);
        lre[ph] = p.x;
        lim[ph] = -p.y;  // conj for inverse transform
    }
    __syncthreads();
    float ozr[16], ozi[16];
    fft4096_r16_core<false>(lre, lim, t, ozr, ozi);
    const float scale = 1.0f / (4096.0f * 512.0f);
#pragma unroll
    for (int i = 0; i < 16; ++i)
        mv[(size_t)b * 4096 + t + 256 * i] = ozr[REV16[i]] * scale;
}

// single block, 1024 threads: batch-mean, iterative top-8 argmax via shfl, per-batch softmax
__global__ __launch_bounds__(1024) void topk_softmax(const float* __restrict__ mv,
                                                     int* __restrict__ idxO,
                                                     float* __restrict__ tcO) {
    __shared__ float vals[4096];
    __shared__ float wv[16];
    __shared__ int wix[16];
    __shared__ int sidx[TOPK];
    const int tid = threadIdx.x;
    const int lane = tid & 63, wvid = tid >> 6;
    for (int j = tid; j < 4096; j += 1024) {
        float s = 0.f;
        for (int b = 0; b < BB; ++b) s += mv[(size_t)b * 4096 + j];
        vals[j] = s * 0.125f;
    }
    __syncthreads();
    for (int k = 0; k < TOPK; ++k) {
        float best = -INFINITY;
        int bi = 0x7fffffff;
        for (int j = tid; j < 4096; j += 1024) {
            float v = vals[j];
            if (v > best) { best = v; bi = j; }
        }
#pragma unroll
        for (int off = 32; off > 0; off >>= 1) {
            float ov = __shfl_down(best, off);
            int oi = __shfl_down(bi, off);
            if (ov > best || (ov == best && oi < bi)) { best = ov; bi = oi; }
        }
        if (lane == 0) { wv[wvid] = best; wix[wvid] = bi; }
        __syncthreads();
        if (wvid == 0) {
            best = (lane < 16) ? wv[lane] : -INFINITY;
            bi = (lane < 16) ? wix[lane] : 0x7fffffff;
#pragma unroll
            for (int off = 8; off > 0; off >>= 1) {
                float ov = __shfl_down(best, off);
                int oi = __shfl_down(bi, off);
                if (ov > best || (ov == best && oi < bi)) { best = ov; bi = oi; }
            }
            if (lane == 0) {
                sidx[k] = bi;
                idxO[k] = bi;
                vals[bi] = -INFINITY;
            }
        }
        __syncthreads();
    }
    if (tid < BB) {
        float w[TOPK];
        float m = -INFINITY;
        for (int k = 0; k < TOPK; ++k) {
            w[k] = mv[(size_t)tid * 4096 + sidx[k]];
            m = fmaxf(m, w[k]);
        }
        float s = 0.f;
        for (int k = 0; k < TOPK; ++k) { w[k] = expf(w[k] - m); s += w[k]; }
        float inv = 1.0f / s;
        for (int k = 0; k < TOPK; ++k) tcO[tid * TOPK + k] = w[k] * inv;
    }
}

// out[b,l,:] = sum_k tc[b,k] * VO_bf16[b,(l+idx[k])%L,:]  — 8 bf16/thread via uint4
__global__ __launch_bounds__(256) void gather_out(const u16* __restrict__ VO,
                                                  const int* __restrict__ idx,
                                                  const float* __restrict__ tc,
                                                  float* __restrict__ out) {
    const int e = blockIdx.x * 256 + threadIdx.x;
    const int d8 = e & 63;           // 8-elem chunk within row
    const int l = (e >> 6) & 4095;
    const int b = e >> 18;
    float s[8] = {};
#pragma unroll
    for (int k = 0; k < TOPK; ++k) {
        const int src = (l + idx[k]) & 4095;
        const float w = tc[b * TOPK + k];
        uint4 v = *(const uint4*)&VO[((size_t)(b * 4096 + src)) * 512 + d8 * 8];
        s[0] += w * __uint_as_float(v.x << 16);
        s[1] += w * __uint_as_float(v.x & 0xFFFF0000u);
        s[2] += w * __uint_as_float(v.y << 16);
        s[3] += w * __uint_as_float(v.y & 0xFFFF0000u);
        s[4] += w * __uint_as_float(v.z << 16);
        s[5] += w * __uint_as_float(v.z & 0xFFFF0000u);
        s[6] += w * __uint_as_float(v.w << 16);
        s[7] += w * __uint_as_float(v.w & 0xFFFF0000u);
    }
    const size_t ob = ((size_t)(b * 4096 + l)) * 512 + d8 * 8;
    *(float4*)&out[ob]     = make_float4(s[0], s[1], s[2], s[3]);
    *(float4*)&out[ob + 4] = make_float4(s[4], s[5], s[6], s[7]);
}

extern "C" void kernel_launch(void* const* d_in, const int* in_sizes, int n_in,
                              void* d_out, int out_size, void* d_ws, size_t ws_size,
                              hipStream_t stream) {
    const float* queries = (const float*)d_in[0];
    const float* keys    = (const float*)d_in[1];
    const float* values  = (const float*)d_in[2];
    const float* Wq = (const float*)d_in[3];
    const float* Wk = (const float*)d_in[5];
    const float* Wv = (const float*)d_in[7];
    const float* bv = (const float*)d_in[8];
    const float* Wo = (const float*)d_in[9];
    const float* bo = (const float*)d_in[10];
    float* out = (float*)d_out;

    float* ws = (float*)d_ws;
    const size_t SZ = (size_t)ML * DMODEL;           // 16,777,216 floats
    float* Qt    = ws;                                // q''^T [512][ML]; reused as VO (bf16)
    float* Kt    = ws + SZ;                           // keys^T
    float* Pp    = ws + 2 * SZ;                       // BB*NGRP*PPH*2 floats ~ 33.6 MB
    float* Pred  = Pp + (size_t)BB * NGRP * PPH * 2;  // BB*PPH*2 floats
    float* mv    = Pred + (size_t)BB * PPH * 2;       // 32768
    int*   idx   = (int*)(mv + 32768);                // 16
    float* tc    = mv + 32768 + 16;                   // 64 (pad 96)
    float* bc    = mv + 32768 + 96;                   // 512
    u16* Mh  = (u16*)(bc + 512);
    u16* Ml  = Mh + 262144;
    u16* Wch = Ml + 262144;
    u16* Wcl = Wch + 262144;
    u16* VOb = (u16*)Qt;  // bf16 VO, reuses Qt (dead after fft_cross)

    dim3 blk(256);

    // 1) weight prep (all fused): M/Wc tiles -> split+transposed bf16; bc
    prep_all<<<dim3(144), blk, 0, stream>>>(Wq, Wk, Wv, Wo, bv, bo, Mh, Ml, Wch, Wcl, bc);

    // 2) q''-GEMM + keys-transpose fused (overlap compute-bound with BW-bound)
    proj_trans<<<dim3(5120), blk, 0, stream>>>(queries, Mh, Ml, Qt, keys, Kt);

    // 3) correlation FFT (Hermitian half-spectrum)
    fft_cross<<<dim3(BB * NGRP), blk, 0, stream>>>(Qt, Kt, Pp);

    // 4) V-GEMM + spectrum reduce fused
    vgemm_reduce<<<dim3(1024 + 72), blk, 0, stream>>>(values, Wch, bc, VOb, (const float2*)Pp, (float2*)Pred);

    // 5) inverse FFT per batch
    ifft_mean<<<dim3(BB), blk, 0, stream>>>((const float2*)Pred, mv);

    // 6) top-k + softmax
    topk_softmax<<<dim3(1), dim3(1024), 0, stream>>>(mv, idx, tc);

    // 7) weighted gather to output
    gather_out<<<dim3((BB * LSEQ * (DMODEL / 8)) / 256), blk, 0, stream>>>(VOb, idx, tc, out);
}

// Round 9
// 276.303 us; speedup vs baseline: 6.4164x; 1.2118x over previous
//
#include <hip/hip_runtime.h>
#include <math.h>

#define LSEQ 4096
#define DMODEL 512
#define BB 8
#define TOPK 8
#define ML (BB * LSEQ)          // 32768 rows
#define FFT_CH 2                // channels per fft_cross block
#define NGRP (DMODEL / FFT_CH)  // 256 groups per batch
#define PPH 2052                // float2 stride of half-spectrum (2049 used, padded)

typedef unsigned short u16;
typedef unsigned int u32;
typedef float f32x4 __attribute__((ext_vector_type(4)));
typedef short s16x8 __attribute__((ext_vector_type(8)));
typedef u16 u16x8 __attribute__((ext_vector_type(8)));

__device__ __forceinline__ u16 rne_bf16(float f) {
    u32 u = __float_as_uint(f);
    return (u16)((u + 0x7FFF + ((u >> 16) & 1)) >> 16);
}

// ==================== 16-pt FFT, fully unrolled DIF (output bit-reversed in regs) ====================
__device__ __forceinline__ void fft16(float (&zr)[16], float (&zi)[16]) {
    const float C1 = 0.92387953251128674f, S1 = 0.38268343236508978f, R2 = 0.70710678118654752f;
#define BF0(i, j) { float ar=zr[i],ai=zi[i],br=zr[j],bi=zi[j]; zr[i]=ar+br; zi[i]=ai+bi; zr[j]=ar-br; zi[j]=ai-bi; }
#define BFW(i, j, wr, wi) { float ar=zr[i],ai=zi[i],br=zr[j],bi=zi[j]; zr[i]=ar+br; zi[i]=ai+bi; float dr=ar-br, di=ai-bi; zr[j]=dr*(wr)-di*(wi); zi[j]=dr*(wi)+di*(wr); }
#define BFI(i, j) { float ar=zr[i],ai=zi[i],br=zr[j],bi=zi[j]; zr[i]=ar+br; zi[i]=ai+bi; float dr=ar-br, di=ai-bi; zr[j]=di; zi[j]=-dr; }
    BF0(0, 8); BFW(1, 9, C1, -S1); BFW(2, 10, R2, -R2); BFW(3, 11, S1, -C1);
    BFI(4, 12); BFW(5, 13, -S1, -C1); BFW(6, 14, -R2, -R2); BFW(7, 15, -C1, -S1);
    BF0(0, 4); BFW(1, 5, R2, -R2); BFI(2, 6); BFW(3, 7, -R2, -R2);
    BF0(8, 12); BFW(9, 13, R2, -R2); BFI(10, 14); BFW(11, 15, -R2, -R2);
    BF0(0, 2); BFI(1, 3); BF0(4, 6); BFI(5, 7);
    BF0(8, 10); BFI(9, 11); BF0(12, 14); BFI(13, 15);
    BF0(0, 1); BF0(2, 3); BF0(4, 5); BF0(6, 7);
    BF0(8, 9); BF0(10, 11); BF0(12, 13); BF0(14, 15);
#undef BF0
#undef BFW
#undef BFI
}

// 3-level radix-16 4096-pt FFT core, chained twiddles.
// Input staged phys-swizzled: phys(n) = n ^ (((n>>8)&3)<<2) ^ (((n>>8)&1)<<4).
// Level-C results returned in ozr/ozi: thread t holds Z[t+256*k2] in slot REV16[k2].
// If WRITEBACK: also writes natural order to LDS and syncs (for mirror reads).
template <bool WRITEBACK>
__device__ __forceinline__ void fft4096_r16_core(float* __restrict__ lre, float* __restrict__ lim, int t,
                                                 float (&ozr)[16], float (&ozi)[16]) {
    constexpr int REV16[16] = {0, 8, 4, 12, 2, 10, 6, 14, 1, 9, 5, 13, 3, 11, 7, 15};
    float zr[16], zi[16];
#pragma unroll
    for (int gg = 0; gg < 16; ++gg) {
        int n = 256 * gg + t;
        int p = n ^ ((gg & 3) << 2) ^ ((gg & 1) << 4);
        zr[gg] = lre[p]; zi[gg] = lim[p];
    }
    fft16(zr, zi);
    {
        const int n1 = t >> 4;
        float w1i, w1r;
        __sincosf(-0.0245436926061702596f * (float)n1, &w1i, &w1r);  // -pi/128 * n1
        float wr = 1.f, wi = 0.f;
#pragma unroll
        for (int k0 = 0; k0 < 16; ++k0) {
            float vr = zr[REV16[k0]], vi = zi[REV16[k0]];
            if (k0) {
                float nr = wr * w1r - wi * w1i;
                wi = wr * w1i + wi * w1r;
                wr = nr;
                float tr = vr * wr - vi * wi;
                vi = vr * wi + vi * wr;
                vr = tr;
            }
            int n = 256 * k0 + t;
            int p = n ^ ((k0 & 3) << 2) ^ ((k0 & 1) << 4);
            lre[p] = vr; lim[p] = vi;
        }
    }
    __syncthreads();
    {
        const int k0 = t >> 4, n2 = t & 15;
        const int x0 = ((k0 & 3) << 2) | ((k0 & 1) << 4);
#pragma unroll
        for (int gg = 0; gg < 16; ++gg) {
            int n = 256 * k0 + 16 * gg + n2;
            zr[gg] = lre[n ^ x0]; zi[gg] = lim[n ^ x0];
        }
        fft16(zr, zi);
        float wbi, wbr, wsi, wsr;
        __sincosf(-0.00153398078788564123f * (float)(n2 * k0), &wbi, &wbr);  // -pi/2048 * n2*k0
        __sincosf(-0.0245436926061702596f * (float)n2, &wsi, &wsr);          // -pi/128 * n2
        float wr = wbr, wi = wbi;
#pragma unroll
        for (int k1 = 0; k1 < 16; ++k1) {
            float vr = zr[REV16[k1]], vi = zi[REV16[k1]];
            if (k1) {
                float nr = wr * wsr - wi * wsi;
                wi = wr * wsi + wi * wsr;
                wr = nr;
            }
            float tr = vr * wr - vi * wi;
            vi = vr * wi + vi * wr;
            vr = tr;
            int n = 256 * k0 + 16 * k1 + n2;
            lre[n ^ x0] = vr; lim[n ^ x0] = vi;
        }
    }
    __syncthreads();
    {
        const int k0 = t & 15, k1 = t >> 4;
        const int nb4 = 64 * k0 + 4 * k1;
        const int xv = (k0 & 3) | ((k0 & 1) << 2);
#pragma unroll
        for (int i = 0; i < 4; ++i) {
            int p4 = (nb4 + i) ^ xv;
            float4 fr = *(const float4*)&lre[4 * p4];
            float4 fi = *(const float4*)&lim[4 * p4];
            ozr[4 * i + 0] = fr.x; ozr[4 * i + 1] = fr.y; ozr[4 * i + 2] = fr.z; ozr[4 * i + 3] = fr.w;
            ozi[4 * i + 0] = fi.x; ozi[4 * i + 1] = fi.y; ozi[4 * i + 2] = fi.z; ozi[4 * i + 3] = fi.w;
        }
        fft16(ozr, ozi);
        if constexpr (WRITEBACK) {
            __syncthreads();
#pragma unroll
            for (int r = 0; r < 16; ++r) {
                const int k2 = REV16[r];
                lre[t + 256 * k2] = ozr[r];
                lim[t + 256 * k2] = ozi[r];
            }
            __syncthreads();
        }
    }
}

// grid: BB*NGRP blocks; block (b,g): channels d = g*FFT_CH..+1.  INPUTS NOW bf16.
__global__ __launch_bounds__(256) void fft_cross(const u16* __restrict__ Qtb,
                                                 const u16* __restrict__ Ktb,
                                                 float* __restrict__ Ppart) {
    __shared__ float lre[4096];
    __shared__ float lim[4096];
    constexpr int REV16[16] = {0, 8, 4, 12, 2, 10, 6, 14, 1, 9, 5, 13, 3, 11, 7, 15};
    const int t = threadIdx.x;
    const int b = blockIdx.x / NGRP;
    const int g = blockIdx.x % NGRP;

    float2 acc[8];
#pragma unroll
    for (int i = 0; i < 8; ++i) acc[i] = make_float2(0.f, 0.f);
    float accn = 0.f;  // Nyquist bin (j=2048), real

    const uint4* q8 = (const uint4*)(Qtb + (size_t)(g * FFT_CH) * ML + (size_t)b * LSEQ);
    const uint4* k8 = (const uint4*)(Ktb + (size_t)(g * FFT_CH) * ML + (size_t)b * LSEQ);

    uint4 pq[2], pk[2];
    pq[0] = q8[t]; pq[1] = q8[t + 256];
    pk[0] = k8[t]; pk[1] = k8[t + 256];

    for (int c = 0; c < FFT_CH; ++c) {
        __syncthreads();  // prev channel's mirror-reads done
#pragma unroll
        for (int i = 0; i < 2; ++i) {
            const int u = t + 256 * i;          // uint4 index (8 bf16)
            const uint4 vq = pq[i], vk = pk[i];
#pragma unroll
            for (int hh = 0; hh < 2; ++hh) {
                const int v = 2 * u + hh;       // float4-block index
                const int key = (v >> 6) & 15;
                const int p4 = v ^ (key & 3) ^ ((key & 1) << 2);
                const u32 w0 = hh ? vq.z : vq.x;
                const u32 w1 = hh ? vq.w : vq.y;
                float4 fa = make_float4(__uint_as_float(w0 << 16), __uint_as_float(w0 & 0xFFFF0000u),
                                        __uint_as_float(w1 << 16), __uint_as_float(w1 & 0xFFFF0000u));
                *(float4*)&lre[4 * p4] = fa;
                const u32 x0 = hh ? vk.z : vk.x;
                const u32 x1 = hh ? vk.w : vk.y;
                float4 fb = make_float4(__uint_as_float(x0 << 16), __uint_as_float(x0 & 0xFFFF0000u),
                                        __uint_as_float(x1 << 16), __uint_as_float(x1 & 0xFFFF0000u));
                *(float4*)&lim[4 * p4] = fb;
            }
        }
        if (c + 1 < FFT_CH) {
            const uint4* qn = q8 + (size_t)(c + 1) * (ML / 8);
            const uint4* kn = k8 + (size_t)(c + 1) * (ML / 8);
            pq[0] = qn[t]; pq[1] = qn[t + 256];
            pk[0] = kn[t]; pk[1] = kn[t + 256];
        }
        __syncthreads();
        float ozr[16], ozi[16];
        fft4096_r16_core<true>(lre, lim, t, ozr, ozi);
        // cross-spectrum: own bins from registers, mirror bins from LDS
#pragma unroll
        for (int i = 0; i < 8; ++i) {
            const int j = i * 256 + t;
            const int nj = (4096 - j) & 4095;
            const int r = REV16[i];
            float zfr = ozr[r], zfi = ozi[r];
            float znr = lre[nj], zni = lim[nj];
            float qr = 0.5f * (zfr + znr);
            float qi = 0.5f * (zfi - zni);
            float kr = 0.5f * (zfi + zni);
            float ki = -0.5f * (zfr - znr);
            acc[i].x += qr * kr + qi * ki;
            acc[i].y += qi * kr - qr * ki;
        }
        if (t == 0) accn += ozr[1] * ozi[1];  // bin 2048 = slot REV16[8]=1 of thread 0
    }
    float2* Pp = (float2*)Ppart + (size_t)blockIdx.x * PPH;
#pragma unroll
    for (int i = 0; i < 8; ++i) Pp[i * 256 + t] = acc[i];
    if (t == 0) Pp[2048] = make_float2(accn, 0.f);
}

// ============ 1-pass RNE-bf16 MFMA GEMM bodies ============
// Q: C^T bf16 [512][ML], no bias.
__device__ __forceinline__ void gemmQ_body(const float* __restrict__ A,
                                           const u16* __restrict__ Bhi,
                                           u16* __restrict__ Ct, int lin, int tid,
                                           u16* sAhi, u16* sBhi) {
    const int t = (lin & 7) * 128 + (lin >> 3);
    const int bm = (t >> 2) * 128;
    const int bn = (t & 3) * 128;
    const int lane = tid & 63, wid = tid >> 6;
    const int wm = wid >> 1, wn = wid & 1;
    const int l15 = lane & 15, kg = lane >> 4;

    f32x4 acc[4][4] = {};

    for (int k0 = 0; k0 < 512; k0 += 64) {
        __syncthreads();
#pragma unroll
        for (int it = 0; it < 4; ++it) {
            const int ch = it * 256 + tid;
            const int row = ch >> 3, c = ch & 7;
            const float* ga = A + (size_t)(bm + row) * 512 + k0 + c * 8;
            float4 f0 = *(const float4*)ga;
            float4 f1 = *(const float4*)(ga + 4);
            float fs[8] = {f0.x, f0.y, f0.z, f0.w, f1.x, f1.y, f1.z, f1.w};
            u32 h[4];
#pragma unroll
            for (int p = 0; p < 4; ++p) {
                u32 u0 = __float_as_uint(fs[2 * p]);
                u32 u1 = __float_as_uint(fs[2 * p + 1]);
                u32 h0 = u0 + 0x7FFF + ((u0 >> 16) & 1);
                u32 h1 = u1 + 0x7FFF + ((u1 >> 16) & 1);
                h[p] = __builtin_amdgcn_perm(h1, h0, 0x07060302u);
            }
            const int off = row * 64 + ((c ^ (row & 7)) << 3);
            *(uint4*)&sAhi[off] = make_uint4(h[0], h[1], h[2], h[3]);
        }
#pragma unroll
        for (int it = 0; it < 4; ++it) {
            const int ch = it * 256 + tid;
            const int row = ch >> 3, c = ch & 7;
            const int off = row * 64 + ((c ^ (row & 7)) << 3);
            const size_t gg = (size_t)(bn + row) * 512 + k0 + c * 8;
            *(u16x8*)&sBhi[off] = *(const u16x8*)&Bhi[gg];
        }
        __syncthreads();
#pragma unroll
        for (int kk = 0; kk < 2; ++kk) {
            const int cbase = kk * 4 + kg;
            s16x8 ah[4], bh[4];
#pragma unroll
            for (int mi = 0; mi < 4; ++mi) {
                const int row = wm * 64 + mi * 16 + l15;
                const int off = row * 64 + (((cbase ^ (row & 7))) << 3);
                ah[mi] = *(const s16x8*)&sAhi[off];
            }
#pragma unroll
            for (int ni = 0; ni < 4; ++ni) {
                const int row = wn * 64 + ni * 16 + l15;
                const int off = row * 64 + (((cbase ^ (row & 7))) << 3);
                bh[ni] = *(const s16x8*)&sBhi[off];
            }
#pragma unroll
            for (int ni = 0; ni < 4; ++ni)
#pragma unroll
                for (int mi = 0; mi < 4; ++mi)
                    acc[mi][ni] = __builtin_amdgcn_mfma_f32_16x16x32_bf16(ah[mi], bh[ni], acc[mi][ni], 0, 0, 0);
        }
    }
    // transposed bf16 store (C/D layout: col = lane&15, row = (lane>>4)*4 + reg)
#pragma unroll
    for (int ni = 0; ni < 4; ++ni) {
        const int d = bn + wn * 64 + ni * 16 + l15;
#pragma unroll
        for (int mi = 0; mi < 4; ++mi) {
            const int rb = bm + wm * 64 + mi * 16 + (kg << 2);
            ushort4 o;
            o.x = rne_bf16(acc[mi][ni][0]); o.y = rne_bf16(acc[mi][ni][1]);
            o.z = rne_bf16(acc[mi][ni][2]); o.w = rne_bf16(acc[mi][ni][3]);
            *(ushort4*)&Ct[(size_t)d * ML + rb] = o;
        }
    }
}

// V: bf16 row-major with bias.
__device__ __forceinline__ void gemm1_body(const float* __restrict__ A,
                                           const u16* __restrict__ Bhi,
                                           const float* __restrict__ bias,
                                           u16* __restrict__ Cv, int lin, int tid,
                                           u16* sAhi, u16* sBhi) {
    const int t = (lin & 7) * 128 + (lin >> 3);
    const int bm = (t >> 2) * 128;
    const int bn = (t & 3) * 128;
    const int lane = tid & 63, wid = tid >> 6;
    const int wm = wid >> 1, wn = wid & 1;
    const int l15 = lane & 15, kg = lane >> 4;

    f32x4 acc[4][4] = {};

    for (int k0 = 0; k0 < 512; k0 += 64) {
        __syncthreads();
#pragma unroll
        for (int it = 0; it < 4; ++it) {
            const int ch = it * 256 + tid;
            const int row = ch >> 3, c = ch & 7;
            const float* ga = A + (size_t)(bm + row) * 512 + k0 + c * 8;
            float4 f0 = *(const float4*)ga;
            float4 f1 = *(const float4*)(ga + 4);
            float fs[8] = {f0.x, f0.y, f0.z, f0.w, f1.x, f1.y, f1.z, f1.w};
            u32 h[4];
#pragma unroll
            for (int p = 0; p < 4; ++p) {
                u32 u0 = __float_as_uint(fs[2 * p]);
                u32 u1 = __float_as_uint(fs[2 * p + 1]);
                u32 h0 = u0 + 0x7FFF + ((u0 >> 16) & 1);
                u32 h1 = u1 + 0x7FFF + ((u1 >> 16) & 1);
                h[p] = __builtin_amdgcn_perm(h1, h0, 0x07060302u);
            }
            const int off = row * 64 + ((c ^ (row & 7)) << 3);
            *(uint4*)&sAhi[off] = make_uint4(h[0], h[1], h[2], h[3]);
        }
#pragma unroll
        for (int it = 0; it < 4; ++it) {
            const int ch = it * 256 + tid;
            const int row = ch >> 3, c = ch & 7;
            const int off = row * 64 + ((c ^ (row & 7)) << 3);
            const size_t gg = (size_t)(bn + row) * 512 + k0 + c * 8;
            *(u16x8*)&sBhi[off] = *(const u16x8*)&Bhi[gg];
        }
        __syncthreads();
#pragma unroll
        for (int kk = 0; kk < 2; ++kk) {
            const int cbase = kk * 4 + kg;
            s16x8 ah[4], bh[4];
#pragma unroll
            for (int mi = 0; mi < 4; ++mi) {
                const int row = wm * 64 + mi * 16 + l15;
                const int off = row * 64 + (((cbase ^ (row & 7))) << 3);
                ah[mi] = *(const s16x8*)&sAhi[off];
            }
#pragma unroll
            for (int ni = 0; ni < 4; ++ni) {
                const int row = wn * 64 + ni * 16 + l15;
                const int off = row * 64 + (((cbase ^ (row & 7))) << 3);
                bh[ni] = *(const s16x8*)&sBhi[off];
            }
#pragma unroll
            for (int ni = 0; ni < 4; ++ni)
#pragma unroll
                for (int mi = 0; mi < 4; ++mi)
                    acc[mi][ni] = __builtin_amdgcn_mfma_f32_16x16x32_bf16(ah[mi], bh[ni], acc[mi][ni], 0, 0, 0);
        }
    }
#pragma unroll
    for (int ni = 0; ni < 4; ++ni) {
        const int col = bn + wn * 64 + ni * 16 + l15;
        const float bvv = bias[col];
#pragma unroll
        for (int mi = 0; mi < 4; ++mi) {
            const int rb = bm + wm * 64 + mi * 16 + (kg << 2);
#pragma unroll
            for (int r = 0; r < 4; ++r)
                Cv[(size_t)(rb + r) * 512 + col] = rne_bf16(acc[mi][ni][r] + bvv);
        }
    }
}

// ============ prep_all: M = Wq@Wk^T and Wc = Wv@Wo -> RNE bf16 transposed [N][K]; plus bc ============
// grid 144: 0..63 -> M tiles, 64..127 -> Wc tiles, 128..143 -> bc
__global__ __launch_bounds__(256) void prep_all(const float* __restrict__ Wq, const float* __restrict__ Wk,
                                                const float* __restrict__ Wv, const float* __restrict__ Wo,
                                                const float* __restrict__ bvec, const float* __restrict__ bo,
                                                u16* __restrict__ Mh, u16* __restrict__ Wch,
                                                float* __restrict__ bc) {
    __shared__ float As[16][64];
    __shared__ float Ws[16][64];
    __shared__ float red[8][32];
    const int bx = blockIdx.x;
    const int tid = threadIdx.x;
    if (bx < 128) {
        const bool isM = bx < 64;
        const int id = bx & 63;
        const int bm = (id >> 3) * 64, bn = (id & 7) * 64;
        const int tx = tid & 15, ty = tid >> 4;
        float acc[4][4] = {};
        const int arow = tid >> 2, ak4 = tid & 3;
        const int wrow = tid >> 4, wc4 = tid & 15;
        const float* Abase = isM ? Wq : Wv;
        for (int k0 = 0; k0 < 512; k0 += 16) {
            float4 av = *(const float4*)&Abase[(size_t)(bm + arow) * 512 + k0 + ak4 * 4];
            float4 wv4;
            if (isM) wv4 = *(const float4*)&Wk[(size_t)(bn + arow) * 512 + k0 + ak4 * 4];
            else     wv4 = *(const float4*)&Wo[(size_t)(k0 + wrow) * 512 + bn + wc4 * 4];
            __syncthreads();
            As[ak4 * 4 + 0][arow] = av.x;
            As[ak4 * 4 + 1][arow] = av.y;
            As[ak4 * 4 + 2][arow] = av.z;
            As[ak4 * 4 + 3][arow] = av.w;
            if (isM) {
                Ws[ak4 * 4 + 0][arow] = wv4.x;
                Ws[ak4 * 4 + 1][arow] = wv4.y;
                Ws[ak4 * 4 + 2][arow] = wv4.z;
                Ws[ak4 * 4 + 3][arow] = wv4.w;
            } else {
                *(float4*)&Ws[wrow][wc4 * 4] = wv4;
            }
            __syncthreads();
#pragma unroll
            for (int k = 0; k < 16; ++k) {
                float4 a = *(const float4*)&As[k][ty * 4];
                float4 b = *(const float4*)&Ws[k][tx * 4];
                acc[0][0] += a.x * b.x; acc[0][1] += a.x * b.y; acc[0][2] += a.x * b.z; acc[0][3] += a.x * b.w;
                acc[1][0] += a.y * b.x; acc[1][1] += a.y * b.y; acc[1][2] += a.y * b.z; acc[1][3] += a.y * b.w;
                acc[2][0] += a.z * b.x; acc[2][1] += a.z * b.y; acc[2][2] += a.z * b.z; acc[2][3] += a.z * b.w;
                acc[3][0] += a.w * b.x; acc[3][1] += a.w * b.y; acc[3][2] += a.w * b.z; acc[3][3] += a.w * b.w;
            }
        }
        u16* dh = isM ? Mh : Wch;
#pragma unroll
        for (int i = 0; i < 4; ++i)
#pragma unroll
            for (int j = 0; j < 4; ++j) {
                const int a = bm + ty * 4 + i;      // k index
                const int n = bn + tx * 4 + j;      // n index
                dh[(size_t)n * 512 + a] = rne_bf16(acc[i][j]);
            }
    } else {
        const int n0 = (bx - 128) * 32;
        const int nl = tid & 31, jg = tid >> 5;
        float partial = 0.f;
        for (int s = 0; s < 64; ++s) {
            int j = jg + 8 * s;
            partial += bvec[j] * Wo[(size_t)j * 512 + n0 + nl];
        }
        red[jg][nl] = partial;
        __syncthreads();
        if (tid < 32) {
            float s2 = 0.f;
            for (int r2 = 0; r2 < 8; ++r2) s2 += red[r2][tid];
            bc[n0 + tid] = s2 + bo[n0 + tid];
        }
    }
}

// ============ proj3: Q-GEMM (1024) + V-GEMM (1024) + keys-transpose->bf16 (4096), 6144 blocks ============
__global__ __launch_bounds__(256, 4) void proj3(const float* __restrict__ queries,
                                                const u16* __restrict__ Mh, u16* __restrict__ Qtb,
                                                const float* __restrict__ values,
                                                const u16* __restrict__ Wch, const float* __restrict__ bc,
                                                u16* __restrict__ VOb,
                                                const float* __restrict__ keys, u16* __restrict__ Ktb) {
    __shared__ __align__(16) u16 smem[2 * 128 * 64];  // 32 KB union
    const int g = blockIdx.x;
    const int q = g / 6, r = g % 6;
    const int tid = threadIdx.x;
    if (r == 0) {
        gemmQ_body(queries, Mh, Qtb, q, tid, smem, smem + 8192);
    } else if (r == 1) {
        gemm1_body(values, Wch, bc, VOb, q, tid, smem, smem + 8192);
    } else {
        float* Ts = (float*)smem;  // [64][65]
        const int tb = q * 4 + (r - 2);
        const int bd = (tb & 7) * 64;
        const int bm = (tb >> 3) * 64;
        const int rr = tid >> 2, c4 = tid & 3;
#pragma unroll
        for (int i = 0; i < 4; ++i) {
            const int c0 = (c4 + 4 * i) * 4;
            float4 v = *(const float4*)&keys[(size_t)(bm + rr) * DMODEL + bd + c0];
            Ts[rr * 65 + c0 + 0] = v.x; Ts[rr * 65 + c0 + 1] = v.y;
            Ts[rr * 65 + c0 + 2] = v.z; Ts[rr * 65 + c0 + 3] = v.w;
        }
        __syncthreads();
        const int dl = tid >> 2, m4 = tid & 3;
#pragma unroll
        for (int i = 0; i < 4; ++i) {
            const int m0 = (m4 + 4 * i) * 4;
            ushort4 o;
            o.x = rne_bf16(Ts[(m0 + 0) * 65 + dl]);
            o.y = rne_bf16(Ts[(m0 + 1) * 65 + dl]);
            o.z = rne_bf16(Ts[(m0 + 2) * 65 + dl]);
            o.w = rne_bf16(Ts[(m0 + 3) * 65 + dl]);
            *(ushort4*)&Ktb[(size_t)(bd + dl) * ML + bm + m0] = o;
        }
    }
}

// sum NGRP half-spectra. grid (9, BB)
__global__ __launch_bounds__(256) void reduce_ppart(const float2* __restrict__ Pp,
                                                    float2* __restrict__ Pred) {
    const int j = blockIdx.x * 256 + threadIdx.x;
    const int b = blockIdx.y;
    if (j > 2048) return;
    float sr = 0.f, si = 0.f;
    const float2* base = Pp + (size_t)b * NGRP * PPH + j;
    for (int g = 0; g < NGRP; ++g) {
        float2 p = base[(size_t)g * PPH];
        sr += p.x;
        si += p.y;
    }
    Pred[(size_t)b * PPH + j] = make_float2(sr, si);
}

// 8 blocks: Hermitian reconstruction + inverse FFT (conj->fwd->Re), scaled
__global__ __launch_bounds__(256) void ifft_mean(const float2* __restrict__ Pred,
                                                 float* __restrict__ mv) {
    __shared__ float lre[4096];
    __shared__ float lim[4096];
    constexpr int REV16[16] = {0, 8, 4, 12, 2, 10, 6, 14, 1, 9, 5, 13, 3, 11, 7, 15};
    const int t = threadIdx.x;
    const int b = blockIdx.x;
    for (int j = t; j < 4096; j += 256) {
        float2 p;
        if (j <= 2048) {
            p = Pred[(size_t)b * PPH + j];
        } else {
            p = Pred[(size_t)b * PPH + (4096 - j)];
            p.y = -p.y;  // Hermitian mirror
        }
        int key = (j >> 8) & 15;
        int ph = j ^ ((key & 3) << 2) ^ ((key & 1) << 4);
        lre[ph] = p.x;
        lim[ph] = -p.y;  // conj for inverse transform
    }
    __syncthreads();
    float ozr[16], ozi[16];
    fft4096_r16_core<false>(lre, lim, t, ozr, ozi);
    const float scale = 1.0f / (4096.0f * 512.0f);
#pragma unroll
    for (int i = 0; i < 16; ++i)
        mv[(size_t)b * 4096 + t + 256 * i] = ozr[REV16[i]] * scale;
}

// single block, 1024 threads: batch-mean, iterative top-8 argmax via shfl, per-batch softmax
__global__ __launch_bounds__(1024) void topk_softmax(const float* __restrict__ mv,
                                                     int* __restrict__ idxO,
                                                     float* __restrict__ tcO) {
    __shared__ float vals[4096];
    __shared__ float wv[16];
    __shared__ int wix[16];
    __shared__ int sidx[TOPK];
    const int tid = threadIdx.x;
    const int lane = tid & 63, wvid = tid >> 6;
    for (int j = tid; j < 4096; j += 1024) {
        float s = 0.f;
        for (int b = 0; b < BB; ++b) s += mv[(size_t)b * 4096 + j];
        vals[j] = s * 0.125f;
    }
    __syncthreads();
    for (int k = 0; k < TOPK; ++k) {
        float best = -INFINITY;
        int bi = 0x7fffffff;
        for (int j = tid; j < 4096; j += 1024) {
            float v = vals[j];
            if (v > best) { best = v; bi = j; }
        }
#pragma unroll
        for (int off = 32; off > 0; off >>= 1) {
            float ov = __shfl_down(best, off);
            int oi = __shfl_down(bi, off);
            if (ov > best || (ov == best && oi < bi)) { best = ov; bi = oi; }
        }
        if (lane == 0) { wv[wvid] = best; wix[wvid] = bi; }
        __syncthreads();
        if (wvid == 0) {
            best = (lane < 16) ? wv[lane] : -INFINITY;
            bi = (lane < 16) ? wix[lane] : 0x7fffffff;
#pragma unroll
            for (int off = 8; off > 0; off >>= 1) {
                float ov = __shfl_down(best, off);
                int oi = __shfl_down(bi, off);
                if (ov > best || (ov == best && oi < bi)) { best = ov; bi = oi; }
            }
            if (lane == 0) {
                sidx[k] = bi;
                idxO[k] = bi;
                vals[bi] = -INFINITY;
            }
        }
        __syncthreads();
    }
    if (tid < BB) {
        float w[TOPK];
        float m = -INFINITY;
        for (int k = 0; k < TOPK; ++k) {
            w[k] = mv[(size_t)tid * 4096 + sidx[k]];
            m = fmaxf(m, w[k]);
        }
        float s = 0.f;
        for (int k = 0; k < TOPK; ++k) { w[k] = expf(w[k] - m); s += w[k]; }
        float inv = 1.0f / s;
        for (int k = 0; k < TOPK; ++k) tcO[tid * TOPK + k] = w[k] * inv;
    }
}

// out[b,l,:] = sum_k tc[b,k] * VO_bf16[b,(l+idx[k])%L,:]
__global__ __launch_bounds__(256) void gather_out(const u16* __restrict__ VO,
                                                  const int* __restrict__ idx,
                                                  const float* __restrict__ tc,
                                                  float* __restrict__ out) {
    const int e = blockIdx.x * 256 + threadIdx.x;
    const int d8 = e & 63;
    const int l = (e >> 6) & 4095;
    const int b = e >> 18;
    float s[8] = {};
#pragma unroll
    for (int k = 0; k < TOPK; ++k) {
        const int src = (l + idx[k]) & 4095;
        const float w = tc[b * TOPK + k];
        uint4 v = *(const uint4*)&VO[((size_t)(b * 4096 + src)) * 512 + d8 * 8];
        s[0] += w * __uint_as_float(v.x << 16);
        s[1] += w * __uint_as_float(v.x & 0xFFFF0000u);
        s[2] += w * __uint_as_float(v.y << 16);
        s[3] += w * __uint_as_float(v.y & 0xFFFF0000u);
        s[4] += w * __uint_as_float(v.z << 16);
        s[5] += w * __uint_as_float(v.z & 0xFFFF0000u);
        s[6] += w * __uint_as_float(v.w << 16);
        s[7] += w * __uint_as_float(v.w & 0xFFFF0000u);
    }
    const size_t ob = ((size_t)(b * 4096 + l)) * 512 + d8 * 8;
    *(float4*)&out[ob]     = make_float4(s[0], s[1], s[2], s[3]);
    *(float4*)&out[ob + 4] = make_float4(s[4], s[5], s[6], s[7]);
}

extern "C" void kernel_launch(void* const* d_in, const int* in_sizes, int n_in,
                              void* d_out, int out_size, void* d_ws, size_t ws_size,
                              hipStream_t stream) {
    const float* queries = (const float*)d_in[0];
    const float* keys    = (const float*)d_in[1];
    const float* values  = (const float*)d_in[2];
    const float* Wq = (const float*)d_in[3];
    const float* Wk = (const float*)d_in[5];
    const float* Wv = (const float*)d_in[7];
    const float* bv = (const float*)d_in[8];
    const float* Wo = (const float*)d_in[9];
    const float* bo = (const float*)d_in[10];
    float* out = (float*)d_out;

    const size_t SZ = (size_t)ML * DMODEL;  // 16,777,216 elements
    u16* Qtb = (u16*)d_ws;                  // bf16 q''^T [512][ML]   32 MB
    u16* Ktb = Qtb + SZ;                    // bf16 keys^T            32 MB
    u16* VOb = Ktb + SZ;                    // bf16 VO [ML][512]      32 MB
    float* Pp   = (float*)(VOb + SZ);       // 33.6 MB
    float* Pred = Pp + (size_t)BB * NGRP * PPH * 2;
    float* mv   = Pred + (size_t)BB * PPH * 2;
    int*   idx  = (int*)(mv + 32768);
    float* tc   = mv + 32768 + 16;
    float* bc   = mv + 32768 + 96;
    u16* Mh  = (u16*)(bc + 512);            // 512 KB
    u16* Wch = Mh + 262144;                 // 512 KB

    dim3 blk(256);

    // 1) weight prep: M = Wq@Wk^T, Wc = Wv@Wo (RNE bf16, [N][K]), bc = bv@Wo + bo
    prep_all<<<dim3(144), blk, 0, stream>>>(Wq, Wk, Wv, Wo, bv, bo, Mh, Wch, bc);

    // 2) mega-dispatch: Q-GEMM + V-GEMM + keys-transpose (all only depend on prep)
    proj3<<<dim3(6144), blk, 0, stream>>>(queries, Mh, Qtb, values, Wch, bc, VOb, keys, Ktb);

    // 3) correlation FFT (bf16 inputs, Hermitian half-spectrum)
    fft_cross<<<dim3(BB * NGRP), blk, 0, stream>>>(Qtb, Ktb, Pp);

    // 4) spectrum reduce
    reduce_ppart<<<dim3(9, BB), blk, 0, stream>>>((const float2*)Pp, (float2*)Pred);

    // 5) inverse FFT per batch
    ifft_mean<<<dim3(BB), blk, 0, stream>>>((const float2*)Pred, mv);

    // 6) top-k + softmax
    topk_softmax<<<dim3(1), dim3(1024), 0, stream>>>(mv, idx, tc);

    // 7) weighted gather to output
    gather_out<<<dim3((BB * LSEQ * (DMODEL / 8)) / 256), blk, 0, stream>>>(VOb, idx, tc, out);
}